// Round 3
// baseline (7945.025 us; speedup 1.0000x reference)
//
#include <hip/hip_runtime.h>
#include <cmath>

#define Tn 4096
#define Hn 1024
#define NHn 16
#define HDn 64
#define In 4096
#define Vn 1024
#define NSTEPSn 8

enum { EPI_NONE = 0, EPI_ADD = 1, EPI_SILU = 2, EPI_MUL = 3, EPI_BIAS = 4 };

typedef __attribute__((ext_vector_type(8))) short bf16x8;
typedef __attribute__((ext_vector_type(4))) float f32x4;

__device__ inline unsigned short bf16rne(float x) {
    unsigned int u = __float_as_uint(x);
    u += 0x7fff + ((u >> 16) & 1);
    return (unsigned short)(u >> 16);
}
__device__ inline float bf2f(unsigned short h) {
    return __uint_as_float(((unsigned int)h) << 16);
}
__device__ inline void split3(float x, unsigned short& h, unsigned short& m,
                              unsigned short& l) {
    h = bf16rne(x);
    float r = x - bf2f(h);
    m = bf16rne(r);
    float r2 = r - bf2f(m);
    l = bf16rne(r2);
}

// Async global->LDS, 16B per lane (wave-uniform LDS base; HW scatters lane*16).
__device__ __forceinline__ void gload_lds(const unsigned short* g,
                                          const unsigned short* l) {
    __builtin_amdgcn_global_load_lds(
        (const __attribute__((address_space(1))) unsigned int*)(uintptr_t)g,
        (__attribute__((address_space(3))) unsigned int*)(unsigned int)(uintptr_t)l,
        16, 0, 0);
}

// ---------------- RoPE cos/sin table ----------------
__global__ void rope_tab_kernel(double2* __restrict__ tab) {
    int tid = threadIdx.x;  // 256 threads
    int j = tid >> 5, i = tid & 31;
    double inv = exp(-((double)(2 * i) * (1.0 / (double)HDn)) * 9.210340371976184);
    double ang = (double)j * inv;
    double2 cs;
    cs.x = cos(ang);
    cs.y = sin(ang);
    tab[tid] = cs;
}

// ---------------- Weight pre-split: W[K][N] fp32 -> W3[3][N][K] bf16 ----------------
__global__ __launch_bounds__(256) void presplit_kernel(const float* __restrict__ W,
                                                       unsigned short* __restrict__ W3,
                                                       int K, int N) {
    __shared__ float S[64][65];
    int k0 = blockIdx.y * 64, n0 = blockIdx.x * 64;
    int tid = threadIdx.x;
#pragma unroll
    for (int r = 0; r < 4; r++) {
        int idx = tid + r * 256;
        int kr = idx >> 4, c4 = (idx & 15) << 2;
        float4 v = *(const float4*)(W + (size_t)(k0 + kr) * N + n0 + c4);
        S[kr][c4] = v.x;
        S[kr][c4 + 1] = v.y;
        S[kr][c4 + 2] = v.z;
        S[kr][c4 + 3] = v.w;
    }
    __syncthreads();
    size_t PS = (size_t)N * K;
#pragma unroll
    for (int r = 0; r < 4; r++) {
        int idx = tid + r * 256;
        int kq = idx & 15, n = idx >> 4;
        ushort4 hq, mq, lq;
        split3(S[4 * kq + 0][n], hq.x, mq.x, lq.x);
        split3(S[4 * kq + 1][n], hq.y, mq.y, lq.y);
        split3(S[4 * kq + 2][n], hq.z, mq.z, lq.z);
        split3(S[4 * kq + 3][n], hq.w, mq.w, lq.w);
        size_t off = (size_t)(n0 + n) * K + k0 + 4 * kq;
        *(ushort4*)(W3 + off) = hq;
        *(ushort4*)(W3 + PS + off) = mq;
        *(ushort4*)(W3 + 2 * PS + off) = lq;
    }
}

// ---------------- RMSNorm -> bf16 triple planes (f64 math) ----------------
__global__ __launch_bounds__(256) void rmsnorm3_kernel(const float* __restrict__ x,
                                                       const float* __restrict__ w,
                                                       unsigned short* __restrict__ y3,
                                                       size_t stride) {
    int t = blockIdx.x;
    const float4* xr = (const float4*)(x + (size_t)t * Hn);
    float4 v = xr[threadIdx.x];
    double ss = (double)v.x * v.x + (double)v.y * v.y + (double)v.z * v.z + (double)v.w * v.w;
#pragma unroll
    for (int o = 1; o < 64; o <<= 1) ss += __shfl_xor(ss, o, 64);
    __shared__ double red[4];
    if ((threadIdx.x & 63) == 0) red[threadIdx.x >> 6] = ss;
    __syncthreads();
    double tot = red[0] + red[1] + red[2] + red[3];
    double rs = 1.0 / sqrt(tot * (1.0 / Hn) + 1e-6);
    const float4* wr = (const float4*)w;
    float4 wv = wr[threadIdx.x];
    float o[4];
    o[0] = (float)((double)v.x * rs * (double)wv.x);
    o[1] = (float)((double)v.y * rs * (double)wv.y);
    o[2] = (float)((double)v.z * rs * (double)wv.z);
    o[3] = (float)((double)v.w * rs * (double)wv.w);
    ushort4 hq, mq, lq;
    split3(o[0], hq.x, mq.x, lq.x);
    split3(o[1], hq.y, mq.y, lq.y);
    split3(o[2], hq.z, mq.z, lq.z);
    split3(o[3], hq.w, mq.w, lq.w);
    size_t off = (size_t)t * Hn + threadIdx.x * 4;
    *(ushort4*)(y3 + off) = hq;
    *(ushort4*)(y3 + stride + off) = mq;
    *(ushort4*)(y3 + 2 * stride + off) = lq;
}

// ---------------- Attention (f64 dot, table RoPE, f32 exp), out bf16 triple ----
__global__ __launch_bounds__(256) void attn_kernel(const float* __restrict__ q,
                                                   const float* __restrict__ K0,
                                                   const float* __restrict__ V0,
                                                   const float* __restrict__ EK,
                                                   const float* __restrict__ EV,
                                                   const int* __restrict__ toks,
                                                   const double2* __restrict__ tab,
                                                   unsigned short* __restrict__ ctx3,
                                                   size_t stride, int p) {
    int wave = blockIdx.x * 4 + (threadIdx.x >> 6);  // t*NH + head
    int lane = threadIdx.x & 63;
    int t = wave >> 4;
    int col = ((wave & 15) << 6) | lane;
    int i = lane & 31;
    int half = lane >> 5;
    size_t base = (size_t)wave * HDn + lane;

    double2 csp = tab[p * 32 + i];
    double qv = (double)q[base];
    double qpart = __shfl_xor(qv, 32, 64);
    double qr = half ? (qv * csp.x + qpart * csp.y) : (qv * csp.x - qpart * csp.y);

    double sc[NSTEPSn];
    int tk[NSTEPSn];
    double m = -1e300;
    for (int j = 0; j <= p; j++) {
        double kr;
        if (j == 0) {
            kr = (double)K0[base];
            tk[0] = 0;
        } else {
            int tok = toks[(size_t)t * NSTEPSn + (j - 1)];
            tk[j] = tok;
            double kv = (double)EK[(size_t)tok * Hn + col];
            double kpart = __shfl_xor(kv, 32, 64);
            double2 cs = tab[j * 32 + i];
            kr = half ? (kv * cs.x + kpart * cs.y) : (kv * cs.x - kpart * cs.y);
        }
        double pr = qr * kr;
#pragma unroll
        for (int o = 1; o < 64; o <<= 1) pr += __shfl_xor(pr, o, 64);
        sc[j] = pr * 0.125;
        m = fmax(m, sc[j]);
    }
    double den = 0.0;
    for (int j = 0; j <= p; j++) {
        sc[j] = (double)expf((float)(sc[j] - m));
        den += sc[j];
    }
    double invd = 1.0 / den;
    double acc = 0.0;
    for (int j = 0; j <= p; j++) {
        double vv = (j == 0) ? (double)V0[base] : (double)EV[(size_t)tk[j] * Hn + col];
        acc += sc[j] * vv;
    }
    unsigned short h, mm, l;
    split3((float)(acc * invd), h, mm, l);
    ctx3[base] = h;
    ctx3[stride + base] = mm;
    ctx3[2 * stride + base] = l;
}

// ---------------- bf16x3 MFMA GEMM: 128x128 tile, 8 waves, 3-buffer pipeline ----
// C(M x N) = A(M x K) @ B(K x N). A planes [3][M][K], B planes [3][N][K].
// LDS cell layout inside each 1KB (16row x 32col bf16) segment is K-OCTET-MAJOR:
// cell(row,slot) = slot*16 + row. Reader lane (row=lane&15, slot=lane>>4) hits
// byte 256*hi + 16*rA -> bank (4*rA+d)%32 -> exactly 2 lanes/bank (free).
// Writer lane l sources global (row = sub*16 + (l&15), col-octet = l>>4), so
// each lane receives the identical data as before -> bit-identical numerics.
// Pipeline: 3 phases/chunk, phase p+1 ds_reads inside phase p's MFMA region;
// counted vmcnt(4) in P2 proves buffer c+1 landed; never vmcnt(0) steady-state.
// FUSED variant: one A-tile, two B matrices (G,U); waves 0-3 own G 128x64,
// waves 4-7 own U; epilogue exchanges silu(g) via LDS (stride 68: conflict-free)
// and writes split3(u * silu(g)) triple.
#define BUFU 24576  // ushorts per buffer: 48KB (A 24KB + B 24KB)
template <int EPI, bool TRIPLE, bool FUSED>
__global__ __launch_bounds__(512, 2) void gemm3_kernel(
    const unsigned short* __restrict__ A3, size_t strideA,
    const unsigned short* __restrict__ B3, const unsigned short* __restrict__ BU3,
    size_t strideB, int ldbk,
    float* Cf, unsigned short* C3, size_t strideC,
    const float* aux, int K, int ldc) {
    __shared__ __align__(16) unsigned short lds[3 * BUFU];  // 144 KB

    int tid = threadIdx.x;
    int wv = tid >> 6, lane = tid & 63;
    int wr, wc, grp;
    if (FUSED) {
        grp = wv >> 2;          // 0 = G, 1 = U
        wr = (wv >> 1) & 1;     // 2 m-groups of 64
        wc = wv & 1;            // 2 n-groups of 32 (64-col tile)
    } else {
        grp = 0;
        wr = wv >> 2;           // 2 m-groups of 64
        wc = wv & 3;            // 4 n-groups of 32 (128-col tile)
    }

    // ---- XCD swizzle ----
    int f = blockIdx.x;
    int xcd = f & 7;
    int j = f >> 3;
    int mblk, nblk;
    if (FUSED) {
        int bmPer = gridDim.x >> 7;  // GN=16 (64-col blocks)
        mblk = (xcd * bmPer + (j >> 4)) * 128;
        nblk = (j & 15) * 64;
    } else {
        int bmPer = gridDim.x >> 6;  // GN=8 (128-col blocks)
        mblk = (xcd * bmPer + (j >> 3)) * 128;
        nblk = (j & 7) * 128;
    }

    // ---- staging segments: 48 x 1KB, each wave owns 6 (2 per phase) ----
    // k-octet-major cells: lane l sources (row = sub*16 + (l&15), col = (l>>4)*8).
    int rsel = lane & 15;
    int csel = (lane >> 4) << 3;
    const unsigned short* gseg[6];
    unsigned lseg[6];
#pragma unroll
    for (int i = 0; i < 6; i++) {
        int s = wv * 6 + i;
        if (s < 24) {
            int pl = s >> 3, sub = s & 7;
            gseg[i] = A3 + (size_t)pl * strideA +
                      (size_t)(mblk + sub * 16 + rsel) * K + csel;
            lseg[i] = pl * 4096 + sub * 512;
        } else if (!FUSED) {
            int u = s - 24;
            int pl = u >> 3, sub = u & 7;
            gseg[i] = B3 + (size_t)pl * strideB +
                      (size_t)(nblk + sub * 16 + rsel) * ldbk + csel;
            lseg[i] = 12288 + pl * 4096 + sub * 512;
        } else {
            int u = s - 24;
            const unsigned short* Bp = (u < 12) ? B3 : BU3;
            int v = (u < 12) ? u : u - 12;
            int pl = v >> 2, sub = v & 3;
            gseg[i] = Bp + (size_t)pl * strideB +
                      (size_t)(nblk + sub * 16 + rsel) * ldbk + csel;
            lseg[i] = 12288 + ((u < 12) ? 0 : 6144) + pl * 2048 + sub * 512;
        }
    }

    const int bbase = 12288 + (FUSED ? grp * 6144 : 0);
    const int bps = FUSED ? 2048 : 4096;  // LDS plane stride in B region

    f32x4 acc[4][2];
    double accd[4][2][4];
#pragma unroll
    for (int mt = 0; mt < 4; mt++)
#pragma unroll
        for (int nt = 0; nt < 2; nt++) {
            acc[mt][nt] = (f32x4){0.f, 0.f, 0.f, 0.f};
#pragma unroll
            for (int r = 0; r < 4; r++) accd[mt][nt][r] = 0.0;
        }

    int rA = lane & 15;
    // fragment offset within a (pl,sub) 512-ushort segment: k-octet-major
    unsigned fo = ((lane >> 4) << 7) + (rA << 3);

    int nc = K >> 5;  // 32-K chunks

    // ---- prologue: stage chunk0 -> buf0, chunk1 -> buf1, preload P0 frags ----
#pragma unroll
    for (int i = 0; i < 6; i++) gload_lds(gseg[i], lds + lseg[i]);
#pragma unroll
    for (int i = 0; i < 6; i++) gload_lds(gseg[i] + 32, lds + BUFU + lseg[i]);
    asm volatile("s_waitcnt vmcnt(6)" ::: "memory");  // chunk 0 landed
    __builtin_amdgcn_s_barrier();

    bf16x8 Af0[4], Bf0[2], Bf1[2];
    {
        const unsigned short* Ar = lds;
        const unsigned short* Br = lds + bbase;
#pragma unroll
        for (int mt = 0; mt < 4; mt++)
            Af0[mt] = *(const bf16x8*)(Ar + (wr * 4 + mt) * 512 + fo);
#pragma unroll
        for (int nt = 0; nt < 2; nt++) {
            Bf0[nt] = *(const bf16x8*)(Br + (wc * 2 + nt) * 512 + fo);
            Bf1[nt] = *(const bf16x8*)(Br + bps + (wc * 2 + nt) * 512 + fo);
        }
    }

    int rd = 0, w2 = 2;
    for (int c = 0; c < nc; ++c) {
        const unsigned short* Ar = lds + rd * BUFU;
        const unsigned short* Br = Ar + bbase;
        unsigned short* Lw = lds + w2 * BUFU;
        const bool pf = (c + 2 < nc);
        const bool nx = (c + 1 < nc);
        int koff = (c + 2) << 5;

        bf16x8 AfN[4], AfM[4], Bf2[2];

        // ================= P0: stage(0,1); MFMA A0B0+A0B1; read A1 ============
        if (pf) {
            gload_lds(gseg[0] + koff, Lw + lseg[0]);
            gload_lds(gseg[1] + koff, Lw + lseg[1]);
        }
        if (c > 0 && (c & 1) == 0) {
#pragma unroll
            for (int mt = 0; mt < 4; mt++)
#pragma unroll
                for (int nt = 0; nt < 2; nt++)
#pragma unroll
                    for (int r = 0; r < 4; r++) {
                        accd[mt][nt][r] += (double)acc[mt][nt][r];
                        acc[mt][nt][r] = 0.f;
                    }
        }
        __builtin_amdgcn_s_barrier();
#pragma unroll
        for (int mt = 0; mt < 4; mt++)
            AfN[mt] = *(const bf16x8*)(Ar + 4096 + (wr * 4 + mt) * 512 + fo);
        __builtin_amdgcn_s_setprio(1);
#pragma unroll
        for (int mt = 0; mt < 4; mt++)
#pragma unroll
            for (int nt = 0; nt < 2; nt++) {
                f32x4 a = acc[mt][nt];
                a = __builtin_amdgcn_mfma_f32_16x16x32_bf16(Af0[mt], Bf0[nt], a, 0, 0, 0);
                a = __builtin_amdgcn_mfma_f32_16x16x32_bf16(Af0[mt], Bf1[nt], a, 0, 0, 0);
                acc[mt][nt] = a;
            }
        __builtin_amdgcn_s_setprio(0);
        __builtin_amdgcn_s_barrier();

        // ================= P1: stage(2,3); MFMA A1B0+A1B1; read A2,B2 =========
        if (pf) {
            gload_lds(gseg[2] + koff, Lw + lseg[2]);
            gload_lds(gseg[3] + koff, Lw + lseg[3]);
        }
        __builtin_amdgcn_s_barrier();
#pragma unroll
        for (int mt = 0; mt < 4; mt++)
            AfM[mt] = *(const bf16x8*)(Ar + 8192 + (wr * 4 + mt) * 512 + fo);
#pragma unroll
        for (int nt = 0; nt < 2; nt++)
            Bf2[nt] = *(const bf16x8*)(Br + 2 * bps + (wc * 2 + nt) * 512 + fo);
        __builtin_amdgcn_s_setprio(1);
#pragma unroll
        for (int mt = 0; mt < 4; mt++)
#pragma unroll
            for (int nt = 0; nt < 2; nt++) {
                f32x4 a = acc[mt][nt];
                a = __builtin_amdgcn_mfma_f32_16x16x32_bf16(AfN[mt], Bf0[nt], a, 0, 0, 0);
                a = __builtin_amdgcn_mfma_f32_16x16x32_bf16(AfN[mt], Bf1[nt], a, 0, 0, 0);
                acc[mt][nt] = a;
            }
        __builtin_amdgcn_s_setprio(0);
        __builtin_amdgcn_s_barrier();

        // ===== P2: vmcnt proves buf c+1 landed; stage(4,5); MFMA; preload P0' ==
        if (nx) {
            if (pf)
                asm volatile("s_waitcnt vmcnt(4)" ::: "memory");
            else
                asm volatile("s_waitcnt vmcnt(0)" ::: "memory");
        }
        if (pf) {
            gload_lds(gseg[4] + koff, Lw + lseg[4]);
            gload_lds(gseg[5] + koff, Lw + lseg[5]);
        }
        __builtin_amdgcn_s_barrier();
        __builtin_amdgcn_s_setprio(1);
#pragma unroll
        for (int mt = 0; mt < 4; mt++)
#pragma unroll
            for (int nt = 0; nt < 2; nt++) {
                f32x4 a = acc[mt][nt];
                a = __builtin_amdgcn_mfma_f32_16x16x32_bf16(Af0[mt], Bf2[nt], a, 0, 0, 0);
                a = __builtin_amdgcn_mfma_f32_16x16x32_bf16(AfM[mt], Bf0[nt], a, 0, 0, 0);
                acc[mt][nt] = a;
            }
        __builtin_amdgcn_s_setprio(0);
        if (nx) {  // preload next chunk's P0 operands (buffer rd+1, proven valid)
            int rdn = (rd + 1 == 3) ? 0 : rd + 1;
            const unsigned short* An = lds + rdn * BUFU;
            const unsigned short* Bn = An + bbase;
#pragma unroll
            for (int mt = 0; mt < 4; mt++)
                Af0[mt] = *(const bf16x8*)(An + (wr * 4 + mt) * 512 + fo);
#pragma unroll
            for (int nt = 0; nt < 2; nt++) {
                Bf0[nt] = *(const bf16x8*)(Bn + (wc * 2 + nt) * 512 + fo);
                Bf1[nt] = *(const bf16x8*)(Bn + bps + (wc * 2 + nt) * 512 + fo);
            }
        }
        __builtin_amdgcn_s_barrier();

        rd = (rd + 1 == 3) ? 0 : rd + 1;
        w2 = (w2 + 1 == 3) ? 0 : w2 + 1;
    }

    // final promote (last 2 chunks)
#pragma unroll
    for (int mt = 0; mt < 4; mt++)
#pragma unroll
        for (int nt = 0; nt < 2; nt++)
#pragma unroll
            for (int r = 0; r < 4; r++) accd[mt][nt][r] += (double)acc[mt][nt][r];

    if (FUSED) {
        // ---- G waves: silu(g) -> LDS; U waves: u * silu(g) -> bf16 triple ----
        // stride 68 dwords: bank = 16*(hi&1) + rA -> 2 lanes/bank (free)
        float* Gs = (float*)lds;  // [128][68] floats, ~34.8 KB
        if (grp == 0) {
#pragma unroll
            for (int mt = 0; mt < 4; mt++)
#pragma unroll
                for (int nt = 0; nt < 2; nt++) {
                    int nl = wc * 32 + nt * 16 + (lane & 15);
                    int mb = wr * 64 + mt * 16 + ((lane >> 4) << 2);
#pragma unroll
                    for (int r = 0; r < 4; r++) {
                        float vf = (float)accd[mt][nt][r];
                        Gs[(mb + r) * 68 + nl] = vf / (1.0f + expf(-vf));
                    }
                }
        }
        __syncthreads();
        if (grp == 1) {
#pragma unroll
            for (int mt = 0; mt < 4; mt++)
#pragma unroll
                for (int nt = 0; nt < 2; nt++) {
                    int nl = wc * 32 + nt * 16 + (lane & 15);
                    int mb = wr * 64 + mt * 16 + ((lane >> 4) << 2);
#pragma unroll
                    for (int r = 0; r < 4; r++) {
                        double v = accd[mt][nt][r] * (double)Gs[(mb + r) * 68 + nl];
                        size_t off = (size_t)(mblk + mb + r) * ldc + (nblk + nl);
                        unsigned short h, mm, l;
                        split3((float)v, h, mm, l);
                        C3[off] = h;
                        C3[strideC + off] = mm;
                        C3[2 * strideC + off] = l;
                    }
                }
        }
        return;
    }

    // ---- epilogue (f64), write f32 or bf16-triple ----
#pragma unroll
    for (int mt = 0; mt < 4; mt++)
#pragma unroll
        for (int nt = 0; nt < 2; nt++) {
            int n = nblk + wc * 32 + nt * 16 + (lane & 15);
            int mb = mblk + wr * 64 + mt * 16 + ((lane >> 4) << 2);
#pragma unroll
            for (int r = 0; r < 4; r++) {
                int m = mb + r;
                size_t off = (size_t)m * ldc + n;
                double v = accd[mt][nt][r];
                if (EPI == EPI_ADD) v += (double)aux[off];
                if (EPI == EPI_SILU) {
                    float vf = (float)v;
                    v = (double)(vf / (1.0f + expf(-vf)));
                }
                if (EPI == EPI_MUL) v *= (double)aux[off];
                if (EPI == EPI_BIAS) v += (double)aux[n];
                if (TRIPLE) {
                    unsigned short h, mm, l;
                    split3((float)v, h, mm, l);
                    C3[off] = h;
                    C3[strideC + off] = mm;
                    C3[2 * strideC + off] = l;
                } else {
                    Cf[off] = (float)v;
                }
            }
        }
}

// ---------------- Argmax over f32 logits (first-max tie-break) ----------------
__global__ __launch_bounds__(256) void argmax_kernel(const float* __restrict__ logits,
                                                     int* __restrict__ out_tok, int p) {
    int t = blockIdx.x;
    const float* lr = logits + (size_t)t * Vn;
    float bv = -INFINITY;
    int bi = 0x7fffffff;
    for (int j = threadIdx.x; j < Vn; j += 256) {
        float v = lr[j];
        if (v > bv || (v == bv && j < bi)) {
            bv = v;
            bi = j;
        }
    }
#pragma unroll
    for (int o = 1; o < 64; o <<= 1) {
        float ov = __shfl_xor(bv, o, 64);
        int oi = __shfl_xor(bi, o, 64);
        if (ov > bv || (ov == bv && oi < bi)) {
            bv = ov;
            bi = oi;
        }
    }
    __shared__ float sv[4];
    __shared__ int si[4];
    if ((threadIdx.x & 63) == 0) {
        sv[threadIdx.x >> 6] = bv;
        si[threadIdx.x >> 6] = bi;
    }
    __syncthreads();
    if (threadIdx.x == 0) {
        for (int w = 1; w < 4; w++) {
            if (sv[w] > bv || (sv[w] == bv && si[w] < bi)) {
                bv = sv[w];
                bi = si[w];
            }
        }
        out_tok[(size_t)t * NSTEPSn + p] = bi;
    }
}

// ---------------- Embedding gather ----------------
__global__ __launch_bounds__(256) void embed_kernel(const float* __restrict__ E,
                                                    const int* __restrict__ toks,
                                                    float* __restrict__ x, int p) {
    int t = blockIdx.x;
    int tok = toks[(size_t)t * NSTEPSn + p];
    float4 v = ((const float4*)(E + (size_t)tok * Hn))[threadIdx.x];
    ((float4*)(x + (size_t)t * Hn))[threadIdx.x] = v;
}

extern "C" void kernel_launch(void* const* d_in, const int* in_sizes, int n_in,
                              void* d_out, int out_size, void* d_ws, size_t ws_size,
                              hipStream_t stream) {
    const float* x0 = (const float*)d_in[0];
    const float* Wq = (const float*)d_in[1];
    const float* Wk = (const float*)d_in[2];
    const float* Wv = (const float*)d_in[3];
    const float* Wo = (const float*)d_in[4];
    const float* Wg = (const float*)d_in[5];
    const float* Wu = (const float*)d_in[6];
    const float* Wd = (const float*)d_in[7];
    const float* n1 = (const float*)d_in[8];
    const float* n2 = (const float*)d_in[9];
    const float* Emb = (const float*)d_in[10];
    const float* Wout = (const float*)d_in[11];
    const float* bout = (const float*)d_in[12];
    int* toks = (int*)d_out;

    float* ws = (float*)d_ws;
    const size_t M1 = 1024 * 1024;
    float* EK = ws;                  // V x H fp32           4MB
    float* EV = ws + 1 * M1;         //                      4MB
    float* K0 = ws + 2 * M1;         // T x H fp32           16MB
    float* V0 = ws + 6 * M1;         //                      16MB
    float* xb = ws + 10 * M1;        // residual hidden      16MB
    float* qb = ws + 14 * M1;        // q / MLP acc / logits 16MB
    float* Gc = ws + 18 * M1;        // (free since GU fuse) 16MB
    unsigned short* s3a = (unsigned short*)(ws + 22 * M1);  // triple TxH  24MB
    unsigned short* s3g = (unsigned short*)(ws + 28 * M1);  // triple TxH  24MB
    double2* tab = (double2*)(ws + 34 * M1);                // 256 double2  4KB
    unsigned short* W3q = (unsigned short*)(ws + 34 * M1 + 1024);  // 6MB
    unsigned short* W3k = W3q + 3 * M1;                            // 6MB
    unsigned short* W3v = W3k + 3 * M1;                            // 6MB
    unsigned short* W3o = W3v + 3 * M1;                            // 6MB
    unsigned short* W3t = W3o + 3 * M1;  // Wout                     6MB
    unsigned short* W3g = W3t + 3 * M1;                            // 24MB
    unsigned short* W3u = W3g + 12 * M1;                           // 24MB
    unsigned short* W3d = W3u + 12 * M1;                           // 24MB
    // total ~= 238 MB

    const size_t STH = (size_t)Tn * Hn;  // plane stride, T x 1024 triples
    const size_t SVH = (size_t)Vn * Hn;  // plane stride, V x H triple
    const size_t SW1 = M1;               // plane stride, 1M-element weights
    const size_t SW4 = 4 * M1;           // plane stride, 4M-element weights
    (void)Gc;

    dim3 blk(256);
    dim3 gblk(512);
    const int gTH = 256;  // (M/128=32) x (N/128=8), 1D swizzled
    const int gVH = 64;   // (M/128=8)  x 8
    const int gGU = 512;  // (M/128=32) x (N/64=16), fused G+U

    // ---- One-time precompute ----
    rope_tab_kernel<<<1, 256, 0, stream>>>(tab);
    presplit_kernel<<<dim3(16, 16), blk, 0, stream>>>(Wq, W3q, Hn, Hn);
    presplit_kernel<<<dim3(16, 16), blk, 0, stream>>>(Wk, W3k, Hn, Hn);
    presplit_kernel<<<dim3(16, 16), blk, 0, stream>>>(Wv, W3v, Hn, Hn);
    presplit_kernel<<<dim3(16, 16), blk, 0, stream>>>(Wo, W3o, Hn, Hn);
    presplit_kernel<<<dim3(16, 16), blk, 0, stream>>>(Wout, W3t, Hn, Vn);
    presplit_kernel<<<dim3(In / 64, Hn / 64), blk, 0, stream>>>(Wg, W3g, Hn, In);
    presplit_kernel<<<dim3(In / 64, Hn / 64), blk, 0, stream>>>(Wu, W3u, Hn, In);
    presplit_kernel<<<dim3(Hn / 64, In / 64), blk, 0, stream>>>(Wd, W3d, In, Hn);
    rmsnorm3_kernel<<<Vn, 256, 0, stream>>>(Emb, n1, s3a, SVH);
    gemm3_kernel<EPI_NONE, false, false><<<gVH, gblk, 0, stream>>>(
        s3a, SVH, W3k, nullptr, SW1, Hn, EK, nullptr, 0, nullptr, Hn, Hn);
    gemm3_kernel<EPI_NONE, false, false><<<gVH, gblk, 0, stream>>>(
        s3a, SVH, W3v, nullptr, SW1, Hn, EV, nullptr, 0, nullptr, Hn, Hn);

    for (int p = 0; p < NSTEPSn; p++) {
        const float* src = (p == 0) ? x0 : xb;

        rmsnorm3_kernel<<<Tn, 256, 0, stream>>>(src, n1, s3a, STH);
        gemm3_kernel<EPI_NONE, false, false><<<gTH, gblk, 0, stream>>>(
            s3a, STH, W3q, nullptr, SW1, Hn, qb, nullptr, 0, nullptr, Hn, Hn);
        if (p == 0) {
            gemm3_kernel<EPI_NONE, false, false><<<gTH, gblk, 0, stream>>>(
                s3a, STH, W3k, nullptr, SW1, Hn, K0, nullptr, 0, nullptr, Hn, Hn);
            gemm3_kernel<EPI_NONE, false, false><<<gTH, gblk, 0, stream>>>(
                s3a, STH, W3v, nullptr, SW1, Hn, V0, nullptr, 0, nullptr, Hn, Hn);
        }
        attn_kernel<<<(Tn * NHn) / 4, 256, 0, stream>>>(qb, K0, V0, EK, EV, toks,
                                                        tab, s3a, STH, p);
        // h2 = ctx @ Wo + src  (in-place into xb when src == xb)
        gemm3_kernel<EPI_ADD, false, false><<<gTH, gblk, 0, stream>>>(
            s3a, STH, W3o, nullptr, SW1, Hn, xb, nullptr, 0, src, Hn, Hn);
        rmsnorm3_kernel<<<Tn, 256, 0, stream>>>(xb, n2, s3a, STH);
        // Gated MLP, chunked over I (4 x 1024): fused silu(x@Wg)*(x@Wu) -> s3g,
        // then chunk-accumulated @Wd into qb.
        for (int c = 0; c < 4; c++) {
            gemm3_kernel<EPI_NONE, true, true><<<gGU, gblk, 0, stream>>>(
                s3a, STH, W3g + (size_t)c * M1, W3u + (size_t)c * M1, SW4, Hn,
                nullptr, s3g, STH, nullptr, Hn, 1024);
            if (c < 3) {
                gemm3_kernel<EPI_ADD, false, false><<<gTH, gblk, 0, stream>>>(
                    s3g, STH, W3d + (size_t)c * 1024, nullptr, SW4, In,
                    qb, nullptr, 0, (c == 0) ? xb : qb, Hn, Hn);
            } else {
                gemm3_kernel<EPI_ADD, true, false><<<gTH, gblk, 0, stream>>>(
                    s3g, STH, W3d + (size_t)c * 1024, nullptr, SW4, In,
                    nullptr, s3a, STH, qb, Hn, Hn);
            }
        }
        // logits = out @ Wout + bout  (into qb)
        gemm3_kernel<EPI_BIAS, false, false><<<gTH, gblk, 0, stream>>>(
            s3a, STH, W3t, nullptr, SW1, Hn, qb, nullptr, 0, bout, Hn, Vn);
        argmax_kernel<<<Tn, 256, 0, stream>>>(qb, toks, p);
        if (p < NSTEPSn - 1) embed_kernel<<<Tn, 256, 0, stream>>>(Emb, toks, xb, p);
    }
}

// Round 4
// 7848.090 us; speedup vs baseline: 1.0124x; 1.0124x over previous
//
#include <hip/hip_runtime.h>
#include <cmath>

#define Tn 4096
#define Hn 1024
#define NHn 16
#define HDn 64
#define In 4096
#define Vn 1024
#define NSTEPSn 8

enum { EPI_NONE = 0, EPI_ADD = 1, EPI_SILU = 2, EPI_MUL = 3, EPI_BIAS = 4 };

typedef __attribute__((ext_vector_type(8))) short bf16x8;
typedef __attribute__((ext_vector_type(4))) float f32x4;

__device__ inline unsigned short bf16rne(float x) {
    unsigned int u = __float_as_uint(x);
    u += 0x7fff + ((u >> 16) & 1);
    return (unsigned short)(u >> 16);
}
__device__ inline float bf2f(unsigned short h) {
    return __uint_as_float(((unsigned int)h) << 16);
}
__device__ inline void split3(float x, unsigned short& h, unsigned short& m,
                              unsigned short& l) {
    h = bf16rne(x);
    float r = x - bf2f(h);
    m = bf16rne(r);
    float r2 = r - bf2f(m);
    l = bf16rne(r2);
}

// Async global->LDS, 16B per lane (wave-uniform LDS base; HW scatters lane*16).
__device__ __forceinline__ void gload_lds(const unsigned short* g,
                                          const unsigned short* l) {
    __builtin_amdgcn_global_load_lds(
        (const __attribute__((address_space(1))) unsigned int*)(uintptr_t)g,
        (__attribute__((address_space(3))) unsigned int*)(unsigned int)(uintptr_t)l,
        16, 0, 0);
}

// ---------------- RoPE cos/sin table ----------------
__global__ void rope_tab_kernel(double2* __restrict__ tab) {
    int tid = threadIdx.x;  // 256 threads
    int j = tid >> 5, i = tid & 31;
    double inv = exp(-((double)(2 * i) * (1.0 / (double)HDn)) * 9.210340371976184);
    double ang = (double)j * inv;
    double2 cs;
    cs.x = cos(ang);
    cs.y = sin(ang);
    tab[tid] = cs;
}

// ---------------- Weight pre-split: W[K][N] fp32 -> W3[3][N][K] bf16 ----------------
__global__ __launch_bounds__(256) void presplit_kernel(const float* __restrict__ W,
                                                       unsigned short* __restrict__ W3,
                                                       int K, int N) {
    __shared__ float S[64][65];
    int k0 = blockIdx.y * 64, n0 = blockIdx.x * 64;
    int tid = threadIdx.x;
#pragma unroll
    for (int r = 0; r < 4; r++) {
        int idx = tid + r * 256;
        int kr = idx >> 4, c4 = (idx & 15) << 2;
        float4 v = *(const float4*)(W + (size_t)(k0 + kr) * N + n0 + c4);
        S[kr][c4] = v.x;
        S[kr][c4 + 1] = v.y;
        S[kr][c4 + 2] = v.z;
        S[kr][c4 + 3] = v.w;
    }
    __syncthreads();
    size_t PS = (size_t)N * K;
#pragma unroll
    for (int r = 0; r < 4; r++) {
        int idx = tid + r * 256;
        int kq = idx & 15, n = idx >> 4;
        ushort4 hq, mq, lq;
        split3(S[4 * kq + 0][n], hq.x, mq.x, lq.x);
        split3(S[4 * kq + 1][n], hq.y, mq.y, lq.y);
        split3(S[4 * kq + 2][n], hq.z, mq.z, lq.z);
        split3(S[4 * kq + 3][n], hq.w, mq.w, lq.w);
        size_t off = (size_t)(n0 + n) * K + k0 + 4 * kq;
        *(ushort4*)(W3 + off) = hq;
        *(ushort4*)(W3 + PS + off) = mq;
        *(ushort4*)(W3 + 2 * PS + off) = lq;
    }
}

// ---------------- RMSNorm -> bf16 triple planes (f64 math) ----------------
__global__ __launch_bounds__(256) void rmsnorm3_kernel(const float* __restrict__ x,
                                                       const float* __restrict__ w,
                                                       unsigned short* __restrict__ y3,
                                                       size_t stride) {
    int t = blockIdx.x;
    const float4* xr = (const float4*)(x + (size_t)t * Hn);
    float4 v = xr[threadIdx.x];
    double ss = (double)v.x * v.x + (double)v.y * v.y + (double)v.z * v.z + (double)v.w * v.w;
#pragma unroll
    for (int o = 1; o < 64; o <<= 1) ss += __shfl_xor(ss, o, 64);
    __shared__ double red[4];
    if ((threadIdx.x & 63) == 0) red[threadIdx.x >> 6] = ss;
    __syncthreads();
    double tot = red[0] + red[1] + red[2] + red[3];
    double rs = 1.0 / sqrt(tot * (1.0 / Hn) + 1e-6);
    const float4* wr = (const float4*)w;
    float4 wv = wr[threadIdx.x];
    float o[4];
    o[0] = (float)((double)v.x * rs * (double)wv.x);
    o[1] = (float)((double)v.y * rs * (double)wv.y);
    o[2] = (float)((double)v.z * rs * (double)wv.z);
    o[3] = (float)((double)v.w * rs * (double)wv.w);
    ushort4 hq, mq, lq;
    split3(o[0], hq.x, mq.x, lq.x);
    split3(o[1], hq.y, mq.y, lq.y);
    split3(o[2], hq.z, mq.z, lq.z);
    split3(o[3], hq.w, mq.w, lq.w);
    size_t off = (size_t)t * Hn + threadIdx.x * 4;
    *(ushort4*)(y3 + off) = hq;
    *(ushort4*)(y3 + stride + off) = mq;
    *(ushort4*)(y3 + 2 * stride + off) = lq;
}

// ---------------- Attention (f64 dot, table RoPE, f32 exp), out bf16 triple ----
__global__ __launch_bounds__(256) void attn_kernel(const float* __restrict__ q,
                                                   const float* __restrict__ K0,
                                                   const float* __restrict__ V0,
                                                   const float* __restrict__ EK,
                                                   const float* __restrict__ EV,
                                                   const int* __restrict__ toks,
                                                   const double2* __restrict__ tab,
                                                   unsigned short* __restrict__ ctx3,
                                                   size_t stride, int p) {
    int wave = blockIdx.x * 4 + (threadIdx.x >> 6);  // t*NH + head
    int lane = threadIdx.x & 63;
    int t = wave >> 4;
    int col = ((wave & 15) << 6) | lane;
    int i = lane & 31;
    int half = lane >> 5;
    size_t base = (size_t)wave * HDn + lane;

    double2 csp = tab[p * 32 + i];
    double qv = (double)q[base];
    double qpart = __shfl_xor(qv, 32, 64);
    double qr = half ? (qv * csp.x + qpart * csp.y) : (qv * csp.x - qpart * csp.y);

    double sc[NSTEPSn];
    int tk[NSTEPSn];
    double m = -1e300;
    for (int j = 0; j <= p; j++) {
        double kr;
        if (j == 0) {
            kr = (double)K0[base];
            tk[0] = 0;
        } else {
            int tok = toks[(size_t)t * NSTEPSn + (j - 1)];
            tk[j] = tok;
            double kv = (double)EK[(size_t)tok * Hn + col];
            double kpart = __shfl_xor(kv, 32, 64);
            double2 cs = tab[j * 32 + i];
            kr = half ? (kv * cs.x + kpart * cs.y) : (kv * cs.x - kpart * cs.y);
        }
        double pr = qr * kr;
#pragma unroll
        for (int o = 1; o < 64; o <<= 1) pr += __shfl_xor(pr, o, 64);
        sc[j] = pr * 0.125;
        m = fmax(m, sc[j]);
    }
    double den = 0.0;
    for (int j = 0; j <= p; j++) {
        sc[j] = (double)expf((float)(sc[j] - m));
        den += sc[j];
    }
    double invd = 1.0 / den;
    double acc = 0.0;
    for (int j = 0; j <= p; j++) {
        double vv = (j == 0) ? (double)V0[base] : (double)EV[(size_t)tk[j] * Hn + col];
        acc += sc[j] * vv;
    }
    unsigned short h, mm, l;
    split3((float)(acc * invd), h, mm, l);
    ctx3[base] = h;
    ctx3[stride + base] = mm;
    ctx3[2 * stride + base] = l;
}

// ---------------- bf16x3 MFMA GEMM: 128x128 tile, 8 waves, 3-buffer pipeline ----
// C(M x N) = A(M x K) @ B(K x N). A planes [3][M][K], B planes [3][N][K].
// Two LDS cell layouts (measured best per variant):
//  !FUSED: row-major cells + quad-XOR (global source: 4 consecutive lanes cover
//          one 64B row-slice -> coalesced staging; reads carry some bank
//          conflicts — measured net faster for the 128-col kernels).
//  FUSED:  k-octet-major cells (reads conflict-free: lane-contiguous LDS;
//          staging scattered 16B/lane — measured net faster here).
// Pipeline: 3 phases/chunk; phase p+1 ds_reads issue inside phase p's MFMA
// region; counted vmcnt(4) in P2 proves buffer c+1 landed; never vmcnt(0) in
// steady state. MFMA product order and f64 promote cadence bit-identical.
// FUSED: one A-tile, two B matrices (G,U); waves 0-3 own G 128x64, waves 4-7
// own U; epilogue exchanges silu(g) via LDS (stride 68) and writes
// split3(u * silu(g)) triple.
#define BUFU 24576  // ushorts per buffer: 48KB (A 24KB + B 24KB)
template <int EPI, bool TRIPLE, bool FUSED>
__global__ __launch_bounds__(512, 2) void gemm3_kernel(
    const unsigned short* __restrict__ A3, size_t strideA,
    const unsigned short* __restrict__ B3, const unsigned short* __restrict__ BU3,
    size_t strideB, int ldbk,
    float* Cf, unsigned short* C3, size_t strideC,
    const float* aux, int K, int ldc) {
    __shared__ __align__(16) unsigned short lds[3 * BUFU];  // 144 KB

    int tid = threadIdx.x;
    int wv = tid >> 6, lane = tid & 63;
    int wr, wc, grp;
    if (FUSED) {
        grp = wv >> 2;          // 0 = G, 1 = U
        wr = (wv >> 1) & 1;     // 2 m-groups of 64
        wc = wv & 1;            // 2 n-groups of 32 (64-col tile)
    } else {
        grp = 0;
        wr = wv >> 2;           // 2 m-groups of 64
        wc = wv & 3;            // 4 n-groups of 32 (128-col tile)
    }

    // ---- XCD swizzle ----
    int f = blockIdx.x;
    int xcd = f & 7;
    int j = f >> 3;
    int mblk, nblk;
    if (FUSED) {
        int bmPer = gridDim.x >> 7;  // GN=16 (64-col blocks)
        mblk = (xcd * bmPer + (j >> 4)) * 128;
        nblk = (j & 15) * 64;
    } else {
        int bmPer = gridDim.x >> 6;  // GN=8 (128-col blocks)
        mblk = (xcd * bmPer + (j >> 3)) * 128;
        nblk = (j & 7) * 128;
    }

    // ---- staging segments: 48 x 1KB, each wave owns 6 (2 per phase) ----
    int rsel, csel;
    if (FUSED) {
        // k-octet-major: lane l sources (row = sub*16 + (l&15), oct = l>>4)
        rsel = lane & 15;
        csel = (lane >> 4) << 3;
    } else {
        // row-major+quad-XOR: lanes 4q..4q+3 cover one 64B row-slice
        rsel = lane >> 2;
        csel = ((lane & 3) ^ ((lane >> 2) & 3)) << 3;
    }
    const unsigned short* gseg[6];
    unsigned lseg[6];
#pragma unroll
    for (int i = 0; i < 6; i++) {
        int s = wv * 6 + i;
        if (s < 24) {
            int pl = s >> 3, sub = s & 7;
            gseg[i] = A3 + (size_t)pl * strideA +
                      (size_t)(mblk + sub * 16 + rsel) * K + csel;
            lseg[i] = pl * 4096 + sub * 512;
        } else if (!FUSED) {
            int u = s - 24;
            int pl = u >> 3, sub = u & 7;
            gseg[i] = B3 + (size_t)pl * strideB +
                      (size_t)(nblk + sub * 16 + rsel) * ldbk + csel;
            lseg[i] = 12288 + pl * 4096 + sub * 512;
        } else {
            int u = s - 24;
            const unsigned short* Bp = (u < 12) ? B3 : BU3;
            int v = (u < 12) ? u : u - 12;
            int pl = v >> 2, sub = v & 3;
            gseg[i] = Bp + (size_t)pl * strideB +
                      (size_t)(nblk + sub * 16 + rsel) * ldbk + csel;
            lseg[i] = 12288 + ((u < 12) ? 0 : 6144) + pl * 2048 + sub * 512;
        }
    }

    const int bbase = 12288 + (FUSED ? grp * 6144 : 0);
    const int bps = FUSED ? 2048 : 4096;  // LDS plane stride in B region

    f32x4 acc[4][2];
    double accd[4][2][4];
#pragma unroll
    for (int mt = 0; mt < 4; mt++)
#pragma unroll
        for (int nt = 0; nt < 2; nt++) {
            acc[mt][nt] = (f32x4){0.f, 0.f, 0.f, 0.f};
#pragma unroll
            for (int r = 0; r < 4; r++) accd[mt][nt][r] = 0.0;
        }

    int rA = lane & 15;
    // fragment byte offset within a 512-ushort segment, per layout
    unsigned fo;
    if (FUSED)
        fo = ((lane >> 4) << 7) + (rA << 3);                 // k-octet-major
    else
        fo = (rA << 5) + ((((lane >> 4) ^ (lane & 3))) << 3);  // row-major+XOR

    int nc = K >> 5;  // 32-K chunks

    // ---- prologue: stage chunk0 -> buf0, chunk1 -> buf1, preload P0 frags ----
#pragma unroll
    for (int i = 0; i < 6; i++) gload_lds(gseg[i], lds + lseg[i]);
#pragma unroll
    for (int i = 0; i < 6; i++) gload_lds(gseg[i] + 32, lds + BUFU + lseg[i]);
    asm volatile("s_waitcnt vmcnt(6)" ::: "memory");  // chunk 0 landed
    __builtin_amdgcn_s_barrier();

    bf16x8 Af0[4], Bf0[2], Bf1[2];
    {
        const unsigned short* Ar = lds;
        const unsigned short* Br = lds + bbase;
#pragma unroll
        for (int mt = 0; mt < 4; mt++)
            Af0[mt] = *(const bf16x8*)(Ar + (wr * 4 + mt) * 512 + fo);
#pragma unroll
        for (int nt = 0; nt < 2; nt++) {
            Bf0[nt] = *(const bf16x8*)(Br + (wc * 2 + nt) * 512 + fo);
            Bf1[nt] = *(const bf16x8*)(Br + bps + (wc * 2 + nt) * 512 + fo);
        }
    }

    int rd = 0, w2 = 2;
    for (int c = 0; c < nc; ++c) {
        const unsigned short* Ar = lds + rd * BUFU;
        const unsigned short* Br = Ar + bbase;
        unsigned short* Lw = lds + w2 * BUFU;
        const bool pf = (c + 2 < nc);
        const bool nx = (c + 1 < nc);
        int koff = (c + 2) << 5;

        bf16x8 AfN[4], AfM[4], Bf2[2];

        // ================= P0: stage(0,1); MFMA A0B0+A0B1; read A1 ============
        if (pf) {
            gload_lds(gseg[0] + koff, Lw + lseg[0]);
            gload_lds(gseg[1] + koff, Lw + lseg[1]);
        }
        if (c > 0 && (c & 1) == 0) {
#pragma unroll
            for (int mt = 0; mt < 4; mt++)
#pragma unroll
                for (int nt = 0; nt < 2; nt++)
#pragma unroll
                    for (int r = 0; r < 4; r++) {
                        accd[mt][nt][r] += (double)acc[mt][nt][r];
                        acc[mt][nt][r] = 0.f;
                    }
        }
        __builtin_amdgcn_s_barrier();
#pragma unroll
        for (int mt = 0; mt < 4; mt++)
            AfN[mt] = *(const bf16x8*)(Ar + 4096 + (wr * 4 + mt) * 512 + fo);
        __builtin_amdgcn_s_setprio(1);
#pragma unroll
        for (int mt = 0; mt < 4; mt++)
#pragma unroll
            for (int nt = 0; nt < 2; nt++) {
                f32x4 a = acc[mt][nt];
                a = __builtin_amdgcn_mfma_f32_16x16x32_bf16(Af0[mt], Bf0[nt], a, 0, 0, 0);
                a = __builtin_amdgcn_mfma_f32_16x16x32_bf16(Af0[mt], Bf1[nt], a, 0, 0, 0);
                acc[mt][nt] = a;
            }
        __builtin_amdgcn_s_setprio(0);
        __builtin_amdgcn_s_barrier();

        // ================= P1: stage(2,3); MFMA A1B0+A1B1; read A2,B2 =========
        if (pf) {
            gload_lds(gseg[2] + koff, Lw + lseg[2]);
            gload_lds(gseg[3] + koff, Lw + lseg[3]);
        }
        __builtin_amdgcn_s_barrier();
#pragma unroll
        for (int mt = 0; mt < 4; mt++)
            AfM[mt] = *(const bf16x8*)(Ar + 8192 + (wr * 4 + mt) * 512 + fo);
#pragma unroll
        for (int nt = 0; nt < 2; nt++)
            Bf2[nt] = *(const bf16x8*)(Br + 2 * bps + (wc * 2 + nt) * 512 + fo);
        __builtin_amdgcn_s_setprio(1);
#pragma unroll
        for (int mt = 0; mt < 4; mt++)
#pragma unroll
            for (int nt = 0; nt < 2; nt++) {
                f32x4 a = acc[mt][nt];
                a = __builtin_amdgcn_mfma_f32_16x16x32_bf16(AfN[mt], Bf0[nt], a, 0, 0, 0);
                a = __builtin_amdgcn_mfma_f32_16x16x32_bf16(AfN[mt], Bf1[nt], a, 0, 0, 0);
                acc[mt][nt] = a;
            }
        __builtin_amdgcn_s_setprio(0);
        __builtin_amdgcn_s_barrier();

        // ===== P2: vmcnt proves buf c+1 landed; stage(4,5); MFMA; preload P0' ==
        if (nx) {
            if (pf)
                asm volatile("s_waitcnt vmcnt(4)" ::: "memory");
            else
                asm volatile("s_waitcnt vmcnt(0)" ::: "memory");
        }
        if (pf) {
            gload_lds(gseg[4] + koff, Lw + lseg[4]);
            gload_lds(gseg[5] + koff, Lw + lseg[5]);
        }
        __builtin_amdgcn_s_barrier();
        __builtin_amdgcn_s_setprio(1);
#pragma unroll
        for (int mt = 0; mt < 4; mt++)
#pragma unroll
            for (int nt = 0; nt < 2; nt++) {
                f32x4 a = acc[mt][nt];
                a = __builtin_amdgcn_mfma_f32_16x16x32_bf16(Af0[mt], Bf2[nt], a, 0, 0, 0);
                a = __builtin_amdgcn_mfma_f32_16x16x32_bf16(AfM[mt], Bf0[nt], a, 0, 0, 0);
                acc[mt][nt] = a;
            }
        __builtin_amdgcn_s_setprio(0);
        if (nx) {  // preload next chunk's P0 operands (buffer rd+1, proven valid)
            int rdn = (rd + 1 == 3) ? 0 : rd + 1;
            const unsigned short* An = lds + rdn * BUFU;
            const unsigned short* Bn = An + bbase;
#pragma unroll
            for (int mt = 0; mt < 4; mt++)
                Af0[mt] = *(const bf16x8*)(An + (wr * 4 + mt) * 512 + fo);
#pragma unroll
            for (int nt = 0; nt < 2; nt++) {
                Bf0[nt] = *(const bf16x8*)(Bn + (wc * 2 + nt) * 512 + fo);
                Bf1[nt] = *(const bf16x8*)(Bn + bps + (wc * 2 + nt) * 512 + fo);
            }
        }
        __builtin_amdgcn_s_barrier();

        rd = (rd + 1 == 3) ? 0 : rd + 1;
        w2 = (w2 + 1 == 3) ? 0 : w2 + 1;
    }

    // final promote (last 2 chunks)
#pragma unroll
    for (int mt = 0; mt < 4; mt++)
#pragma unroll
        for (int nt = 0; nt < 2; nt++)
#pragma unroll
            for (int r = 0; r < 4; r++) accd[mt][nt][r] += (double)acc[mt][nt][r];

    if (FUSED) {
        // ---- G waves: silu(g) -> LDS; U waves: u * silu(g) -> bf16 triple ----
        // stride 68 dwords: bank = 16*(hi&1) + rA -> 2 lanes/bank (free)
        float* Gs = (float*)lds;  // [128][68] floats, ~34.8 KB
        if (grp == 0) {
#pragma unroll
            for (int mt = 0; mt < 4; mt++)
#pragma unroll
                for (int nt = 0; nt < 2; nt++) {
                    int nl = wc * 32 + nt * 16 + (lane & 15);
                    int mb = wr * 64 + mt * 16 + ((lane >> 4) << 2);
#pragma unroll
                    for (int r = 0; r < 4; r++) {
                        float vf = (float)accd[mt][nt][r];
                        Gs[(mb + r) * 68 + nl] = vf / (1.0f + expf(-vf));
                    }
                }
        }
        __syncthreads();
        if (grp == 1) {
#pragma unroll
            for (int mt = 0; mt < 4; mt++)
#pragma unroll
                for (int nt = 0; nt < 2; nt++) {
                    int nl = wc * 32 + nt * 16 + (lane & 15);
                    int mb = wr * 64 + mt * 16 + ((lane >> 4) << 2);
#pragma unroll
                    for (int r = 0; r < 4; r++) {
                        double v = accd[mt][nt][r] * (double)Gs[(mb + r) * 68 + nl];
                        size_t off = (size_t)(mblk + mb + r) * ldc + (nblk + nl);
                        unsigned short h, mm, l;
                        split3((float)v, h, mm, l);
                        C3[off] = h;
                        C3[strideC + off] = mm;
                        C3[2 * strideC + off] = l;
                    }
                }
        }
        return;
    }

    // ---- epilogue (f64), write f32 or bf16-triple ----
#pragma unroll
    for (int mt = 0; mt < 4; mt++)
#pragma unroll
        for (int nt = 0; nt < 2; nt++) {
            int n = nblk + wc * 32 + nt * 16 + (lane & 15);
            int mb = mblk + wr * 64 + mt * 16 + ((lane >> 4) << 2);
#pragma unroll
            for (int r = 0; r < 4; r++) {
                int m = mb + r;
                size_t off = (size_t)m * ldc + n;
                double v = accd[mt][nt][r];
                if (EPI == EPI_ADD) v += (double)aux[off];
                if (EPI == EPI_SILU) {
                    float vf = (float)v;
                    v = (double)(vf / (1.0f + expf(-vf)));
                }
                if (EPI == EPI_MUL) v *= (double)aux[off];
                if (EPI == EPI_BIAS) v += (double)aux[n];
                if (TRIPLE) {
                    unsigned short h, mm, l;
                    split3((float)v, h, mm, l);
                    C3[off] = h;
                    C3[strideC + off] = mm;
                    C3[2 * strideC + off] = l;
                } else {
                    Cf[off] = (float)v;
                }
            }
        }
}

// ---------------- Argmax over f32 logits (first-max tie-break) ----------------
__global__ __launch_bounds__(256) void argmax_kernel(const float* __restrict__ logits,
                                                     int* __restrict__ out_tok, int p) {
    int t = blockIdx.x;
    const float* lr = logits + (size_t)t * Vn;
    float bv = -INFINITY;
    int bi = 0x7fffffff;
    for (int j = threadIdx.x; j < Vn; j += 256) {
        float v = lr[j];
        if (v > bv || (v == bv && j < bi)) {
            bv = v;
            bi = j;
        }
    }
#pragma unroll
    for (int o = 1; o < 64; o <<= 1) {
        float ov = __shfl_xor(bv, o, 64);
        int oi = __shfl_xor(bi, o, 64);
        if (ov > bv || (ov == bv && oi < bi)) {
            bv = ov;
            bi = oi;
        }
    }
    __shared__ float sv[4];
    __shared__ int si[4];
    if ((threadIdx.x & 63) == 0) {
        sv[threadIdx.x >> 6] = bv;
        si[threadIdx.x >> 6] = bi;
    }
    __syncthreads();
    if (threadIdx.x == 0) {
        for (int w = 1; w < 4; w++) {
            if (sv[w] > bv || (sv[w] == bv && si[w] < bi)) {
                bv = sv[w];
                bi = si[w];
            }
        }
        out_tok[(size_t)t * NSTEPSn + p] = bi;
    }
}

// ---------------- Embedding gather ----------------
__global__ __launch_bounds__(256) void embed_kernel(const float* __restrict__ E,
                                                    const int* __restrict__ toks,
                                                    float* __restrict__ x, int p) {
    int t = blockIdx.x;
    int tok = toks[(size_t)t * NSTEPSn + p];
    float4 v = ((const float4*)(E + (size_t)tok * Hn))[threadIdx.x];
    ((float4*)(x + (size_t)t * Hn))[threadIdx.x] = v;
}

extern "C" void kernel_launch(void* const* d_in, const int* in_sizes, int n_in,
                              void* d_out, int out_size, void* d_ws, size_t ws_size,
                              hipStream_t stream) {
    const float* x0 = (const float*)d_in[0];
    const float* Wq = (const float*)d_in[1];
    const float* Wk = (const float*)d_in[2];
    const float* Wv = (const float*)d_in[3];
    const float* Wo = (const float*)d_in[4];
    const float* Wg = (const float*)d_in[5];
    const float* Wu = (const float*)d_in[6];
    const float* Wd = (const float*)d_in[7];
    const float* n1 = (const float*)d_in[8];
    const float* n2 = (const float*)d_in[9];
    const float* Emb = (const float*)d_in[10];
    const float* Wout = (const float*)d_in[11];
    const float* bout = (const float*)d_in[12];
    int* toks = (int*)d_out;

    float* ws = (float*)d_ws;
    const size_t M1 = 1024 * 1024;
    float* EK = ws;                  // V x H fp32           4MB
    float* EV = ws + 1 * M1;         //                      4MB
    float* K0 = ws + 2 * M1;         // T x H fp32           16MB
    float* V0 = ws + 6 * M1;         //                      16MB
    float* xb = ws + 10 * M1;        // residual hidden      16MB
    float* qb = ws + 14 * M1;        // q / MLP acc / logits 16MB
    float* Gc = ws + 18 * M1;        // (free since GU fuse) 16MB
    unsigned short* s3a = (unsigned short*)(ws + 22 * M1);  // triple TxH  24MB
    unsigned short* s3g = (unsigned short*)(ws + 28 * M1);  // triple TxH  24MB
    double2* tab = (double2*)(ws + 34 * M1);                // 256 double2  4KB
    unsigned short* W3q = (unsigned short*)(ws + 34 * M1 + 1024);  // 6MB
    unsigned short* W3k = W3q + 3 * M1;                            // 6MB
    unsigned short* W3v = W3k + 3 * M1;                            // 6MB
    unsigned short* W3o = W3v + 3 * M1;                            // 6MB
    unsigned short* W3t = W3o + 3 * M1;  // Wout                     6MB
    unsigned short* W3g = W3t + 3 * M1;                            // 24MB
    unsigned short* W3u = W3g + 12 * M1;                           // 24MB
    unsigned short* W3d = W3u + 12 * M1;                           // 24MB
    // total ~= 238 MB

    const size_t STH = (size_t)Tn * Hn;  // plane stride, T x 1024 triples
    const size_t SVH = (size_t)Vn * Hn;  // plane stride, V x H triple
    const size_t SW1 = M1;               // plane stride, 1M-element weights
    const size_t SW4 = 4 * M1;           // plane stride, 4M-element weights
    (void)Gc;

    dim3 blk(256);
    dim3 gblk(512);
    const int gTH = 256;  // (M/128=32) x (N/128=8), 1D swizzled
    const int gVH = 64;   // (M/128=8)  x 8
    const int gGU = 512;  // (M/128=32) x (N/64=16), fused G+U

    // ---- One-time precompute ----
    rope_tab_kernel<<<1, 256, 0, stream>>>(tab);
    presplit_kernel<<<dim3(16, 16), blk, 0, stream>>>(Wq, W3q, Hn, Hn);
    presplit_kernel<<<dim3(16, 16), blk, 0, stream>>>(Wk, W3k, Hn, Hn);
    presplit_kernel<<<dim3(16, 16), blk, 0, stream>>>(Wv, W3v, Hn, Hn);
    presplit_kernel<<<dim3(16, 16), blk, 0, stream>>>(Wo, W3o, Hn, Hn);
    presplit_kernel<<<dim3(16, 16), blk, 0, stream>>>(Wout, W3t, Hn, Vn);
    presplit_kernel<<<dim3(In / 64, Hn / 64), blk, 0, stream>>>(Wg, W3g, Hn, In);
    presplit_kernel<<<dim3(In / 64, Hn / 64), blk, 0, stream>>>(Wu, W3u, Hn, In);
    presplit_kernel<<<dim3(Hn / 64, In / 64), blk, 0, stream>>>(Wd, W3d, In, Hn);
    rmsnorm3_kernel<<<Vn, 256, 0, stream>>>(Emb, n1, s3a, SVH);
    gemm3_kernel<EPI_NONE, false, false><<<gVH, gblk, 0, stream>>>(
        s3a, SVH, W3k, nullptr, SW1, Hn, EK, nullptr, 0, nullptr, Hn, Hn);
    gemm3_kernel<EPI_NONE, false, false><<<gVH, gblk, 0, stream>>>(
        s3a, SVH, W3v, nullptr, SW1, Hn, EV, nullptr, 0, nullptr, Hn, Hn);

    for (int p = 0; p < NSTEPSn; p++) {
        const float* src = (p == 0) ? x0 : xb;

        rmsnorm3_kernel<<<Tn, 256, 0, stream>>>(src, n1, s3a, STH);
        gemm3_kernel<EPI_NONE, false, false><<<gTH, gblk, 0, stream>>>(
            s3a, STH, W3q, nullptr, SW1, Hn, qb, nullptr, 0, nullptr, Hn, Hn);
        if (p == 0) {
            gemm3_kernel<EPI_NONE, false, false><<<gTH, gblk, 0, stream>>>(
                s3a, STH, W3k, nullptr, SW1, Hn, K0, nullptr, 0, nullptr, Hn, Hn);
            gemm3_kernel<EPI_NONE, false, false><<<gTH, gblk, 0, stream>>>(
                s3a, STH, W3v, nullptr, SW1, Hn, V0, nullptr, 0, nullptr, Hn, Hn);
        }
        attn_kernel<<<(Tn * NHn) / 4, 256, 0, stream>>>(qb, K0, V0, EK, EV, toks,
                                                        tab, s3a, STH, p);
        // h2 = ctx @ Wo + src  (in-place into xb when src == xb)
        gemm3_kernel<EPI_ADD, false, false><<<gTH, gblk, 0, stream>>>(
            s3a, STH, W3o, nullptr, SW1, Hn, xb, nullptr, 0, src, Hn, Hn);
        rmsnorm3_kernel<<<Tn, 256, 0, stream>>>(xb, n2, s3a, STH);
        // Gated MLP, chunked over I (4 x 1024): fused silu(x@Wg)*(x@Wu) -> s3g,
        // then chunk-accumulated @Wd into qb.
        for (int c = 0; c < 4; c++) {
            gemm3_kernel<EPI_NONE, true, true><<<gGU, gblk, 0, stream>>>(
                s3a, STH, W3g + (size_t)c * M1, W3u + (size_t)c * M1, SW4, Hn,
                nullptr, s3g, STH, nullptr, Hn, 1024);
            if (c < 3) {
                gemm3_kernel<EPI_ADD, false, false><<<gTH, gblk, 0, stream>>>(
                    s3g, STH, W3d + (size_t)c * 1024, nullptr, SW4, In,
                    qb, nullptr, 0, (c == 0) ? xb : qb, Hn, Hn);
            } else {
                gemm3_kernel<EPI_ADD, true, false><<<gTH, gblk, 0, stream>>>(
                    s3g, STH, W3d + (size_t)c * 1024, nullptr, SW4, In,
                    nullptr, s3a, STH, qb, Hn, Hn);
            }
        }
        // logits = out @ Wout + bout  (into qb)
        gemm3_kernel<EPI_BIAS, false, false><<<gTH, gblk, 0, stream>>>(
            s3a, STH, W3t, nullptr, SW1, Hn, qb, nullptr, 0, bout, Hn, Vn);
        argmax_kernel<<<Tn, 256, 0, stream>>>(qb, toks, p);
        if (p < NSTEPSn - 1) embed_kernel<<<Tn, 256, 0, stream>>>(Emb, toks, xb, p);
    }
}

// Round 5
// 7845.415 us; speedup vs baseline: 1.0127x; 1.0003x over previous
//
#include <hip/hip_runtime.h>
#include <cmath>

#define Tn 4096
#define Hn 1024
#define NHn 16
#define HDn 64
#define In 4096
#define Vn 1024
#define NSTEPSn 8

enum { EPI_NONE = 0, EPI_ADD = 1, EPI_SILU = 2, EPI_MUL = 3, EPI_BIAS = 4 };

typedef __attribute__((ext_vector_type(8))) short bf16x8;
typedef __attribute__((ext_vector_type(4))) float f32x4;

__device__ inline unsigned short bf16rne(float x) {
    unsigned int u = __float_as_uint(x);
    u += 0x7fff + ((u >> 16) & 1);
    return (unsigned short)(u >> 16);
}
__device__ inline float bf2f(unsigned short h) {
    return __uint_as_float(((unsigned int)h) << 16);
}
__device__ inline void split3(float x, unsigned short& h, unsigned short& m,
                              unsigned short& l) {
    h = bf16rne(x);
    float r = x - bf2f(h);
    m = bf16rne(r);
    float r2 = r - bf2f(m);
    l = bf16rne(r2);
}

// Async global->LDS, 16B per lane (wave-uniform LDS base; HW scatters lane*16).
__device__ __forceinline__ void gload_lds(const unsigned short* g,
                                          const unsigned short* l) {
    __builtin_amdgcn_global_load_lds(
        (const __attribute__((address_space(1))) unsigned int*)(uintptr_t)g,
        (__attribute__((address_space(3))) unsigned int*)(unsigned int)(uintptr_t)l,
        16, 0, 0);
}

// ---------------- RoPE cos/sin table ----------------
__global__ void rope_tab_kernel(double2* __restrict__ tab) {
    int tid = threadIdx.x;  // 256 threads
    int j = tid >> 5, i = tid & 31;
    double inv = exp(-((double)(2 * i) * (1.0 / (double)HDn)) * 9.210340371976184);
    double ang = (double)j * inv;
    double2 cs;
    cs.x = cos(ang);
    cs.y = sin(ang);
    tab[tid] = cs;
}

// ---------------- Weight pre-split: W[K][N] fp32 -> W3[3][N][K] bf16 ----------------
__global__ __launch_bounds__(256) void presplit_kernel(const float* __restrict__ W,
                                                       unsigned short* __restrict__ W3,
                                                       int K, int N) {
    __shared__ float S[64][65];
    int k0 = blockIdx.y * 64, n0 = blockIdx.x * 64;
    int tid = threadIdx.x;
#pragma unroll
    for (int r = 0; r < 4; r++) {
        int idx = tid + r * 256;
        int kr = idx >> 4, c4 = (idx & 15) << 2;
        float4 v = *(const float4*)(W + (size_t)(k0 + kr) * N + n0 + c4);
        S[kr][c4] = v.x;
        S[kr][c4 + 1] = v.y;
        S[kr][c4 + 2] = v.z;
        S[kr][c4 + 3] = v.w;
    }
    __syncthreads();
    size_t PS = (size_t)N * K;
#pragma unroll
    for (int r = 0; r < 4; r++) {
        int idx = tid + r * 256;
        int kq = idx & 15, n = idx >> 4;
        ushort4 hq, mq, lq;
        split3(S[4 * kq + 0][n], hq.x, mq.x, lq.x);
        split3(S[4 * kq + 1][n], hq.y, mq.y, lq.y);
        split3(S[4 * kq + 2][n], hq.z, mq.z, lq.z);
        split3(S[4 * kq + 3][n], hq.w, mq.w, lq.w);
        size_t off = (size_t)(n0 + n) * K + k0 + 4 * kq;
        *(ushort4*)(W3 + off) = hq;
        *(ushort4*)(W3 + PS + off) = mq;
        *(ushort4*)(W3 + 2 * PS + off) = lq;
    }
}

// ---------------- RMSNorm -> bf16 triple planes (f64 math) ----------------
__global__ __launch_bounds__(256) void rmsnorm3_kernel(const float* __restrict__ x,
                                                       const float* __restrict__ w,
                                                       unsigned short* __restrict__ y3,
                                                       size_t stride) {
    int t = blockIdx.x;
    const float4* xr = (const float4*)(x + (size_t)t * Hn);
    float4 v = xr[threadIdx.x];
    double ss = (double)v.x * v.x + (double)v.y * v.y + (double)v.z * v.z + (double)v.w * v.w;
#pragma unroll
    for (int o = 1; o < 64; o <<= 1) ss += __shfl_xor(ss, o, 64);
    __shared__ double red[4];
    if ((threadIdx.x & 63) == 0) red[threadIdx.x >> 6] = ss;
    __syncthreads();
    double tot = red[0] + red[1] + red[2] + red[3];
    double rs = 1.0 / sqrt(tot * (1.0 / Hn) + 1e-6);
    const float4* wr = (const float4*)w;
    float4 wv = wr[threadIdx.x];
    float o[4];
    o[0] = (float)((double)v.x * rs * (double)wv.x);
    o[1] = (float)((double)v.y * rs * (double)wv.y);
    o[2] = (float)((double)v.z * rs * (double)wv.z);
    o[3] = (float)((double)v.w * rs * (double)wv.w);
    ushort4 hq, mq, lq;
    split3(o[0], hq.x, mq.x, lq.x);
    split3(o[1], hq.y, mq.y, lq.y);
    split3(o[2], hq.z, mq.z, lq.z);
    split3(o[3], hq.w, mq.w, lq.w);
    size_t off = (size_t)t * Hn + threadIdx.x * 4;
    *(ushort4*)(y3 + off) = hq;
    *(ushort4*)(y3 + stride + off) = mq;
    *(ushort4*)(y3 + 2 * stride + off) = lq;
}

// ---------------- Attention (f64 dot, table RoPE, f32 exp), out bf16 triple ----
// Fully unrolled over NSTEPS with uniform (j<=p) guards: all per-j arrays are
// statically indexed (registers, not scratch), and tok/EK/EV/cs loads are
// hoisted into independent batches so they overlap. Arithmetic order is
// bit-identical to the previous (verified) kernel.
__global__ __launch_bounds__(256) void attn_kernel(const float* __restrict__ q,
                                                   const float* __restrict__ K0,
                                                   const float* __restrict__ V0,
                                                   const float* __restrict__ EK,
                                                   const float* __restrict__ EV,
                                                   const int* __restrict__ toks,
                                                   const double2* __restrict__ tab,
                                                   unsigned short* __restrict__ ctx3,
                                                   size_t stride, int p) {
    int wave = blockIdx.x * 4 + (threadIdx.x >> 6);  // t*NH + head
    int lane = threadIdx.x & 63;
    int t = wave >> 4;
    int col = ((wave & 15) << 6) | lane;
    int i = lane & 31;
    int half = lane >> 5;
    size_t base = (size_t)wave * HDn + lane;

    double2 csp = tab[p * 32 + i];
    double qv = (double)q[base];
    double qpart = __shfl_xor(qv, 32, 64);
    double qr = half ? (qv * csp.x + qpart * csp.y) : (qv * csp.x - qpart * csp.y);

    // ---- hoisted independent loads ----
    int tk[NSTEPSn];
    double kv[NSTEPSn], vv[NSTEPSn];
    double2 cs[NSTEPSn];
    tk[0] = 0;
    kv[0] = (double)K0[base];
    vv[0] = (double)V0[base];
#pragma unroll
    for (int j = 1; j < NSTEPSn; j++)
        if (j <= p) tk[j] = toks[(size_t)t * NSTEPSn + (j - 1)];
#pragma unroll
    for (int j = 1; j < NSTEPSn; j++)
        if (j <= p) {
            kv[j] = (double)EK[(size_t)tk[j] * Hn + col];
            vv[j] = (double)EV[(size_t)tk[j] * Hn + col];
            cs[j] = tab[j * 32 + i];
        }

    double sc[NSTEPSn];
    double m = -1e300;
#pragma unroll
    for (int j = 0; j < NSTEPSn; j++)
        if (j <= p) {
            double kr;
            if (j == 0) {
                kr = kv[0];
            } else {
                double kpart = __shfl_xor(kv[j], 32, 64);
                kr = half ? (kv[j] * cs[j].x + kpart * cs[j].y)
                          : (kv[j] * cs[j].x - kpart * cs[j].y);
            }
            double pr = qr * kr;
#pragma unroll
            for (int o = 1; o < 64; o <<= 1) pr += __shfl_xor(pr, o, 64);
            sc[j] = pr * 0.125;
            m = fmax(m, sc[j]);
        }
    double den = 0.0;
#pragma unroll
    for (int j = 0; j < NSTEPSn; j++)
        if (j <= p) {
            sc[j] = (double)expf((float)(sc[j] - m));
            den += sc[j];
        }
    double invd = 1.0 / den;
    double acc = 0.0;
#pragma unroll
    for (int j = 0; j < NSTEPSn; j++)
        if (j <= p) acc += sc[j] * vv[j];

    unsigned short h, mm, l;
    split3((float)(acc * invd), h, mm, l);
    ctx3[base] = h;
    ctx3[stride + base] = mm;
    ctx3[2 * stride + base] = l;
}

// ---------------- bf16x3 MFMA GEMM: 128x128 tile, 8 waves, 3-buffer pipeline ----
// C(M x N) = A(M x K) @ B(K x N). A planes [3][M][K], B planes [3][N][K].
// Row-major cells + quad-XOR staging (coalesced 64B row-slices per 4 lanes).
// Pipeline: 3 phases/chunk; phase p+1 ds_reads issue inside phase p's MFMA
// region; counted vmcnt(4) in P2 proves buffer c+1 landed; never vmcnt(0) in
// steady state. MFMA product order and f64 promote cadence bit-identical.
// (FUSED variant retained in source but no longer instantiated — measured a
// per-unit loss vs two separate passes of this kernel.)
#define BUFU 24576  // ushorts per buffer: 48KB (A 24KB + B 24KB)
template <int EPI, bool TRIPLE, bool FUSED>
__global__ __launch_bounds__(512, 2) void gemm3_kernel(
    const unsigned short* __restrict__ A3, size_t strideA,
    const unsigned short* __restrict__ B3, const unsigned short* __restrict__ BU3,
    size_t strideB, int ldbk,
    float* Cf, unsigned short* C3, size_t strideC,
    const float* aux, int K, int ldc) {
    __shared__ __align__(16) unsigned short lds[3 * BUFU];  // 144 KB

    int tid = threadIdx.x;
    int wv = tid >> 6, lane = tid & 63;
    int wr, wc, grp;
    if (FUSED) {
        grp = wv >> 2;          // 0 = G, 1 = U
        wr = (wv >> 1) & 1;     // 2 m-groups of 64
        wc = wv & 1;            // 2 n-groups of 32 (64-col tile)
    } else {
        grp = 0;
        wr = wv >> 2;           // 2 m-groups of 64
        wc = wv & 3;            // 4 n-groups of 32 (128-col tile)
    }

    // ---- XCD swizzle ----
    int f = blockIdx.x;
    int xcd = f & 7;
    int j = f >> 3;
    int mblk, nblk;
    if (FUSED) {
        int bmPer = gridDim.x >> 7;  // GN=16 (64-col blocks)
        mblk = (xcd * bmPer + (j >> 4)) * 128;
        nblk = (j & 15) * 64;
    } else {
        int bmPer = gridDim.x >> 6;  // GN=8 (128-col blocks)
        mblk = (xcd * bmPer + (j >> 3)) * 128;
        nblk = (j & 7) * 128;
    }

    // ---- staging segments: 48 x 1KB, each wave owns 6 (2 per phase) ----
    int rsel, csel;
    if (FUSED) {
        // k-octet-major: lane l sources (row = sub*16 + (l&15), oct = l>>4)
        rsel = lane & 15;
        csel = (lane >> 4) << 3;
    } else {
        // row-major+quad-XOR: lanes 4q..4q+3 cover one 64B row-slice
        rsel = lane >> 2;
        csel = ((lane & 3) ^ ((lane >> 2) & 3)) << 3;
    }
    const unsigned short* gseg[6];
    unsigned lseg[6];
#pragma unroll
    for (int i = 0; i < 6; i++) {
        int s = wv * 6 + i;
        if (s < 24) {
            int pl = s >> 3, sub = s & 7;
            gseg[i] = A3 + (size_t)pl * strideA +
                      (size_t)(mblk + sub * 16 + rsel) * K + csel;
            lseg[i] = pl * 4096 + sub * 512;
        } else if (!FUSED) {
            int u = s - 24;
            int pl = u >> 3, sub = u & 7;
            gseg[i] = B3 + (size_t)pl * strideB +
                      (size_t)(nblk + sub * 16 + rsel) * ldbk + csel;
            lseg[i] = 12288 + pl * 4096 + sub * 512;
        } else {
            int u = s - 24;
            const unsigned short* Bp = (u < 12) ? B3 : BU3;
            int v = (u < 12) ? u : u - 12;
            int pl = v >> 2, sub = v & 3;
            gseg[i] = Bp + (size_t)pl * strideB +
                      (size_t)(nblk + sub * 16 + rsel) * ldbk + csel;
            lseg[i] = 12288 + ((u < 12) ? 0 : 6144) + pl * 2048 + sub * 512;
        }
    }

    const int bbase = 12288 + (FUSED ? grp * 6144 : 0);
    const int bps = FUSED ? 2048 : 4096;  // LDS plane stride in B region

    f32x4 acc[4][2];
    double accd[4][2][4];
#pragma unroll
    for (int mt = 0; mt < 4; mt++)
#pragma unroll
        for (int nt = 0; nt < 2; nt++) {
            acc[mt][nt] = (f32x4){0.f, 0.f, 0.f, 0.f};
#pragma unroll
            for (int r = 0; r < 4; r++) accd[mt][nt][r] = 0.0;
        }

    int rA = lane & 15;
    // fragment byte offset within a 512-ushort segment, per layout
    unsigned fo;
    if (FUSED)
        fo = ((lane >> 4) << 7) + (rA << 3);                 // k-octet-major
    else
        fo = (rA << 5) + ((((lane >> 4) ^ (lane & 3))) << 3);  // row-major+XOR

    int nc = K >> 5;  // 32-K chunks

    // ---- prologue: stage chunk0 -> buf0, chunk1 -> buf1, preload P0 frags ----
#pragma unroll
    for (int i = 0; i < 6; i++) gload_lds(gseg[i], lds + lseg[i]);
#pragma unroll
    for (int i = 0; i < 6; i++) gload_lds(gseg[i] + 32, lds + BUFU + lseg[i]);
    asm volatile("s_waitcnt vmcnt(6)" ::: "memory");  // chunk 0 landed
    __builtin_amdgcn_s_barrier();

    bf16x8 Af0[4], Bf0[2], Bf1[2];
    {
        const unsigned short* Ar = lds;
        const unsigned short* Br = lds + bbase;
#pragma unroll
        for (int mt = 0; mt < 4; mt++)
            Af0[mt] = *(const bf16x8*)(Ar + (wr * 4 + mt) * 512 + fo);
#pragma unroll
        for (int nt = 0; nt < 2; nt++) {
            Bf0[nt] = *(const bf16x8*)(Br + (wc * 2 + nt) * 512 + fo);
            Bf1[nt] = *(const bf16x8*)(Br + bps + (wc * 2 + nt) * 512 + fo);
        }
    }

    int rd = 0, w2 = 2;
    for (int c = 0; c < nc; ++c) {
        const unsigned short* Ar = lds + rd * BUFU;
        const unsigned short* Br = Ar + bbase;
        unsigned short* Lw = lds + w2 * BUFU;
        const bool pf = (c + 2 < nc);
        const bool nx = (c + 1 < nc);
        int koff = (c + 2) << 5;

        bf16x8 AfN[4], AfM[4], Bf2[2];

        // ================= P0: stage(0,1); MFMA A0B0+A0B1; read A1 ============
        if (pf) {
            gload_lds(gseg[0] + koff, Lw + lseg[0]);
            gload_lds(gseg[1] + koff, Lw + lseg[1]);
        }
        if (c > 0 && (c & 1) == 0) {
#pragma unroll
            for (int mt = 0; mt < 4; mt++)
#pragma unroll
                for (int nt = 0; nt < 2; nt++)
#pragma unroll
                    for (int r = 0; r < 4; r++) {
                        accd[mt][nt][r] += (double)acc[mt][nt][r];
                        acc[mt][nt][r] = 0.f;
                    }
        }
        __builtin_amdgcn_s_barrier();
#pragma unroll
        for (int mt = 0; mt < 4; mt++)
            AfN[mt] = *(const bf16x8*)(Ar + 4096 + (wr * 4 + mt) * 512 + fo);
        __builtin_amdgcn_s_setprio(1);
#pragma unroll
        for (int mt = 0; mt < 4; mt++)
#pragma unroll
            for (int nt = 0; nt < 2; nt++) {
                f32x4 a = acc[mt][nt];
                a = __builtin_amdgcn_mfma_f32_16x16x32_bf16(Af0[mt], Bf0[nt], a, 0, 0, 0);
                a = __builtin_amdgcn_mfma_f32_16x16x32_bf16(Af0[mt], Bf1[nt], a, 0, 0, 0);
                acc[mt][nt] = a;
            }
        __builtin_amdgcn_s_setprio(0);
        __builtin_amdgcn_s_barrier();

        // ================= P1: stage(2,3); MFMA A1B0+A1B1; read A2,B2 =========
        if (pf) {
            gload_lds(gseg[2] + koff, Lw + lseg[2]);
            gload_lds(gseg[3] + koff, Lw + lseg[3]);
        }
        __builtin_amdgcn_s_barrier();
#pragma unroll
        for (int mt = 0; mt < 4; mt++)
            AfM[mt] = *(const bf16x8*)(Ar + 8192 + (wr * 4 + mt) * 512 + fo);
#pragma unroll
        for (int nt = 0; nt < 2; nt++)
            Bf2[nt] = *(const bf16x8*)(Br + 2 * bps + (wc * 2 + nt) * 512 + fo);
        __builtin_amdgcn_s_setprio(1);
#pragma unroll
        for (int mt = 0; mt < 4; mt++)
#pragma unroll
            for (int nt = 0; nt < 2; nt++) {
                f32x4 a = acc[mt][nt];
                a = __builtin_amdgcn_mfma_f32_16x16x32_bf16(AfN[mt], Bf0[nt], a, 0, 0, 0);
                a = __builtin_amdgcn_mfma_f32_16x16x32_bf16(AfN[mt], Bf1[nt], a, 0, 0, 0);
                acc[mt][nt] = a;
            }
        __builtin_amdgcn_s_setprio(0);
        __builtin_amdgcn_s_barrier();

        // ===== P2: vmcnt proves buf c+1 landed; stage(4,5); MFMA; preload P0' ==
        if (nx) {
            if (pf)
                asm volatile("s_waitcnt vmcnt(4)" ::: "memory");
            else
                asm volatile("s_waitcnt vmcnt(0)" ::: "memory");
        }
        if (pf) {
            gload_lds(gseg[4] + koff, Lw + lseg[4]);
            gload_lds(gseg[5] + koff, Lw + lseg[5]);
        }
        __builtin_amdgcn_s_barrier();
        __builtin_amdgcn_s_setprio(1);
#pragma unroll
        for (int mt = 0; mt < 4; mt++)
#pragma unroll
            for (int nt = 0; nt < 2; nt++) {
                f32x4 a = acc[mt][nt];
                a = __builtin_amdgcn_mfma_f32_16x16x32_bf16(Af0[mt], Bf2[nt], a, 0, 0, 0);
                a = __builtin_amdgcn_mfma_f32_16x16x32_bf16(AfM[mt], Bf0[nt], a, 0, 0, 0);
                acc[mt][nt] = a;
            }
        __builtin_amdgcn_s_setprio(0);
        if (nx) {  // preload next chunk's P0 operands (buffer rd+1, proven valid)
            int rdn = (rd + 1 == 3) ? 0 : rd + 1;
            const unsigned short* An = lds + rdn * BUFU;
            const unsigned short* Bn = An + bbase;
#pragma unroll
            for (int mt = 0; mt < 4; mt++)
                Af0[mt] = *(const bf16x8*)(An + (wr * 4 + mt) * 512 + fo);
#pragma unroll
            for (int nt = 0; nt < 2; nt++) {
                Bf0[nt] = *(const bf16x8*)(Bn + (wc * 2 + nt) * 512 + fo);
                Bf1[nt] = *(const bf16x8*)(Bn + bps + (wc * 2 + nt) * 512 + fo);
            }
        }
        __builtin_amdgcn_s_barrier();

        rd = (rd + 1 == 3) ? 0 : rd + 1;
        w2 = (w2 + 1 == 3) ? 0 : w2 + 1;
    }

    // final promote (last 2 chunks)
#pragma unroll
    for (int mt = 0; mt < 4; mt++)
#pragma unroll
        for (int nt = 0; nt < 2; nt++)
#pragma unroll
            for (int r = 0; r < 4; r++) accd[mt][nt][r] += (double)acc[mt][nt][r];

    if (FUSED) {
        // ---- G waves: silu(g) -> LDS; U waves: u * silu(g) -> bf16 triple ----
        float* Gs = (float*)lds;  // [128][68] floats
        if (grp == 0) {
#pragma unroll
            for (int mt = 0; mt < 4; mt++)
#pragma unroll
                for (int nt = 0; nt < 2; nt++) {
                    int nl = wc * 32 + nt * 16 + (lane & 15);
                    int mb = wr * 64 + mt * 16 + ((lane >> 4) << 2);
#pragma unroll
                    for (int r = 0; r < 4; r++) {
                        float vf = (float)accd[mt][nt][r];
                        Gs[(mb + r) * 68 + nl] = vf / (1.0f + expf(-vf));
                    }
                }
        }
        __syncthreads();
        if (grp == 1) {
#pragma unroll
            for (int mt = 0; mt < 4; mt++)
#pragma unroll
                for (int nt = 0; nt < 2; nt++) {
                    int nl = wc * 32 + nt * 16 + (lane & 15);
                    int mb = wr * 64 + mt * 16 + ((lane >> 4) << 2);
#pragma unroll
                    for (int r = 0; r < 4; r++) {
                        double v = accd[mt][nt][r] * (double)Gs[(mb + r) * 68 + nl];
                        size_t off = (size_t)(mblk + mb + r) * ldc + (nblk + nl);
                        unsigned short h, mm, l;
                        split3((float)v, h, mm, l);
                        C3[off] = h;
                        C3[strideC + off] = mm;
                        C3[2 * strideC + off] = l;
                    }
                }
        }
        return;
    }

    // ---- epilogue (f64), write f32 or bf16-triple ----
#pragma unroll
    for (int mt = 0; mt < 4; mt++)
#pragma unroll
        for (int nt = 0; nt < 2; nt++) {
            int n = nblk + wc * 32 + nt * 16 + (lane & 15);
            int mb = mblk + wr * 64 + mt * 16 + ((lane >> 4) << 2);
#pragma unroll
            for (int r = 0; r < 4; r++) {
                int m = mb + r;
                size_t off = (size_t)m * ldc + n;
                double v = accd[mt][nt][r];
                if (EPI == EPI_ADD) v += (double)aux[off];
                if (EPI == EPI_SILU) {
                    float vf = (float)v;
                    v = (double)(vf / (1.0f + expf(-vf)));
                }
                if (EPI == EPI_MUL) v *= (double)aux[off];
                if (EPI == EPI_BIAS) v += (double)aux[n];
                if (TRIPLE) {
                    unsigned short h, mm, l;
                    split3((float)v, h, mm, l);
                    C3[off] = h;
                    C3[strideC + off] = mm;
                    C3[2 * strideC + off] = l;
                } else {
                    Cf[off] = (float)v;
                }
            }
        }
}

// ---------------- Argmax over f32 logits (first-max tie-break) ----------------
__global__ __launch_bounds__(256) void argmax_kernel(const float* __restrict__ logits,
                                                     int* __restrict__ out_tok, int p) {
    int t = blockIdx.x;
    const float* lr = logits + (size_t)t * Vn;
    float bv = -INFINITY;
    int bi = 0x7fffffff;
    for (int j = threadIdx.x; j < Vn; j += 256) {
        float v = lr[j];
        if (v > bv || (v == bv && j < bi)) {
            bv = v;
            bi = j;
        }
    }
#pragma unroll
    for (int o = 1; o < 64; o <<= 1) {
        float ov = __shfl_xor(bv, o, 64);
        int oi = __shfl_xor(bi, o, 64);
        if (ov > bv || (ov == bv && oi < bi)) {
            bv = ov;
            bi = oi;
        }
    }
    __shared__ float sv[4];
    __shared__ int si[4];
    if ((threadIdx.x & 63) == 0) {
        sv[threadIdx.x >> 6] = bv;
        si[threadIdx.x >> 6] = bi;
    }
    __syncthreads();
    if (threadIdx.x == 0) {
        for (int w = 1; w < 4; w++) {
            if (sv[w] > bv || (sv[w] == bv && si[w] < bi)) {
                bv = sv[w];
                bi = si[w];
            }
        }
        out_tok[(size_t)t * NSTEPSn + p] = bi;
    }
}

// ---------------- Embedding gather ----------------
__global__ __launch_bounds__(256) void embed_kernel(const float* __restrict__ E,
                                                    const int* __restrict__ toks,
                                                    float* __restrict__ x, int p) {
    int t = blockIdx.x;
    int tok = toks[(size_t)t * NSTEPSn + p];
    float4 v = ((const float4*)(E + (size_t)tok * Hn))[threadIdx.x];
    ((float4*)(x + (size_t)t * Hn))[threadIdx.x] = v;
}

extern "C" void kernel_launch(void* const* d_in, const int* in_sizes, int n_in,
                              void* d_out, int out_size, void* d_ws, size_t ws_size,
                              hipStream_t stream) {
    const float* x0 = (const float*)d_in[0];
    const float* Wq = (const float*)d_in[1];
    const float* Wk = (const float*)d_in[2];
    const float* Wv = (const float*)d_in[3];
    const float* Wo = (const float*)d_in[4];
    const float* Wg = (const float*)d_in[5];
    const float* Wu = (const float*)d_in[6];
    const float* Wd = (const float*)d_in[7];
    const float* n1 = (const float*)d_in[8];
    const float* n2 = (const float*)d_in[9];
    const float* Emb = (const float*)d_in[10];
    const float* Wout = (const float*)d_in[11];
    const float* bout = (const float*)d_in[12];
    int* toks = (int*)d_out;

    float* ws = (float*)d_ws;
    const size_t M1 = 1024 * 1024;
    float* EK = ws;                  // V x H fp32           4MB
    float* EV = ws + 1 * M1;         //                      4MB
    float* K0 = ws + 2 * M1;         // T x H fp32           16MB
    float* V0 = ws + 6 * M1;         //                      16MB
    float* xb = ws + 10 * M1;        // residual hidden      16MB
    float* qb = ws + 14 * M1;        // q / MLP acc / logits 16MB
    float* Gc = ws + 18 * M1;        // silu chunk fp32      16MB
    unsigned short* s3a = (unsigned short*)(ws + 22 * M1);  // triple TxH  24MB
    unsigned short* s3g = (unsigned short*)(ws + 28 * M1);  // triple TxH  24MB
    double2* tab = (double2*)(ws + 34 * M1);                // 256 double2  4KB
    unsigned short* W3q = (unsigned short*)(ws + 34 * M1 + 1024);  // 6MB
    unsigned short* W3k = W3q + 3 * M1;                            // 6MB
    unsigned short* W3v = W3k + 3 * M1;                            // 6MB
    unsigned short* W3o = W3v + 3 * M1;                            // 6MB
    unsigned short* W3t = W3o + 3 * M1;  // Wout                     6MB
    unsigned short* W3g = W3t + 3 * M1;                            // 24MB
    unsigned short* W3u = W3g + 12 * M1;                           // 24MB
    unsigned short* W3d = W3u + 12 * M1;                           // 24MB
    // total ~= 238 MB

    const size_t STH = (size_t)Tn * Hn;  // plane stride, T x 1024 triples
    const size_t SVH = (size_t)Vn * Hn;  // plane stride, V x H triple
    const size_t SW1 = M1;               // plane stride, 1M-element weights
    const size_t SW4 = 4 * M1;           // plane stride, 4M-element weights

    dim3 blk(256);
    dim3 gblk(512);
    const int gTH = 256;  // (M/128=32) x (N/128=8), 1D swizzled
    const int gVH = 64;   // (M/128=8)  x 8

    // ---- One-time precompute ----
    rope_tab_kernel<<<1, 256, 0, stream>>>(tab);
    presplit_kernel<<<dim3(16, 16), blk, 0, stream>>>(Wq, W3q, Hn, Hn);
    presplit_kernel<<<dim3(16, 16), blk, 0, stream>>>(Wk, W3k, Hn, Hn);
    presplit_kernel<<<dim3(16, 16), blk, 0, stream>>>(Wv, W3v, Hn, Hn);
    presplit_kernel<<<dim3(16, 16), blk, 0, stream>>>(Wo, W3o, Hn, Hn);
    presplit_kernel<<<dim3(16, 16), blk, 0, stream>>>(Wout, W3t, Hn, Vn);
    presplit_kernel<<<dim3(In / 64, Hn / 64), blk, 0, stream>>>(Wg, W3g, Hn, In);
    presplit_kernel<<<dim3(In / 64, Hn / 64), blk, 0, stream>>>(Wu, W3u, Hn, In);
    presplit_kernel<<<dim3(Hn / 64, In / 64), blk, 0, stream>>>(Wd, W3d, In, Hn);
    rmsnorm3_kernel<<<Vn, 256, 0, stream>>>(Emb, n1, s3a, SVH);
    gemm3_kernel<EPI_NONE, false, false><<<gVH, gblk, 0, stream>>>(
        s3a, SVH, W3k, nullptr, SW1, Hn, EK, nullptr, 0, nullptr, Hn, Hn);
    gemm3_kernel<EPI_NONE, false, false><<<gVH, gblk, 0, stream>>>(
        s3a, SVH, W3v, nullptr, SW1, Hn, EV, nullptr, 0, nullptr, Hn, Hn);

    for (int p = 0; p < NSTEPSn; p++) {
        const float* src = (p == 0) ? x0 : xb;

        rmsnorm3_kernel<<<Tn, 256, 0, stream>>>(src, n1, s3a, STH);
        gemm3_kernel<EPI_NONE, false, false><<<gTH, gblk, 0, stream>>>(
            s3a, STH, W3q, nullptr, SW1, Hn, qb, nullptr, 0, nullptr, Hn, Hn);
        if (p == 0) {
            gemm3_kernel<EPI_NONE, false, false><<<gTH, gblk, 0, stream>>>(
                s3a, STH, W3k, nullptr, SW1, Hn, K0, nullptr, 0, nullptr, Hn, Hn);
            gemm3_kernel<EPI_NONE, false, false><<<gTH, gblk, 0, stream>>>(
                s3a, STH, W3v, nullptr, SW1, Hn, V0, nullptr, 0, nullptr, Hn, Hn);
        }
        attn_kernel<<<(Tn * NHn) / 4, 256, 0, stream>>>(qb, K0, V0, EK, EV, toks,
                                                        tab, s3a, STH, p);
        // h2 = ctx @ Wo + src  (in-place into xb when src == xb)
        gemm3_kernel<EPI_ADD, false, false><<<gTH, gblk, 0, stream>>>(
            s3a, STH, W3o, nullptr, SW1, Hn, xb, nullptr, 0, src, Hn, Hn);
        rmsnorm3_kernel<<<Tn, 256, 0, stream>>>(xb, n2, s3a, STH);
        // Gated MLP, chunked over I (4 x 1024): separate G (silu -> Gc fp32)
        // and U (mul by Gc -> s3g triple) — measured faster than the fused
        // kernel (2x43us vs 121us per pair); then chunk-accumulated @Wd.
        for (int c = 0; c < 4; c++) {
            gemm3_kernel<EPI_SILU, false, false><<<gTH, gblk, 0, stream>>>(
                s3a, STH, W3g + (size_t)c * M1, nullptr, SW4, Hn,
                Gc, nullptr, 0, nullptr, Hn, 1024);
            gemm3_kernel<EPI_MUL, true, false><<<gTH, gblk, 0, stream>>>(
                s3a, STH, W3u + (size_t)c * M1, nullptr, SW4, Hn,
                nullptr, s3g, STH, Gc, Hn, 1024);
            if (c < 3) {
                gemm3_kernel<EPI_ADD, false, false><<<gTH, gblk, 0, stream>>>(
                    s3g, STH, W3d + (size_t)c * 1024, nullptr, SW4, In,
                    qb, nullptr, 0, (c == 0) ? xb : qb, Hn, Hn);
            } else {
                gemm3_kernel<EPI_ADD, true, false><<<gTH, gblk, 0, stream>>>(
                    s3g, STH, W3d + (size_t)c * 1024, nullptr, SW4, In,
                    nullptr, s3a, STH, qb, Hn, Hn);
            }
        }
        // logits = out @ Wout + bout  (into qb)
        gemm3_kernel<EPI_BIAS, false, false><<<gTH, gblk, 0, stream>>>(
            s3a, STH, W3t, nullptr, SW1, Hn, qb, nullptr, 0, bout, Hn, Vn);
        argmax_kernel<<<Tn, 256, 0, stream>>>(qb, toks, p);
        if (p < NSTEPSn - 1) embed_kernel<<<Tn, 256, 0, stream>>>(Emb, toks, xb, p);
    }
}

// Round 8
// 6051.849 us; speedup vs baseline: 1.3128x; 1.2964x over previous
//
#include <hip/hip_runtime.h>
#include <hip/hip_fp16.h>
#include <cmath>

#define Tn 4096
#define Hn 1024
#define NHn 16
#define HDn 64
#define In 4096
#define Vn 1024
#define NSTEPSn 8

enum { EPI_NONE = 0, EPI_ADD = 1, EPI_SILU = 2, EPI_MUL = 3, EPI_BIAS = 4 };

typedef __attribute__((ext_vector_type(8))) _Float16 f16x8;
typedef __attribute__((ext_vector_type(4))) float f32x4;

// fp32 -> f16 high/low split (RNE), with the LOW plane pre-scaled by 2^11 so
// it stays in f16 NORMAL range (unscaled residuals of 0.02-magnitude weights
// are ~1e-5 — f16 subnormal; if MFMA flushed them the correction would vanish).
// Reconstruction: x ~= h + l * 2^-11, residual ~2^-22 relative — far below the
// f32 reference's own ~2^-19 accumulation noise that dominates token margins.
// The 2^-11 is applied in the GEMM promote (separate accl accumulator).
__device__ inline unsigned short f16rne(float x) {
    return __half_as_ushort(__float2half(x));
}
__device__ inline float f16tof(unsigned short h) {
    return __half2float(__ushort_as_half(h));
}
__device__ inline void split2(float x, unsigned short& h, unsigned short& l) {
    h = f16rne(x);
    float r = (x - f16tof(h)) * 2048.0f;
    l = f16rne(r);
}

// Async global->LDS, 16B per lane (wave-uniform LDS base; HW scatters lane*16).
__device__ __forceinline__ void gload_lds(const unsigned short* g,
                                          const unsigned short* l) {
    __builtin_amdgcn_global_load_lds(
        (const __attribute__((address_space(1))) unsigned int*)(uintptr_t)g,
        (__attribute__((address_space(3))) unsigned int*)(unsigned int)(uintptr_t)l,
        16, 0, 0);
}

// ---------------- RoPE cos/sin table ----------------
__global__ void rope_tab_kernel(double2* __restrict__ tab) {
    int tid = threadIdx.x;  // 256 threads
    int j = tid >> 5, i = tid & 31;
    double inv = exp(-((double)(2 * i) * (1.0 / (double)HDn)) * 9.210340371976184);
    double ang = (double)j * inv;
    double2 cs;
    cs.x = cos(ang);
    cs.y = sin(ang);
    tab[tid] = cs;
}

// ---------------- Weight pre-split: W[K][N] fp32 -> W2[2][N][K] f16 ----------------
__global__ __launch_bounds__(256) void presplit_kernel(const float* __restrict__ W,
                                                       unsigned short* __restrict__ W2,
                                                       int K, int N) {
    __shared__ float S[64][65];
    int k0 = blockIdx.y * 64, n0 = blockIdx.x * 64;
    int tid = threadIdx.x;
#pragma unroll
    for (int r = 0; r < 4; r++) {
        int idx = tid + r * 256;
        int kr = idx >> 4, c4 = (idx & 15) << 2;
        float4 v = *(const float4*)(W + (size_t)(k0 + kr) * N + n0 + c4);
        S[kr][c4] = v.x;
        S[kr][c4 + 1] = v.y;
        S[kr][c4 + 2] = v.z;
        S[kr][c4 + 3] = v.w;
    }
    __syncthreads();
    size_t PS = (size_t)N * K;
#pragma unroll
    for (int r = 0; r < 4; r++) {
        int idx = tid + r * 256;
        int kq = idx & 15, n = idx >> 4;
        ushort4 hq, lq;
        split2(S[4 * kq + 0][n], hq.x, lq.x);
        split2(S[4 * kq + 1][n], hq.y, lq.y);
        split2(S[4 * kq + 2][n], hq.z, lq.z);
        split2(S[4 * kq + 3][n], hq.w, lq.w);
        size_t off = (size_t)(n0 + n) * K + k0 + 4 * kq;
        *(ushort4*)(W2 + off) = hq;
        *(ushort4*)(W2 + PS + off) = lq;
    }
}

// ---------------- RMSNorm -> f16 h/l planes (f64 math) ----------------
__global__ __launch_bounds__(256) void rmsnorm2_kernel(const float* __restrict__ x,
                                                       const float* __restrict__ w,
                                                       unsigned short* __restrict__ y2,
                                                       size_t stride) {
    int t = blockIdx.x;
    const float4* xr = (const float4*)(x + (size_t)t * Hn);
    float4 v = xr[threadIdx.x];
    double ss = (double)v.x * v.x + (double)v.y * v.y + (double)v.z * v.z + (double)v.w * v.w;
#pragma unroll
    for (int o = 1; o < 64; o <<= 1) ss += __shfl_xor(ss, o, 64);
    __shared__ double red[4];
    if ((threadIdx.x & 63) == 0) red[threadIdx.x >> 6] = ss;
    __syncthreads();
    double tot = red[0] + red[1] + red[2] + red[3];
    double rs = 1.0 / sqrt(tot * (1.0 / Hn) + 1e-6);
    const float4* wr = (const float4*)w;
    float4 wv = wr[threadIdx.x];
    float o[4];
    o[0] = (float)((double)v.x * rs * (double)wv.x);
    o[1] = (float)((double)v.y * rs * (double)wv.y);
    o[2] = (float)((double)v.z * rs * (double)wv.z);
    o[3] = (float)((double)v.w * rs * (double)wv.w);
    ushort4 hq, lq;
    split2(o[0], hq.x, lq.x);
    split2(o[1], hq.y, lq.y);
    split2(o[2], hq.z, lq.z);
    split2(o[3], hq.w, lq.w);
    size_t off = (size_t)t * Hn + threadIdx.x * 4;
    *(ushort4*)(y2 + off) = hq;
    *(ushort4*)(y2 + stride + off) = lq;
}

// ---------------- Attention (f64 dot, table RoPE, f32 exp), out f16 h/l ----
__global__ __launch_bounds__(256) void attn_kernel(const float* __restrict__ q,
                                                   const float* __restrict__ K0,
                                                   const float* __restrict__ V0,
                                                   const float* __restrict__ EK,
                                                   const float* __restrict__ EV,
                                                   const int* __restrict__ toks,
                                                   const double2* __restrict__ tab,
                                                   unsigned short* __restrict__ ctx2,
                                                   size_t stride, int p) {
    int wave = blockIdx.x * 4 + (threadIdx.x >> 6);  // t*NH + head
    int lane = threadIdx.x & 63;
    int t = wave >> 4;
    int col = ((wave & 15) << 6) | lane;
    int i = lane & 31;
    int half = lane >> 5;
    size_t base = (size_t)wave * HDn + lane;

    double2 csp = tab[p * 32 + i];
    double qv = (double)q[base];
    double qpart = __shfl_xor(qv, 32, 64);
    double qr = half ? (qv * csp.x + qpart * csp.y) : (qv * csp.x - qpart * csp.y);

    double sc[NSTEPSn];
    int tk[NSTEPSn];
    double m = -1e300;
    for (int j = 0; j <= p; j++) {
        double kr;
        if (j == 0) {
            kr = (double)K0[base];
            tk[0] = 0;
        } else {
            int tok = toks[(size_t)t * NSTEPSn + (j - 1)];
            tk[j] = tok;
            double kv = (double)EK[(size_t)tok * Hn + col];
            double kpart = __shfl_xor(kv, 32, 64);
            double2 cs = tab[j * 32 + i];
            kr = half ? (kv * cs.x + kpart * cs.y) : (kv * cs.x - kpart * cs.y);
        }
        double pr = qr * kr;
#pragma unroll
        for (int o = 1; o < 64; o <<= 1) pr += __shfl_xor(pr, o, 64);
        sc[j] = pr * 0.125;
        m = fmax(m, sc[j]);
    }
    double den = 0.0;
    for (int j = 0; j <= p; j++) {
        sc[j] = (double)expf((float)(sc[j] - m));
        den += sc[j];
    }
    double invd = 1.0 / den;
    double acc = 0.0;
    for (int j = 0; j <= p; j++) {
        double vv = (j == 0) ? (double)V0[base] : (double)EV[(size_t)tk[j] * Hn + col];
        acc += sc[j] * vv;
    }
    unsigned short h, l;
    split2((float)(acc * invd), h, l);
    ctx2[base] = h;
    ctx2[stride + base] = l;
}

// ---------------- f16x2 MFMA GEMM: 128x128 tile, 8 waves, 3-buffer pipeline ----
// C(M x N) = A(M x K) @ B(K x N). A planes [2][M][K] f16, B planes [2][N][K];
// low planes pre-scaled by 2^11 (see split2). 3 products per K-chunk:
//   Ah*Bh -> acc (unit scale), Ah*Bl' + Al'*Bh -> accl (2^11 scale).
// Promote: accd += acc + accl * 2^-11 (f64). Residual ~2^-22 relative.
// Row-major cells + quad-XOR staging (4 consecutive lanes cover one 64B
// row-slice -> coalesced global_load_lds). Pipeline: 3 phases/chunk (one
// product each); next-phase ds_reads issue inside the current MFMA region;
// counted vmcnt(4) in P2 proves buffer c+1 landed (the following barrier makes
// the per-wave wait collective); never vmcnt(0) in steady state.
#define BUFU 16384  // ushorts per buffer: 32KB (A 16KB + B 16KB)
template <int EPI, bool PAIR>
__global__ __launch_bounds__(512, 2) void gemm2_kernel(
    const unsigned short* __restrict__ A2, size_t strideA,
    const unsigned short* __restrict__ B2, size_t strideB, int ldbk,
    float* Cf, unsigned short* C2, size_t strideC,
    const float* aux, int K, int ldc) {
    __shared__ __align__(16) unsigned short lds[3 * BUFU];  // 96 KB

    int tid = threadIdx.x;
    int wv = tid >> 6, lane = tid & 63;
    int wr = wv >> 2;  // 2 m-groups of 64
    int wc = wv & 3;   // 4 n-groups of 32

    // ---- XCD swizzle: GN = 8 fixed (N=1024/128) ----
    int f = blockIdx.x;
    int xcd = f & 7;
    int j = f >> 3;
    int bmPer = gridDim.x >> 6;  // GM/8 (256->4, 64->1)
    int mblk = (xcd * bmPer + (j >> 3)) * 128;
    int nblk = (j & 7) * 128;

    // ---- staging segments: 32 x 1KB, each wave owns 4 (2 in P0, 2 in P1) ----
    // row-major+quad-XOR: lanes 4q..4q+3 cover one 64B row-slice
    int rsel = lane >> 2;
    int csel = ((lane & 3) ^ ((lane >> 2) & 3)) << 3;
    const unsigned short* gseg[4];
    unsigned lseg[4];
#pragma unroll
    for (int i = 0; i < 4; i++) {
        int s = wv * 4 + i;
        if (s < 16) {
            int pl = s >> 3, sub = s & 7;
            gseg[i] = A2 + (size_t)pl * strideA +
                      (size_t)(mblk + sub * 16 + rsel) * K + csel;
            lseg[i] = pl * 4096 + sub * 512;
        } else {
            int u = s - 16;
            int pl = u >> 3, sub = u & 7;
            gseg[i] = B2 + (size_t)pl * strideB +
                      (size_t)(nblk + sub * 16 + rsel) * ldbk + csel;
            lseg[i] = 8192 + pl * 4096 + sub * 512;
        }
    }

    f32x4 acc[4][2], accl[4][2];
    double accd[4][2][4];
#pragma unroll
    for (int mt = 0; mt < 4; mt++)
#pragma unroll
        for (int nt = 0; nt < 2; nt++) {
            acc[mt][nt] = (f32x4){0.f, 0.f, 0.f, 0.f};
            accl[mt][nt] = (f32x4){0.f, 0.f, 0.f, 0.f};
#pragma unroll
            for (int r = 0; r < 4; r++) accd[mt][nt][r] = 0.0;
        }

    int rA = lane & 15;
    // fragment offset within a 512-ushort segment (row-major + quad-XOR)
    unsigned fo = (rA << 5) + (((lane >> 4) ^ (lane & 3)) << 3);

    int nc = K >> 5;  // 32-K chunks

    // ---- prologue: stage chunk0 -> buf0, chunk1 -> buf1, preload Ah/Bh ----
#pragma unroll
    for (int i = 0; i < 4; i++) gload_lds(gseg[i], lds + lseg[i]);
#pragma unroll
    for (int i = 0; i < 4; i++) gload_lds(gseg[i] + 32, lds + BUFU + lseg[i]);
    asm volatile("s_waitcnt vmcnt(4)" ::: "memory");  // chunk 0 landed
    __builtin_amdgcn_s_barrier();

    f16x8 Ah[4], Al[4], Bh[2], Bl[2];
#pragma unroll
    for (int mt = 0; mt < 4; mt++)
        Ah[mt] = *(const f16x8*)(lds + (wr * 4 + mt) * 512 + fo);
#pragma unroll
    for (int nt = 0; nt < 2; nt++)
        Bh[nt] = *(const f16x8*)(lds + 8192 + (wc * 2 + nt) * 512 + fo);

    int rd = 0, w2 = 2;
    for (int c = 0; c < nc; ++c) {
        const unsigned short* Ar = lds + rd * BUFU;
        unsigned short* Lw = lds + w2 * BUFU;
        const bool pf = (c + 2 < nc);
        const bool nx = (c + 1 < nc);
        int koff = (c + 2) << 5;

        // ================= P0: stage(0,1); MFMA Ah*Bh; read Bl ================
        if (pf) {
            gload_lds(gseg[0] + koff, Lw + lseg[0]);
            gload_lds(gseg[1] + koff, Lw + lseg[1]);
        }
        if (c > 0 && (c & 1) == 0) {  // promote completed chunks during DMA
#pragma unroll
            for (int mt = 0; mt < 4; mt++)
#pragma unroll
                for (int nt = 0; nt < 2; nt++)
#pragma unroll
                    for (int r = 0; r < 4; r++) {
                        accd[mt][nt][r] += (double)acc[mt][nt][r] +
                                           (double)accl[mt][nt][r] * 4.8828125e-4;
                        acc[mt][nt][r] = 0.f;
                        accl[mt][nt][r] = 0.f;
                    }
        }
        __builtin_amdgcn_s_barrier();
#pragma unroll
        for (int nt = 0; nt < 2; nt++)
            Bl[nt] = *(const f16x8*)(Ar + 12288 + (wc * 2 + nt) * 512 + fo);
        __builtin_amdgcn_s_setprio(1);
#pragma unroll
        for (int mt = 0; mt < 4; mt++)
#pragma unroll
            for (int nt = 0; nt < 2; nt++)
                acc[mt][nt] = __builtin_amdgcn_mfma_f32_16x16x32_f16(
                    Ah[mt], Bh[nt], acc[mt][nt], 0, 0, 0);
        __builtin_amdgcn_s_setprio(0);
        __builtin_amdgcn_s_barrier();

        // ================= P1: stage(2,3); MFMA Ah*Bl -> accl; read Al ========
        if (pf) {
            gload_lds(gseg[2] + koff, Lw + lseg[2]);
            gload_lds(gseg[3] + koff, Lw + lseg[3]);
        }
        __builtin_amdgcn_s_barrier();
#pragma unroll
        for (int mt = 0; mt < 4; mt++)
            Al[mt] = *(const f16x8*)(Ar + 4096 + (wr * 4 + mt) * 512 + fo);
        __builtin_amdgcn_s_setprio(1);
#pragma unroll
        for (int mt = 0; mt < 4; mt++)
#pragma unroll
            for (int nt = 0; nt < 2; nt++)
                accl[mt][nt] = __builtin_amdgcn_mfma_f32_16x16x32_f16(
                    Ah[mt], Bl[nt], accl[mt][nt], 0, 0, 0);
        __builtin_amdgcn_s_setprio(0);
        __builtin_amdgcn_s_barrier();

        // ===== P2: vmcnt proves buf c+1 landed; MFMA Al*Bh -> accl; preload ====
        if (nx) {
            if (pf)
                asm volatile("s_waitcnt vmcnt(4)" ::: "memory");
            else
                asm volatile("s_waitcnt vmcnt(0)" ::: "memory");
        }
        __builtin_amdgcn_s_barrier();
        __builtin_amdgcn_s_setprio(1);
#pragma unroll
        for (int mt = 0; mt < 4; mt++)
#pragma unroll
            for (int nt = 0; nt < 2; nt++)
                accl[mt][nt] = __builtin_amdgcn_mfma_f32_16x16x32_f16(
                    Al[mt], Bh[nt], accl[mt][nt], 0, 0, 0);
        __builtin_amdgcn_s_setprio(0);
        if (nx) {  // preload next chunk's Ah/Bh (buffer rd+1, proven landed)
            int rdn = (rd + 1 == 3) ? 0 : rd + 1;
            const unsigned short* An = lds + rdn * BUFU;
#pragma unroll
            for (int mt = 0; mt < 4; mt++)
                Ah[mt] = *(const f16x8*)(An + (wr * 4 + mt) * 512 + fo);
#pragma unroll
            for (int nt = 0; nt < 2; nt++)
                Bh[nt] = *(const f16x8*)(An + 8192 + (wc * 2 + nt) * 512 + fo);
        }
        __builtin_amdgcn_s_barrier();

        rd = (rd + 1 == 3) ? 0 : rd + 1;
        w2 = (w2 + 1 == 3) ? 0 : w2 + 1;
    }

    // final promote (last 2 chunks)
#pragma unroll
    for (int mt = 0; mt < 4; mt++)
#pragma unroll
        for (int nt = 0; nt < 2; nt++)
#pragma unroll
            for (int r = 0; r < 4; r++)
                accd[mt][nt][r] += (double)acc[mt][nt][r] +
                                   (double)accl[mt][nt][r] * 4.8828125e-4;

    // ---- epilogue (f64), write f32 or f16 h/l pair ----
#pragma unroll
    for (int mt = 0; mt < 4; mt++)
#pragma unroll
        for (int nt = 0; nt < 2; nt++) {
            int n = nblk + wc * 32 + nt * 16 + (lane & 15);
            int mb = mblk + wr * 64 + mt * 16 + ((lane >> 4) << 2);
#pragma unroll
            for (int r = 0; r < 4; r++) {
                int m = mb + r;
                size_t off = (size_t)m * ldc + n;
                double v = accd[mt][nt][r];
                if (EPI == EPI_ADD) v += (double)aux[off];
                if (EPI == EPI_SILU) {
                    float vf = (float)v;
                    v = (double)(vf / (1.0f + expf(-vf)));
                }
                if (EPI == EPI_MUL) v *= (double)aux[off];
                if (EPI == EPI_BIAS) v += (double)aux[n];
                if (PAIR) {
                    unsigned short h, l;
                    split2((float)v, h, l);
                    C2[off] = h;
                    C2[strideC + off] = l;
                } else {
                    Cf[off] = (float)v;
                }
            }
        }
}

// ---------------- Argmax over f32 logits (first-max tie-break) ----------------
__global__ __launch_bounds__(256) void argmax_kernel(const float* __restrict__ logits,
                                                     int* __restrict__ out_tok, int p) {
    int t = blockIdx.x;
    const float* lr = logits + (size_t)t * Vn;
    float bv = -INFINITY;
    int bi = 0x7fffffff;
    for (int j = threadIdx.x; j < Vn; j += 256) {
        float v = lr[j];
        if (v > bv || (v == bv && j < bi)) {
            bv = v;
            bi = j;
        }
    }
#pragma unroll
    for (int o = 1; o < 64; o <<= 1) {
        float ov = __shfl_xor(bv, o, 64);
        int oi = __shfl_xor(bi, o, 64);
        if (ov > bv || (ov == bv && oi < bi)) {
            bv = ov;
            bi = oi;
        }
    }
    __shared__ float sv[4];
    __shared__ int si[4];
    if ((threadIdx.x & 63) == 0) {
        sv[threadIdx.x >> 6] = bv;
        si[threadIdx.x >> 6] = bi;
    }
    __syncthreads();
    if (threadIdx.x == 0) {
        for (int w = 1; w < 4; w++) {
            if (sv[w] > bv || (sv[w] == bv && si[w] < bi)) {
                bv = sv[w];
                bi = si[w];
            }
        }
        out_tok[(size_t)t * NSTEPSn + p] = bi;
    }
}

// ---------------- Embedding gather ----------------
__global__ __launch_bounds__(256) void embed_kernel(const float* __restrict__ E,
                                                    const int* __restrict__ toks,
                                                    float* __restrict__ x, int p) {
    int t = blockIdx.x;
    int tok = toks[(size_t)t * NSTEPSn + p];
    float4 v = ((const float4*)(E + (size_t)tok * Hn))[threadIdx.x];
    ((float4*)(x + (size_t)t * Hn))[threadIdx.x] = v;
}

extern "C" void kernel_launch(void* const* d_in, const int* in_sizes, int n_in,
                              void* d_out, int out_size, void* d_ws, size_t ws_size,
                              hipStream_t stream) {
    const float* x0 = (const float*)d_in[0];
    const float* Wq = (const float*)d_in[1];
    const float* Wk = (const float*)d_in[2];
    const float* Wv = (const float*)d_in[3];
    const float* Wo = (const float*)d_in[4];
    const float* Wg = (const float*)d_in[5];
    const float* Wu = (const float*)d_in[6];
    const float* Wd = (const float*)d_in[7];
    const float* n1 = (const float*)d_in[8];
    const float* n2 = (const float*)d_in[9];
    const float* Emb = (const float*)d_in[10];
    const float* Wout = (const float*)d_in[11];
    const float* bout = (const float*)d_in[12];
    int* toks = (int*)d_out;

    float* ws = (float*)d_ws;
    const size_t M1 = 1024 * 1024;
    float* EK = ws;                  // V x H fp32           4MB
    float* EV = ws + 1 * M1;         //                      4MB
    float* K0 = ws + 2 * M1;         // T x H fp32           16MB
    float* V0 = ws + 6 * M1;         //                      16MB
    float* xb = ws + 10 * M1;        // residual hidden      16MB
    float* qb = ws + 14 * M1;        // q / MLP acc / logits 16MB
    float* Gc = ws + 18 * M1;        // silu chunk fp32      16MB
    unsigned short* s2a = (unsigned short*)(ws + 22 * M1);  // h/l TxH  (16MB used)
    unsigned short* s2g = (unsigned short*)(ws + 28 * M1);  // h/l TxH  (16MB used)
    double2* tab = (double2*)(ws + 34 * M1);                // 256 double2  4KB
    unsigned short* W2q = (unsigned short*)(ws + 34 * M1 + 1024);  // 2 planes used
    unsigned short* W2k = W2q + 3 * M1;
    unsigned short* W2v = W2k + 3 * M1;
    unsigned short* W2o = W2v + 3 * M1;
    unsigned short* W2t = W2o + 3 * M1;  // Wout
    unsigned short* W2g = W2t + 3 * M1;
    unsigned short* W2u = W2g + 12 * M1;
    unsigned short* W2d = W2u + 12 * M1;
    // total ~= 238 MB (offsets kept from the bf16x3 layout; 3rd planes unused)

    const size_t STH = (size_t)Tn * Hn;  // plane stride, T x 1024
    const size_t SVH = (size_t)Vn * Hn;  // plane stride, V x H
    const size_t SW1 = M1;               // plane stride, 1M-element weights
    const size_t SW4 = 4 * M1;           // plane stride, 4M-element weights

    dim3 blk(256);
    dim3 gblk(512);
    const int gTH = 256;  // (M/128=32) x (N/128=8), 1D swizzled
    const int gVH = 64;   // (M/128=8)  x 8

    // ---- One-time precompute ----
    rope_tab_kernel<<<1, 256, 0, stream>>>(tab);
    presplit_kernel<<<dim3(16, 16), blk, 0, stream>>>(Wq, W2q, Hn, Hn);
    presplit_kernel<<<dim3(16, 16), blk, 0, stream>>>(Wk, W2k, Hn, Hn);
    presplit_kernel<<<dim3(16, 16), blk, 0, stream>>>(Wv, W2v, Hn, Hn);
    presplit_kernel<<<dim3(16, 16), blk, 0, stream>>>(Wo, W2o, Hn, Hn);
    presplit_kernel<<<dim3(16, 16), blk, 0, stream>>>(Wout, W2t, Hn, Vn);
    presplit_kernel<<<dim3(In / 64, Hn / 64), blk, 0, stream>>>(Wg, W2g, Hn, In);
    presplit_kernel<<<dim3(In / 64, Hn / 64), blk, 0, stream>>>(Wu, W2u, Hn, In);
    presplit_kernel<<<dim3(Hn / 64, In / 64), blk, 0, stream>>>(Wd, W2d, In, Hn);
    rmsnorm2_kernel<<<Vn, 256, 0, stream>>>(Emb, n1, s2a, SVH);
    gemm2_kernel<EPI_NONE, false><<<gVH, gblk, 0, stream>>>(
        s2a, SVH, W2k, SW1, Hn, EK, nullptr, 0, nullptr, Hn, Hn);
    gemm2_kernel<EPI_NONE, false><<<gVH, gblk, 0, stream>>>(
        s2a, SVH, W2v, SW1, Hn, EV, nullptr, 0, nullptr, Hn, Hn);

    for (int p = 0; p < NSTEPSn; p++) {
        const float* src = (p == 0) ? x0 : xb;

        rmsnorm2_kernel<<<Tn, 256, 0, stream>>>(src, n1, s2a, STH);
        gemm2_kernel<EPI_NONE, false><<<gTH, gblk, 0, stream>>>(
            s2a, STH, W2q, SW1, Hn, qb, nullptr, 0, nullptr, Hn, Hn);
        if (p == 0) {
            gemm2_kernel<EPI_NONE, false><<<gTH, gblk, 0, stream>>>(
                s2a, STH, W2k, SW1, Hn, K0, nullptr, 0, nullptr, Hn, Hn);
            gemm2_kernel<EPI_NONE, false><<<gTH, gblk, 0, stream>>>(
                s2a, STH, W2v, SW1, Hn, V0, nullptr, 0, nullptr, Hn, Hn);
        }
        attn_kernel<<<(Tn * NHn) / 4, 256, 0, stream>>>(qb, K0, V0, EK, EV, toks,
                                                        tab, s2a, STH, p);
        // h2 = ctx @ Wo + src  (in-place into xb when src == xb)
        gemm2_kernel<EPI_ADD, false><<<gTH, gblk, 0, stream>>>(
            s2a, STH, W2o, SW1, Hn, xb, nullptr, 0, src, Hn, Hn);
        rmsnorm2_kernel<<<Tn, 256, 0, stream>>>(xb, n2, s2a, STH);
        // Gated MLP, chunked over I (4 x 1024): G (silu -> Gc f32), U (mul by
        // Gc -> s2g h/l), then chunk-accumulated @Wd into qb.
        for (int c = 0; c < 4; c++) {
            gemm2_kernel<EPI_SILU, false><<<gTH, gblk, 0, stream>>>(
                s2a, STH, W2g + (size_t)c * M1, SW4, Hn,
                Gc, nullptr, 0, nullptr, Hn, 1024);
            gemm2_kernel<EPI_MUL, true><<<gTH, gblk, 0, stream>>>(
                s2a, STH, W2u + (size_t)c * M1, SW4, Hn,
                nullptr, s2g, STH, Gc, Hn, 1024);
            if (c < 3) {
                gemm2_kernel<EPI_ADD, false><<<gTH, gblk, 0, stream>>>(
                    s2g, STH, W2d + (size_t)c * 1024, SW4, In,
                    qb, nullptr, 0, (c == 0) ? xb : qb, Hn, Hn);
            } else {
                gemm2_kernel<EPI_ADD, true><<<gTH, gblk, 0, stream>>>(
                    s2g, STH, W2d + (size_t)c * 1024, SW4, In,
                    nullptr, s2a, STH, qb, Hn, Hn);
            }
        }
        // logits = out @ Wout + bout  (into qb)
        gemm2_kernel<EPI_BIAS, false><<<gTH, gblk, 0, stream>>>(
            s2a, STH, W2t, SW1, Hn, qb, nullptr, 0, bout, Hn, Vn);
        argmax_kernel<<<Tn, 256, 0, stream>>>(qb, toks, p);
        if (p < NSTEPSn - 1) embed_kernel<<<Tn, 256, 0, stream>>>(Emb, toks, xb, p);
    }
}

// Round 9
// 5928.755 us; speedup vs baseline: 1.3401x; 1.0208x over previous
//
#include <hip/hip_runtime.h>
#include <hip/hip_fp16.h>
#include <cmath>

#define Tn 4096
#define Hn 1024
#define NHn 16
#define HDn 64
#define In 4096
#define Vn 1024
#define NSTEPSn 8

enum { EPI_NONE = 0, EPI_ADD = 1, EPI_SILU = 2, EPI_MUL = 3, EPI_BIAS = 4 };

typedef __attribute__((ext_vector_type(8))) _Float16 f16x8;
typedef __attribute__((ext_vector_type(4))) float f32x4;

// fp32 -> f16 high/low split (RNE), with the LOW plane pre-scaled by 2^11 so
// it stays in f16 NORMAL range (unscaled residuals of 0.02-magnitude weights
// are ~1e-5 — f16 subnormal; if MFMA flushed them the correction would vanish).
// Reconstruction: x ~= h + l * 2^-11, residual ~2^-22 relative — far below the
// f32 reference's own ~2^-19 accumulation noise that dominates token margins.
// The 2^-11 is applied in the GEMM promote (separate accl accumulator).
__device__ inline unsigned short f16rne(float x) {
    return __half_as_ushort(__float2half(x));
}
__device__ inline float f16tof(unsigned short h) {
    return __half2float(__ushort_as_half(h));
}
__device__ inline void split2(float x, unsigned short& h, unsigned short& l) {
    h = f16rne(x);
    float r = (x - f16tof(h)) * 2048.0f;
    l = f16rne(r);
}

// Async global->LDS, 16B per lane (wave-uniform LDS base; HW scatters lane*16).
__device__ __forceinline__ void gload_lds(const unsigned short* g,
                                          const unsigned short* l) {
    __builtin_amdgcn_global_load_lds(
        (const __attribute__((address_space(1))) unsigned int*)(uintptr_t)g,
        (__attribute__((address_space(3))) unsigned int*)(unsigned int)(uintptr_t)l,
        16, 0, 0);
}

// ---------------- RoPE cos/sin table ----------------
__global__ void rope_tab_kernel(double2* __restrict__ tab) {
    int tid = threadIdx.x;  // 256 threads
    int j = tid >> 5, i = tid & 31;
    double inv = exp(-((double)(2 * i) * (1.0 / (double)HDn)) * 9.210340371976184);
    double ang = (double)j * inv;
    double2 cs;
    cs.x = cos(ang);
    cs.y = sin(ang);
    tab[tid] = cs;
}

// ---------------- Weight pre-split: W[K][N] fp32 -> W2[2][N][K] f16 ----------------
__global__ __launch_bounds__(256) void presplit_kernel(const float* __restrict__ W,
                                                       unsigned short* __restrict__ W2,
                                                       int K, int N) {
    __shared__ float S[64][65];
    int k0 = blockIdx.y * 64, n0 = blockIdx.x * 64;
    int tid = threadIdx.x;
#pragma unroll
    for (int r = 0; r < 4; r++) {
        int idx = tid + r * 256;
        int kr = idx >> 4, c4 = (idx & 15) << 2;
        float4 v = *(const float4*)(W + (size_t)(k0 + kr) * N + n0 + c4);
        S[kr][c4] = v.x;
        S[kr][c4 + 1] = v.y;
        S[kr][c4 + 2] = v.z;
        S[kr][c4 + 3] = v.w;
    }
    __syncthreads();
    size_t PS = (size_t)N * K;
#pragma unroll
    for (int r = 0; r < 4; r++) {
        int idx = tid + r * 256;
        int kq = idx & 15, n = idx >> 4;
        ushort4 hq, lq;
        split2(S[4 * kq + 0][n], hq.x, lq.x);
        split2(S[4 * kq + 1][n], hq.y, lq.y);
        split2(S[4 * kq + 2][n], hq.z, lq.z);
        split2(S[4 * kq + 3][n], hq.w, lq.w);
        size_t off = (size_t)(n0 + n) * K + k0 + 4 * kq;
        *(ushort4*)(W2 + off) = hq;
        *(ushort4*)(W2 + PS + off) = lq;
    }
}

// ---------------- RMSNorm -> f16 h/l planes (f64 math) ----------------
__global__ __launch_bounds__(256) void rmsnorm2_kernel(const float* __restrict__ x,
                                                       const float* __restrict__ w,
                                                       unsigned short* __restrict__ y2,
                                                       size_t stride) {
    int t = blockIdx.x;
    const float4* xr = (const float4*)(x + (size_t)t * Hn);
    float4 v = xr[threadIdx.x];
    double ss = (double)v.x * v.x + (double)v.y * v.y + (double)v.z * v.z + (double)v.w * v.w;
#pragma unroll
    for (int o = 1; o < 64; o <<= 1) ss += __shfl_xor(ss, o, 64);
    __shared__ double red[4];
    if ((threadIdx.x & 63) == 0) red[threadIdx.x >> 6] = ss;
    __syncthreads();
    double tot = red[0] + red[1] + red[2] + red[3];
    double rs = 1.0 / sqrt(tot * (1.0 / Hn) + 1e-6);
    const float4* wr = (const float4*)w;
    float4 wv = wr[threadIdx.x];
    float o[4];
    o[0] = (float)((double)v.x * rs * (double)wv.x);
    o[1] = (float)((double)v.y * rs * (double)wv.y);
    o[2] = (float)((double)v.z * rs * (double)wv.z);
    o[3] = (float)((double)v.w * rs * (double)wv.w);
    ushort4 hq, lq;
    split2(o[0], hq.x, lq.x);
    split2(o[1], hq.y, lq.y);
    split2(o[2], hq.z, lq.z);
    split2(o[3], hq.w, lq.w);
    size_t off = (size_t)t * Hn + threadIdx.x * 4;
    *(ushort4*)(y2 + off) = hq;
    *(ushort4*)(y2 + stride + off) = lq;
}

// ---------------- Attention: 8 (t,head) pairs per wave, stride-8 cols ----------
// Lane l: group g = l>>3 owns pair wv*8+g; s = l&7 owns cols {s, s+8, .., s+56}.
// RoPE partner col+-32 is IN-LANE (k<->k+4): zero shuffles for rope. The dot is
// 8 in-lane f64 FMAs + a 3-stage 8-lane reduce (xor 1,2,4) producing 8 scores
// per wave — ~2.7x fewer f64 wave-instructions than the 64-lane butterfly.
// Per-element rope/exp/softmax expressions are identical to the verified
// kernel; only the f64 summation order changes (tree-of-8 vs 64-butterfly).
__global__ __launch_bounds__(256) void attn_kernel(const float* __restrict__ q,
                                                   const float* __restrict__ K0,
                                                   const float* __restrict__ V0,
                                                   const float* __restrict__ EK,
                                                   const float* __restrict__ EV,
                                                   const int* __restrict__ toks,
                                                   const double2* __restrict__ tab,
                                                   unsigned short* __restrict__ ctx2,
                                                   size_t stride, int p) {
    int wv = blockIdx.x * 4 + (threadIdx.x >> 6);  // wave id; 8 pairs per wave
    int lane = threadIdx.x & 63;
    int g = lane >> 3, s = lane & 7;
    int pair = wv * 8 + g;  // t*NH + head
    int t = pair >> 4;
    int head = pair & 15;
    int colbase = pair << 6;  // base into [T*NH*64] arrays

    // ---- q load + rope at position p (partner in-lane: k <-> k+4) ----
    double qv[8], qr[8];
#pragma unroll
    for (int k = 0; k < 8; k++) qv[k] = (double)q[colbase + s + 8 * k];
#pragma unroll
    for (int k = 0; k < 4; k++) {
        double2 cs = tab[p * 32 + s + 8 * k];
        qr[k] = qv[k] * cs.x - qv[k + 4] * cs.y;       // half=0: qv*c - part*s
        qr[k + 4] = qv[k + 4] * cs.x + qv[k] * cs.y;   // half=1: qv*c + part*s
    }

    // ---- scores ----
    double sc[NSTEPSn];
    int tk[NSTEPSn];
    double m = -1e300;
    for (int j = 0; j <= p; j++) {
        double kr[8];
        if (j == 0) {
            tk[0] = 0;
#pragma unroll
            for (int k = 0; k < 8; k++) kr[k] = (double)K0[colbase + s + 8 * k];
        } else {
            int tok = toks[(size_t)t * NSTEPSn + (j - 1)];
            tk[j] = tok;
            size_t eb = (size_t)tok * Hn + (head << 6);
            double kv[8];
#pragma unroll
            for (int k = 0; k < 8; k++) kv[k] = (double)EK[eb + s + 8 * k];
#pragma unroll
            for (int k = 0; k < 4; k++) {
                double2 cs = tab[j * 32 + s + 8 * k];
                kr[k] = kv[k] * cs.x - kv[k + 4] * cs.y;
                kr[k + 4] = kv[k + 4] * cs.x + kv[k] * cs.y;
            }
        }
        double pr = 0.0;
#pragma unroll
        for (int k = 0; k < 8; k++) pr += qr[k] * kr[k];
#pragma unroll
        for (int o = 1; o < 8; o <<= 1) pr += __shfl_xor(pr, o, 64);
        sc[j] = pr * 0.125;
        m = fmax(m, sc[j]);
    }

    // ---- softmax (f32 exp, f64 sum — same as verified kernel) ----
    double den = 0.0;
    for (int j = 0; j <= p; j++) {
        sc[j] = (double)expf((float)(sc[j] - m));
        den += sc[j];
    }
    double invd = 1.0 / den;

    // ---- PV ----
    double acc[8];
#pragma unroll
    for (int k = 0; k < 8; k++) acc[k] = 0.0;
    for (int j = 0; j <= p; j++) {
        if (j == 0) {
#pragma unroll
            for (int k = 0; k < 8; k++)
                acc[k] += sc[0] * (double)V0[colbase + s + 8 * k];
        } else {
            size_t eb = (size_t)tk[j] * Hn + (head << 6);
#pragma unroll
            for (int k = 0; k < 8; k++)
                acc[k] += sc[j] * (double)EV[eb + s + 8 * k];
        }
    }

#pragma unroll
    for (int k = 0; k < 8; k++) {
        unsigned short h, l;
        split2((float)(acc[k] * invd), h, l);
        ctx2[colbase + s + 8 * k] = h;
        ctx2[stride + colbase + s + 8 * k] = l;
    }
}

// ---------------- f16x2 MFMA GEMM: 128x128 tile, 8 waves, 3-buffer pipeline ----
// C(M x N) = A(M x K) @ B(K x N). A planes [2][M][K] f16, B planes [2][N][K];
// low planes pre-scaled by 2^11 (see split2). 3 products per K-chunk:
//   Ah*Bh -> acc (unit scale), Ah*Bl' + Al'*Bh -> accl (2^11 scale).
// Promote: accd += acc + accl * 2^-11 (f64). Residual ~2^-22 relative.
// Row-major cells + quad-XOR staging (4 consecutive lanes cover one 64B
// row-slice -> coalesced global_load_lds). Pipeline: 3 phases/chunk (one
// product each); next-phase ds_reads issue inside the current MFMA region;
// counted vmcnt(4) in P2 proves buffer c+1 landed (the following barrier makes
// the per-wave wait collective); never vmcnt(0) in steady state.
#define BUFU 16384  // ushorts per buffer: 32KB (A 16KB + B 16KB)
template <int EPI, bool PAIR>
__global__ __launch_bounds__(512, 2) void gemm2_kernel(
    const unsigned short* __restrict__ A2, size_t strideA,
    const unsigned short* __restrict__ B2, size_t strideB, int ldbk,
    float* Cf, unsigned short* C2, size_t strideC,
    const float* aux, int K, int ldc) {
    __shared__ __align__(16) unsigned short lds[3 * BUFU];  // 96 KB

    int tid = threadIdx.x;
    int wv = tid >> 6, lane = tid & 63;
    int wr = wv >> 2;  // 2 m-groups of 64
    int wc = wv & 3;   // 4 n-groups of 32

    // ---- XCD swizzle: GN = 8 fixed (N=1024/128) ----
    int f = blockIdx.x;
    int xcd = f & 7;
    int j = f >> 3;
    int bmPer = gridDim.x >> 6;  // GM/8 (256->4, 64->1)
    int mblk = (xcd * bmPer + (j >> 3)) * 128;
    int nblk = (j & 7) * 128;

    // ---- staging segments: 32 x 1KB, each wave owns 4 (2 in P0, 2 in P1) ----
    // row-major+quad-XOR: lanes 4q..4q+3 cover one 64B row-slice
    int rsel = lane >> 2;
    int csel = ((lane & 3) ^ ((lane >> 2) & 3)) << 3;
    const unsigned short* gseg[4];
    unsigned lseg[4];
#pragma unroll
    for (int i = 0; i < 4; i++) {
        int s = wv * 4 + i;
        if (s < 16) {
            int pl = s >> 3, sub = s & 7;
            gseg[i] = A2 + (size_t)pl * strideA +
                      (size_t)(mblk + sub * 16 + rsel) * K + csel;
            lseg[i] = pl * 4096 + sub * 512;
        } else {
            int u = s - 16;
            int pl = u >> 3, sub = u & 7;
            gseg[i] = B2 + (size_t)pl * strideB +
                      (size_t)(nblk + sub * 16 + rsel) * ldbk + csel;
            lseg[i] = 8192 + pl * 4096 + sub * 512;
        }
    }

    f32x4 acc[4][2], accl[4][2];
    double accd[4][2][4];
#pragma unroll
    for (int mt = 0; mt < 4; mt++)
#pragma unroll
        for (int nt = 0; nt < 2; nt++) {
            acc[mt][nt] = (f32x4){0.f, 0.f, 0.f, 0.f};
            accl[mt][nt] = (f32x4){0.f, 0.f, 0.f, 0.f};
#pragma unroll
            for (int r = 0; r < 4; r++) accd[mt][nt][r] = 0.0;
        }

    int rA = lane & 15;
    // fragment offset within a 512-ushort segment (row-major + quad-XOR)
    unsigned fo = (rA << 5) + (((lane >> 4) ^ (lane & 3)) << 3);

    int nc = K >> 5;  // 32-K chunks

    // ---- prologue: stage chunk0 -> buf0, chunk1 -> buf1, preload Ah/Bh ----
#pragma unroll
    for (int i = 0; i < 4; i++) gload_lds(gseg[i], lds + lseg[i]);
#pragma unroll
    for (int i = 0; i < 4; i++) gload_lds(gseg[i] + 32, lds + BUFU + lseg[i]);
    asm volatile("s_waitcnt vmcnt(4)" ::: "memory");  // chunk 0 landed
    __builtin_amdgcn_s_barrier();

    f16x8 Ah[4], Al[4], Bh[2], Bl[2];
#pragma unroll
    for (int mt = 0; mt < 4; mt++)
        Ah[mt] = *(const f16x8*)(lds + (wr * 4 + mt) * 512 + fo);
#pragma unroll
    for (int nt = 0; nt < 2; nt++)
        Bh[nt] = *(const f16x8*)(lds + 8192 + (wc * 2 + nt) * 512 + fo);

    int rd = 0, w2 = 2;
    for (int c = 0; c < nc; ++c) {
        const unsigned short* Ar = lds + rd * BUFU;
        unsigned short* Lw = lds + w2 * BUFU;
        const bool pf = (c + 2 < nc);
        const bool nx = (c + 1 < nc);
        int koff = (c + 2) << 5;

        // ================= P0: stage(0,1); MFMA Ah*Bh; read Bl ================
        if (pf) {
            gload_lds(gseg[0] + koff, Lw + lseg[0]);
            gload_lds(gseg[1] + koff, Lw + lseg[1]);
        }
        if (c > 0 && (c & 1) == 0) {  // promote completed chunks during DMA
#pragma unroll
            for (int mt = 0; mt < 4; mt++)
#pragma unroll
                for (int nt = 0; nt < 2; nt++)
#pragma unroll
                    for (int r = 0; r < 4; r++) {
                        accd[mt][nt][r] += (double)acc[mt][nt][r] +
                                           (double)accl[mt][nt][r] * 4.8828125e-4;
                        acc[mt][nt][r] = 0.f;
                        accl[mt][nt][r] = 0.f;
                    }
        }
        __builtin_amdgcn_s_barrier();
#pragma unroll
        for (int nt = 0; nt < 2; nt++)
            Bl[nt] = *(const f16x8*)(Ar + 12288 + (wc * 2 + nt) * 512 + fo);
        __builtin_amdgcn_s_setprio(1);
#pragma unroll
        for (int mt = 0; mt < 4; mt++)
#pragma unroll
            for (int nt = 0; nt < 2; nt++)
                acc[mt][nt] = __builtin_amdgcn_mfma_f32_16x16x32_f16(
                    Ah[mt], Bh[nt], acc[mt][nt], 0, 0, 0);
        __builtin_amdgcn_s_setprio(0);
        __builtin_amdgcn_s_barrier();

        // ================= P1: stage(2,3); MFMA Ah*Bl -> accl; read Al ========
        if (pf) {
            gload_lds(gseg[2] + koff, Lw + lseg[2]);
            gload_lds(gseg[3] + koff, Lw + lseg[3]);
        }
        __builtin_amdgcn_s_barrier();
#pragma unroll
        for (int mt = 0; mt < 4; mt++)
            Al[mt] = *(const f16x8*)(Ar + 4096 + (wr * 4 + mt) * 512 + fo);
        __builtin_amdgcn_s_setprio(1);
#pragma unroll
        for (int mt = 0; mt < 4; mt++)
#pragma unroll
            for (int nt = 0; nt < 2; nt++)
                accl[mt][nt] = __builtin_amdgcn_mfma_f32_16x16x32_f16(
                    Ah[mt], Bl[nt], accl[mt][nt], 0, 0, 0);
        __builtin_amdgcn_s_setprio(0);
        __builtin_amdgcn_s_barrier();

        // ===== P2: vmcnt proves buf c+1 landed; MFMA Al*Bh -> accl; preload ====
        if (nx) {
            if (pf)
                asm volatile("s_waitcnt vmcnt(4)" ::: "memory");
            else
                asm volatile("s_waitcnt vmcnt(0)" ::: "memory");
        }
        __builtin_amdgcn_s_barrier();
        __builtin_amdgcn_s_setprio(1);
#pragma unroll
        for (int mt = 0; mt < 4; mt++)
#pragma unroll
            for (int nt = 0; nt < 2; nt++)
                accl[mt][nt] = __builtin_amdgcn_mfma_f32_16x16x32_f16(
                    Al[mt], Bh[nt], accl[mt][nt], 0, 0, 0);
        __builtin_amdgcn_s_setprio(0);
        if (nx) {  // preload next chunk's Ah/Bh (buffer rd+1, proven landed)
            int rdn = (rd + 1 == 3) ? 0 : rd + 1;
            const unsigned short* An = lds + rdn * BUFU;
#pragma unroll
            for (int mt = 0; mt < 4; mt++)
                Ah[mt] = *(const f16x8*)(An + (wr * 4 + mt) * 512 + fo);
#pragma unroll
            for (int nt = 0; nt < 2; nt++)
                Bh[nt] = *(const f16x8*)(An + 8192 + (wc * 2 + nt) * 512 + fo);
        }
        __builtin_amdgcn_s_barrier();

        rd = (rd + 1 == 3) ? 0 : rd + 1;
        w2 = (w2 + 1 == 3) ? 0 : w2 + 1;
    }

    // final promote (last 2 chunks)
#pragma unroll
    for (int mt = 0; mt < 4; mt++)
#pragma unroll
        for (int nt = 0; nt < 2; nt++)
#pragma unroll
            for (int r = 0; r < 4; r++)
                accd[mt][nt][r] += (double)acc[mt][nt][r] +
                                   (double)accl[mt][nt][r] * 4.8828125e-4;

    // ---- epilogue (f64), write f32 or f16 h/l pair ----
#pragma unroll
    for (int mt = 0; mt < 4; mt++)
#pragma unroll
        for (int nt = 0; nt < 2; nt++) {
            int n = nblk + wc * 32 + nt * 16 + (lane & 15);
            int mb = mblk + wr * 64 + mt * 16 + ((lane >> 4) << 2);
#pragma unroll
            for (int r = 0; r < 4; r++) {
                int m = mb + r;
                size_t off = (size_t)m * ldc + n;
                double v = accd[mt][nt][r];
                if (EPI == EPI_ADD) v += (double)aux[off];
                if (EPI == EPI_SILU) {
                    float vf = (float)v;
                    v = (double)(vf / (1.0f + expf(-vf)));
                }
                if (EPI == EPI_MUL) v *= (double)aux[off];
                if (EPI == EPI_BIAS) v += (double)aux[n];
                if (PAIR) {
                    unsigned short h, l;
                    split2((float)v, h, l);
                    C2[off] = h;
                    C2[strideC + off] = l;
                } else {
                    Cf[off] = (float)v;
                }
            }
        }
}

// ---------------- Argmax over f32 logits (first-max tie-break) ----------------
__global__ __launch_bounds__(256) void argmax_kernel(const float* __restrict__ logits,
                                                     int* __restrict__ out_tok, int p) {
    int t = blockIdx.x;
    const float* lr = logits + (size_t)t * Vn;
    float bv = -INFINITY;
    int bi = 0x7fffffff;
    for (int j = threadIdx.x; j < Vn; j += 256) {
        float v = lr[j];
        if (v > bv || (v == bv && j < bi)) {
            bv = v;
            bi = j;
        }
    }
#pragma unroll
    for (int o = 1; o < 64; o <<= 1) {
        float ov = __shfl_xor(bv, o, 64);
        int oi = __shfl_xor(bi, o, 64);
        if (ov > bv || (ov == bv && oi < bi)) {
            bv = ov;
            bi = oi;
        }
    }
    __shared__ float sv[4];
    __shared__ int si[4];
    if ((threadIdx.x & 63) == 0) {
        sv[threadIdx.x >> 6] = bv;
        si[threadIdx.x >> 6] = bi;
    }
    __syncthreads();
    if (threadIdx.x == 0) {
        for (int w = 1; w < 4; w++) {
            if (sv[w] > bv || (sv[w] == bv && si[w] < bi)) {
                bv = sv[w];
                bi = si[w];
            }
        }
        out_tok[(size_t)t * NSTEPSn + p] = bi;
    }
}

// ---------------- Embedding gather ----------------
__global__ __launch_bounds__(256) void embed_kernel(const float* __restrict__ E,
                                                    const int* __restrict__ toks,
                                                    float* __restrict__ x, int p) {
    int t = blockIdx.x;
    int tok = toks[(size_t)t * NSTEPSn + p];
    float4 v = ((const float4*)(E + (size_t)tok * Hn))[threadIdx.x];
    ((float4*)(x + (size_t)t * Hn))[threadIdx.x] = v;
}

extern "C" void kernel_launch(void* const* d_in, const int* in_sizes, int n_in,
                              void* d_out, int out_size, void* d_ws, size_t ws_size,
                              hipStream_t stream) {
    const float* x0 = (const float*)d_in[0];
    const float* Wq = (const float*)d_in[1];
    const float* Wk = (const float*)d_in[2];
    const float* Wv = (const float*)d_in[3];
    const float* Wo = (const float*)d_in[4];
    const float* Wg = (const float*)d_in[5];
    const float* Wu = (const float*)d_in[6];
    const float* Wd = (const float*)d_in[7];
    const float* n1 = (const float*)d_in[8];
    const float* n2 = (const float*)d_in[9];
    const float* Emb = (const float*)d_in[10];
    const float* Wout = (const float*)d_in[11];
    const float* bout = (const float*)d_in[12];
    int* toks = (int*)d_out;

    float* ws = (float*)d_ws;
    const size_t M1 = 1024 * 1024;
    float* EK = ws;                  // V x H fp32           4MB
    float* EV = ws + 1 * M1;         //                      4MB
    float* K0 = ws + 2 * M1;         // T x H fp32           16MB
    float* V0 = ws + 6 * M1;         //                      16MB
    float* xb = ws + 10 * M1;        // residual hidden      16MB
    float* qb = ws + 14 * M1;        // q / MLP acc / logits 16MB
    float* Gc = ws + 18 * M1;        // silu chunk fp32      16MB
    unsigned short* s2a = (unsigned short*)(ws + 22 * M1);  // h/l TxH  (16MB used)
    unsigned short* s2g = (unsigned short*)(ws + 28 * M1);  // h/l TxH  (16MB used)
    double2* tab = (double2*)(ws + 34 * M1);                // 256 double2  4KB
    unsigned short* W2q = (unsigned short*)(ws + 34 * M1 + 1024);  // 2 planes used
    unsigned short* W2k = W2q + 3 * M1;
    unsigned short* W2v = W2k + 3 * M1;
    unsigned short* W2o = W2v + 3 * M1;
    unsigned short* W2t = W2o + 3 * M1;  // Wout
    unsigned short* W2g = W2t + 3 * M1;
    unsigned short* W2u = W2g + 12 * M1;
    unsigned short* W2d = W2u + 12 * M1;
    // total ~= 238 MB (offsets kept from the bf16x3 layout; 3rd planes unused)

    const size_t STH = (size_t)Tn * Hn;  // plane stride, T x 1024
    const size_t SVH = (size_t)Vn * Hn;  // plane stride, V x H
    const size_t SW1 = M1;               // plane stride, 1M-element weights
    const size_t SW4 = 4 * M1;           // plane stride, 4M-element weights

    dim3 blk(256);
    dim3 gblk(512);
    const int gTH = 256;  // (M/128=32) x (N/128=8), 1D swizzled
    const int gVH = 64;   // (M/128=8)  x 8
    const int gAT = (Tn * NHn) / 32;  // attn: 8 pairs/wave x 4 waves = 2048

    // ---- One-time precompute ----
    rope_tab_kernel<<<1, 256, 0, stream>>>(tab);
    presplit_kernel<<<dim3(16, 16), blk, 0, stream>>>(Wq, W2q, Hn, Hn);
    presplit_kernel<<<dim3(16, 16), blk, 0, stream>>>(Wk, W2k, Hn, Hn);
    presplit_kernel<<<dim3(16, 16), blk, 0, stream>>>(Wv, W2v, Hn, Hn);
    presplit_kernel<<<dim3(16, 16), blk, 0, stream>>>(Wo, W2o, Hn, Hn);
    presplit_kernel<<<dim3(16, 16), blk, 0, stream>>>(Wout, W2t, Hn, Vn);
    presplit_kernel<<<dim3(In / 64, Hn / 64), blk, 0, stream>>>(Wg, W2g, Hn, In);
    presplit_kernel<<<dim3(In / 64, Hn / 64), blk, 0, stream>>>(Wu, W2u, Hn, In);
    presplit_kernel<<<dim3(Hn / 64, In / 64), blk, 0, stream>>>(Wd, W2d, In, Hn);
    rmsnorm2_kernel<<<Vn, 256, 0, stream>>>(Emb, n1, s2a, SVH);
    gemm2_kernel<EPI_NONE, false><<<gVH, gblk, 0, stream>>>(
        s2a, SVH, W2k, SW1, Hn, EK, nullptr, 0, nullptr, Hn, Hn);
    gemm2_kernel<EPI_NONE, false><<<gVH, gblk, 0, stream>>>(
        s2a, SVH, W2v, SW1, Hn, EV, nullptr, 0, nullptr, Hn, Hn);

    for (int p = 0; p < NSTEPSn; p++) {
        const float* src = (p == 0) ? x0 : xb;

        rmsnorm2_kernel<<<Tn, 256, 0, stream>>>(src, n1, s2a, STH);
        gemm2_kernel<EPI_NONE, false><<<gTH, gblk, 0, stream>>>(
            s2a, STH, W2q, SW1, Hn, qb, nullptr, 0, nullptr, Hn, Hn);
        if (p == 0) {
            gemm2_kernel<EPI_NONE, false><<<gTH, gblk, 0, stream>>>(
                s2a, STH, W2k, SW1, Hn, K0, nullptr, 0, nullptr, Hn, Hn);
            gemm2_kernel<EPI_NONE, false><<<gTH, gblk, 0, stream>>>(
                s2a, STH, W2v, SW1, Hn, V0, nullptr, 0, nullptr, Hn, Hn);
        }
        attn_kernel<<<gAT, 256, 0, stream>>>(qb, K0, V0, EK, EV, toks,
                                             tab, s2a, STH, p);
        // h2 = ctx @ Wo + src  (in-place into xb when src == xb)
        gemm2_kernel<EPI_ADD, false><<<gTH, gblk, 0, stream>>>(
            s2a, STH, W2o, SW1, Hn, xb, nullptr, 0, src, Hn, Hn);
        rmsnorm2_kernel<<<Tn, 256, 0, stream>>>(xb, n2, s2a, STH);
        // Gated MLP, chunked over I (4 x 1024): G (silu -> Gc f32), U (mul by
        // Gc -> s2g h/l), then chunk-accumulated @Wd into qb.
        for (int c = 0; c < 4; c++) {
            gemm2_kernel<EPI_SILU, false><<<gTH, gblk, 0, stream>>>(
                s2a, STH, W2g + (size_t)c * M1, SW4, Hn,
                Gc, nullptr, 0, nullptr, Hn, 1024);
            gemm2_kernel<EPI_MUL, true><<<gTH, gblk, 0, stream>>>(
                s2a, STH, W2u + (size_t)c * M1, SW4, Hn,
                nullptr, s2g, STH, Gc, Hn, 1024);
            if (c < 3) {
                gemm2_kernel<EPI_ADD, false><<<gTH, gblk, 0, stream>>>(
                    s2g, STH, W2d + (size_t)c * 1024, SW4, In,
                    qb, nullptr, 0, (c == 0) ? xb : qb, Hn, Hn);
            } else {
                gemm2_kernel<EPI_ADD, true><<<gTH, gblk, 0, stream>>>(
                    s2g, STH, W2d + (size_t)c * 1024, SW4, In,
                    nullptr, s2a, STH, qb, Hn, Hn);
            }
        }
        // logits = out @ Wout + bout  (into qb)
        gemm2_kernel<EPI_BIAS, false><<<gTH, gblk, 0, stream>>>(
            s2a, STH, W2t, SW1, Hn, qb, nullptr, 0, bout, Hn, Vn);
        argmax_kernel<<<Tn, 256, 0, stream>>>(qb, toks, p);
        if (p < NSTEPSn - 1) embed_kernel<<<Tn, 256, 0, stream>>>(Emb, toks, xb, p);
    }
}

// Round 10
// 5803.914 us; speedup vs baseline: 1.3689x; 1.0215x over previous
//
#include <hip/hip_runtime.h>
#include <hip/hip_fp16.h>
#include <cmath>

#define Tn 4096
#define Hn 1024
#define NHn 16
#define HDn 64
#define In 4096
#define Vn 1024
#define NSTEPSn 8

enum { EPI_NONE = 0, EPI_ADD = 1, EPI_SILU = 2, EPI_MUL = 3, EPI_BIAS = 4 };

typedef __attribute__((ext_vector_type(8))) _Float16 f16x8;
typedef __attribute__((ext_vector_type(4))) float f32x4;

// fp32 -> f16 high/low split (RNE), with the LOW plane pre-scaled by 2^11 so
// it stays in f16 NORMAL range (unscaled residuals of 0.02-magnitude weights
// are ~1e-5 — f16 subnormal; if MFMA flushed them the correction would vanish).
// Reconstruction: x ~= h + l * 2^-11, residual ~2^-22 relative — far below the
// f32 reference's own ~2^-19 accumulation noise that dominates token margins.
// The 2^-11 is applied in the GEMM promote (separate accl accumulator).
__device__ inline unsigned short f16rne(float x) {
    return __half_as_ushort(__float2half(x));
}
__device__ inline float f16tof(unsigned short h) {
    return __half2float(__ushort_as_half(h));
}
__device__ inline void split2(float x, unsigned short& h, unsigned short& l) {
    h = f16rne(x);
    float r = (x - f16tof(h)) * 2048.0f;
    l = f16rne(r);
}

// Async global->LDS, 16B per lane (wave-uniform LDS base; HW scatters lane*16).
__device__ __forceinline__ void gload_lds(const unsigned short* g,
                                          const unsigned short* l) {
    __builtin_amdgcn_global_load_lds(
        (const __attribute__((address_space(1))) unsigned int*)(uintptr_t)g,
        (__attribute__((address_space(3))) unsigned int*)(unsigned int)(uintptr_t)l,
        16, 0, 0);
}

// ---------------- RoPE cos/sin table ----------------
__global__ void rope_tab_kernel(double2* __restrict__ tab) {
    int tid = threadIdx.x;  // 256 threads
    int j = tid >> 5, i = tid & 31;
    double inv = exp(-((double)(2 * i) * (1.0 / (double)HDn)) * 9.210340371976184);
    double ang = (double)j * inv;
    double2 cs;
    cs.x = cos(ang);
    cs.y = sin(ang);
    tab[tid] = cs;
}

// ---------------- Weight pre-split: W[K][N] fp32 -> W2[2][N][K] f16 ----------------
__global__ __launch_bounds__(256) void presplit_kernel(const float* __restrict__ W,
                                                       unsigned short* __restrict__ W2,
                                                       int K, int N) {
    __shared__ float S[64][65];
    int k0 = blockIdx.y * 64, n0 = blockIdx.x * 64;
    int tid = threadIdx.x;
#pragma unroll
    for (int r = 0; r < 4; r++) {
        int idx = tid + r * 256;
        int kr = idx >> 4, c4 = (idx & 15) << 2;
        float4 v = *(const float4*)(W + (size_t)(k0 + kr) * N + n0 + c4);
        S[kr][c4] = v.x;
        S[kr][c4 + 1] = v.y;
        S[kr][c4 + 2] = v.z;
        S[kr][c4 + 3] = v.w;
    }
    __syncthreads();
    size_t PS = (size_t)N * K;
#pragma unroll
    for (int r = 0; r < 4; r++) {
        int idx = tid + r * 256;
        int kq = idx & 15, n = idx >> 4;
        ushort4 hq, lq;
        split2(S[4 * kq + 0][n], hq.x, lq.x);
        split2(S[4 * kq + 1][n], hq.y, lq.y);
        split2(S[4 * kq + 2][n], hq.z, lq.z);
        split2(S[4 * kq + 3][n], hq.w, lq.w);
        size_t off = (size_t)(n0 + n) * K + k0 + 4 * kq;
        *(ushort4*)(W2 + off) = hq;
        *(ushort4*)(W2 + PS + off) = lq;
    }
}

// ---------------- RMSNorm -> f16 h/l planes (f64 math) ----------------
__global__ __launch_bounds__(256) void rmsnorm2_kernel(const float* __restrict__ x,
                                                       const float* __restrict__ w,
                                                       unsigned short* __restrict__ y2,
                                                       size_t stride) {
    int t = blockIdx.x;
    const float4* xr = (const float4*)(x + (size_t)t * Hn);
    float4 v = xr[threadIdx.x];
    double ss = (double)v.x * v.x + (double)v.y * v.y + (double)v.z * v.z + (double)v.w * v.w;
#pragma unroll
    for (int o = 1; o < 64; o <<= 1) ss += __shfl_xor(ss, o, 64);
    __shared__ double red[4];
    if ((threadIdx.x & 63) == 0) red[threadIdx.x >> 6] = ss;
    __syncthreads();
    double tot = red[0] + red[1] + red[2] + red[3];
    double rs = 1.0 / sqrt(tot * (1.0 / Hn) + 1e-6);
    const float4* wr = (const float4*)w;
    float4 wv = wr[threadIdx.x];
    float o[4];
    o[0] = (float)((double)v.x * rs * (double)wv.x);
    o[1] = (float)((double)v.y * rs * (double)wv.y);
    o[2] = (float)((double)v.z * rs * (double)wv.z);
    o[3] = (float)((double)v.w * rs * (double)wv.w);
    ushort4 hq, lq;
    split2(o[0], hq.x, lq.x);
    split2(o[1], hq.y, lq.y);
    split2(o[2], hq.z, lq.z);
    split2(o[3], hq.w, lq.w);
    size_t off = (size_t)t * Hn + threadIdx.x * 4;
    *(ushort4*)(y2 + off) = hq;
    *(ushort4*)(y2 + stride + off) = lq;
}

// ---------------- Attention: 8 (t,head) pairs per wave, stride-8 cols ----------
// Lane l: group g = l>>3 owns pair wv*8+g; s = l&7 owns cols {s, s+8, .., s+56}.
// RoPE partner col+-32 is IN-LANE (k<->k+4): zero shuffles for rope. The dot is
// 8 in-lane f64 FMAs + a 3-stage 8-lane reduce (xor 1,2,4) producing 8 scores
// per wave. Per-element rope/exp/softmax expressions identical to the verified
// kernel; only the f64 summation order differs (tree-of-8 vs 64-butterfly).
__global__ __launch_bounds__(256) void attn_kernel(const float* __restrict__ q,
                                                   const float* __restrict__ K0,
                                                   const float* __restrict__ V0,
                                                   const float* __restrict__ EK,
                                                   const float* __restrict__ EV,
                                                   const int* __restrict__ toks,
                                                   const double2* __restrict__ tab,
                                                   unsigned short* __restrict__ ctx2,
                                                   size_t stride, int p) {
    int wv = blockIdx.x * 4 + (threadIdx.x >> 6);  // wave id; 8 pairs per wave
    int lane = threadIdx.x & 63;
    int g = lane >> 3, s = lane & 7;
    int pair = wv * 8 + g;  // t*NH + head
    int t = pair >> 4;
    int head = pair & 15;
    int colbase = pair << 6;  // base into [T*NH*64] arrays

    // ---- q load + rope at position p (partner in-lane: k <-> k+4) ----
    double qv[8], qr[8];
#pragma unroll
    for (int k = 0; k < 8; k++) qv[k] = (double)q[colbase + s + 8 * k];
#pragma unroll
    for (int k = 0; k < 4; k++) {
        double2 cs = tab[p * 32 + s + 8 * k];
        qr[k] = qv[k] * cs.x - qv[k + 4] * cs.y;       // half=0: qv*c - part*s
        qr[k + 4] = qv[k + 4] * cs.x + qv[k] * cs.y;   // half=1: qv*c + part*s
    }

    // ---- scores ----
    double sc[NSTEPSn];
    int tk[NSTEPSn];
    double m = -1e300;
    for (int j = 0; j <= p; j++) {
        double kr[8];
        if (j == 0) {
            tk[0] = 0;
#pragma unroll
            for (int k = 0; k < 8; k++) kr[k] = (double)K0[colbase + s + 8 * k];
        } else {
            int tok = toks[(size_t)t * NSTEPSn + (j - 1)];
            tk[j] = tok;
            size_t eb = (size_t)tok * Hn + (head << 6);
            double kv[8];
#pragma unroll
            for (int k = 0; k < 8; k++) kv[k] = (double)EK[eb + s + 8 * k];
#pragma unroll
            for (int k = 0; k < 4; k++) {
                double2 cs = tab[j * 32 + s + 8 * k];
                kr[k] = kv[k] * cs.x - kv[k + 4] * cs.y;
                kr[k + 4] = kv[k + 4] * cs.x + kv[k] * cs.y;
            }
        }
        double pr = 0.0;
#pragma unroll
        for (int k = 0; k < 8; k++) pr += qr[k] * kr[k];
#pragma unroll
        for (int o = 1; o < 8; o <<= 1) pr += __shfl_xor(pr, o, 64);
        sc[j] = pr * 0.125;
        m = fmax(m, sc[j]);
    }

    // ---- softmax (f32 exp, f64 sum — same as verified kernel) ----
    double den = 0.0;
    for (int j = 0; j <= p; j++) {
        sc[j] = (double)expf((float)(sc[j] - m));
        den += sc[j];
    }
    double invd = 1.0 / den;

    // ---- PV ----
    double acc[8];
#pragma unroll
    for (int k = 0; k < 8; k++) acc[k] = 0.0;
    for (int j = 0; j <= p; j++) {
        if (j == 0) {
#pragma unroll
            for (int k = 0; k < 8; k++)
                acc[k] += sc[0] * (double)V0[colbase + s + 8 * k];
        } else {
            size_t eb = (size_t)tk[j] * Hn + (head << 6);
#pragma unroll
            for (int k = 0; k < 8; k++)
                acc[k] += sc[j] * (double)EV[eb + s + 8 * k];
        }
    }

#pragma unroll
    for (int k = 0; k < 8; k++) {
        unsigned short h, l;
        split2((float)(acc[k] * invd), h, l);
        ctx2[colbase + s + 8 * k] = h;
        ctx2[stride + colbase + s + 8 * k] = l;
    }
}

// ---------------- f16x2 MFMA GEMM: 64x128 tile, 8 waves, 3-buffer pipeline ----
// C(M x N) = A(M x K) @ B(K x N). A planes [2][M][K] f16, B planes [2][N][K];
// low planes pre-scaled by 2^11 (see split2). 3 products per K-chunk:
//   Ah*Bh -> acc (unit scale), Ah*Bl' + Al'*Bh -> accl (2^11 scale).
// Promote: accd += acc + accl * 2^-11 (f64) every 2 chunks (same cadence as the
// verified 128x128 kernel -> per-output-element arithmetic is bit-identical).
// 64x128 tile, grid 2x larger -> 2 BLOCKS PER CU (144KB LDS, 4 waves/SIMD):
// when one block stalls at a barrier/vmcnt the other block's waves fill the
// CU — the R9 counters (MfmaUtil 13.6%, VALU 24%, HBM 9%, Occ 21%) showed the
// 1-block/CU lockstep left the machine idle at every barrier.
// Pipeline: 3 phases/chunk; next-phase ds_reads issue inside the current MFMA
// region; counted vmcnt(3) in P2 proves buffer c+1 landed; never vmcnt(0) in
// steady state. Staging: 3 segs/wave (2 in P0, 1 in P1).
#define BUFU 12288  // ushorts per buffer: 24KB (A 8KB + B 16KB)
template <int EPI, bool PAIR>
__global__ __launch_bounds__(512, 4) void gemm2_kernel(
    const unsigned short* __restrict__ A2, size_t strideA,
    const unsigned short* __restrict__ B2, size_t strideB, int ldbk,
    float* Cf, unsigned short* C2, size_t strideC,
    const float* aux, int K, int ldc) {
    __shared__ __align__(16) unsigned short lds[3 * BUFU];  // 72 KB

    int tid = threadIdx.x;
    int wv = tid >> 6, lane = tid & 63;
    int wr = wv >> 2;  // 2 m-groups of 32
    int wc = wv & 3;   // 4 n-groups of 32

    // ---- XCD swizzle: GN = 8 fixed (N=1024/128) ----
    int f = blockIdx.x;
    int xcd = f & 7;
    int j = f >> 3;
    int bmPer = gridDim.x >> 6;  // m-blocks per xcd (512->8, 128->2)
    int mblk = (xcd * bmPer + (j >> 3)) * 64;
    int nblk = (j & 7) * 128;

    // ---- staging segments: 24 x 1KB, each wave owns 3 (2 in P0, 1 in P1) ----
    // row-major+quad-XOR: lanes 4q..4q+3 cover one 64B row-slice
    int rsel = lane >> 2;
    int csel = ((lane & 3) ^ ((lane >> 2) & 3)) << 3;
    const unsigned short* gseg[3];
    unsigned lseg[3];
#pragma unroll
    for (int i = 0; i < 3; i++) {
        int s = wv * 3 + i;
        if (s < 8) {
            int pl = s >> 2, sub = s & 3;
            gseg[i] = A2 + (size_t)pl * strideA +
                      (size_t)(mblk + sub * 16 + rsel) * K + csel;
            lseg[i] = pl * 2048 + sub * 512;
        } else {
            int u = s - 8;
            int pl = u >> 3, sub = u & 7;
            gseg[i] = B2 + (size_t)pl * strideB +
                      (size_t)(nblk + sub * 16 + rsel) * ldbk + csel;
            lseg[i] = 4096 + pl * 4096 + sub * 512;
        }
    }

    f32x4 acc[2][2], accl[2][2];
    double accd[2][2][4];
#pragma unroll
    for (int mt = 0; mt < 2; mt++)
#pragma unroll
        for (int nt = 0; nt < 2; nt++) {
            acc[mt][nt] = (f32x4){0.f, 0.f, 0.f, 0.f};
            accl[mt][nt] = (f32x4){0.f, 0.f, 0.f, 0.f};
#pragma unroll
            for (int r = 0; r < 4; r++) accd[mt][nt][r] = 0.0;
        }

    int rA = lane & 15;
    // fragment offset within a 512-ushort segment (row-major + quad-XOR)
    unsigned fo = (rA << 5) + (((lane >> 4) ^ (lane & 3)) << 3);

    int nc = K >> 5;  // 32-K chunks

    // ---- prologue: stage chunk0 -> buf0, chunk1 -> buf1, preload Ah/Bh ----
#pragma unroll
    for (int i = 0; i < 3; i++) gload_lds(gseg[i], lds + lseg[i]);
#pragma unroll
    for (int i = 0; i < 3; i++) gload_lds(gseg[i] + 32, lds + BUFU + lseg[i]);
    asm volatile("s_waitcnt vmcnt(3)" ::: "memory");  // chunk 0 landed
    __builtin_amdgcn_s_barrier();

    f16x8 Ah[2], Al[2], Bh[2], Bl[2];
#pragma unroll
    for (int mt = 0; mt < 2; mt++)
        Ah[mt] = *(const f16x8*)(lds + (wr * 2 + mt) * 512 + fo);
#pragma unroll
    for (int nt = 0; nt < 2; nt++)
        Bh[nt] = *(const f16x8*)(lds + 4096 + (wc * 2 + nt) * 512 + fo);

    int rd = 0, w2 = 2;
    for (int c = 0; c < nc; ++c) {
        const unsigned short* Ar = lds + rd * BUFU;
        unsigned short* Lw = lds + w2 * BUFU;
        const bool pf = (c + 2 < nc);
        const bool nx = (c + 1 < nc);
        int koff = (c + 2) << 5;

        // ================= P0: stage(0,1); MFMA Ah*Bh; read Bl ================
        if (pf) {
            gload_lds(gseg[0] + koff, Lw + lseg[0]);
            gload_lds(gseg[1] + koff, Lw + lseg[1]);
        }
        if (c > 0 && (c & 1) == 0) {  // promote completed chunks during DMA
#pragma unroll
            for (int mt = 0; mt < 2; mt++)
#pragma unroll
                for (int nt = 0; nt < 2; nt++)
#pragma unroll
                    for (int r = 0; r < 4; r++) {
                        accd[mt][nt][r] += (double)acc[mt][nt][r] +
                                           (double)accl[mt][nt][r] * 4.8828125e-4;
                        acc[mt][nt][r] = 0.f;
                        accl[mt][nt][r] = 0.f;
                    }
        }
        __builtin_amdgcn_s_barrier();
#pragma unroll
        for (int nt = 0; nt < 2; nt++)
            Bl[nt] = *(const f16x8*)(Ar + 8192 + (wc * 2 + nt) * 512 + fo);
        __builtin_amdgcn_s_setprio(1);
#pragma unroll
        for (int mt = 0; mt < 2; mt++)
#pragma unroll
            for (int nt = 0; nt < 2; nt++)
                acc[mt][nt] = __builtin_amdgcn_mfma_f32_16x16x32_f16(
                    Ah[mt], Bh[nt], acc[mt][nt], 0, 0, 0);
        __builtin_amdgcn_s_setprio(0);
        __builtin_amdgcn_s_barrier();

        // ================= P1: stage(2); MFMA Ah*Bl -> accl; read Al ==========
        if (pf) {
            gload_lds(gseg[2] + koff, Lw + lseg[2]);
        }
        __builtin_amdgcn_s_barrier();
#pragma unroll
        for (int mt = 0; mt < 2; mt++)
            Al[mt] = *(const f16x8*)(Ar + 2048 + (wr * 2 + mt) * 512 + fo);
        __builtin_amdgcn_s_setprio(1);
#pragma unroll
        for (int mt = 0; mt < 2; mt++)
#pragma unroll
            for (int nt = 0; nt < 2; nt++)
                accl[mt][nt] = __builtin_amdgcn_mfma_f32_16x16x32_f16(
                    Ah[mt], Bl[nt], accl[mt][nt], 0, 0, 0);
        __builtin_amdgcn_s_setprio(0);
        __builtin_amdgcn_s_barrier();

        // ===== P2: vmcnt proves buf c+1 landed; MFMA Al*Bh -> accl; preload ====
        if (nx) {
            if (pf)
                asm volatile("s_waitcnt vmcnt(3)" ::: "memory");
            else
                asm volatile("s_waitcnt vmcnt(0)" ::: "memory");
        }
        __builtin_amdgcn_s_barrier();
        __builtin_amdgcn_s_setprio(1);
#pragma unroll
        for (int mt = 0; mt < 2; mt++)
#pragma unroll
            for (int nt = 0; nt < 2; nt++)
                accl[mt][nt] = __builtin_amdgcn_mfma_f32_16x16x32_f16(
                    Al[mt], Bh[nt], accl[mt][nt], 0, 0, 0);
        __builtin_amdgcn_s_setprio(0);
        if (nx) {  // preload next chunk's Ah/Bh (buffer rd+1, proven landed)
            int rdn = (rd + 1 == 3) ? 0 : rd + 1;
            const unsigned short* An = lds + rdn * BUFU;
#pragma unroll
            for (int mt = 0; mt < 2; mt++)
                Ah[mt] = *(const f16x8*)(An + (wr * 2 + mt) * 512 + fo);
#pragma unroll
            for (int nt = 0; nt < 2; nt++)
                Bh[nt] = *(const f16x8*)(An + 4096 + (wc * 2 + nt) * 512 + fo);
        }
        __builtin_amdgcn_s_barrier();

        rd = (rd + 1 == 3) ? 0 : rd + 1;
        w2 = (w2 + 1 == 3) ? 0 : w2 + 1;
    }

    // final promote (last 2 chunks)
#pragma unroll
    for (int mt = 0; mt < 2; mt++)
#pragma unroll
        for (int nt = 0; nt < 2; nt++)
#pragma unroll
            for (int r = 0; r < 4; r++)
                accd[mt][nt][r] += (double)acc[mt][nt][r] +
                                   (double)accl[mt][nt][r] * 4.8828125e-4;

    // ---- epilogue (f64), write f32 or f16 h/l pair ----
#pragma unroll
    for (int mt = 0; mt < 2; mt++)
#pragma unroll
        for (int nt = 0; nt < 2; nt++) {
            int n = nblk + wc * 32 + nt * 16 + (lane & 15);
            int mb = mblk + wr * 32 + mt * 16 + ((lane >> 4) << 2);
#pragma unroll
            for (int r = 0; r < 4; r++) {
                int m = mb + r;
                size_t off = (size_t)m * ldc + n;
                double v = accd[mt][nt][r];
                if (EPI == EPI_ADD) v += (double)aux[off];
                if (EPI == EPI_SILU) {
                    float vf = (float)v;
                    v = (double)(vf / (1.0f + expf(-vf)));
                }
                if (EPI == EPI_MUL) v *= (double)aux[off];
                if (EPI == EPI_BIAS) v += (double)aux[n];
                if (PAIR) {
                    unsigned short h, l;
                    split2((float)v, h, l);
                    C2[off] = h;
                    C2[strideC + off] = l;
                } else {
                    Cf[off] = (float)v;
                }
            }
        }
}

// ---------------- Argmax over f32 logits (first-max tie-break) ----------------
__global__ __launch_bounds__(256) void argmax_kernel(const float* __restrict__ logits,
                                                     int* __restrict__ out_tok, int p) {
    int t = blockIdx.x;
    const float* lr = logits + (size_t)t * Vn;
    float bv = -INFINITY;
    int bi = 0x7fffffff;
    for (int j = threadIdx.x; j < Vn; j += 256) {
        float v = lr[j];
        if (v > bv || (v == bv && j < bi)) {
            bv = v;
            bi = j;
        }
    }
#pragma unroll
    for (int o = 1; o < 64; o <<= 1) {
        float ov = __shfl_xor(bv, o, 64);
        int oi = __shfl_xor(bi, o, 64);
        if (ov > bv || (ov == bv && oi < bi)) {
            bv = ov;
            bi = oi;
        }
    }
    __shared__ float sv[4];
    __shared__ int si[4];
    if ((threadIdx.x & 63) == 0) {
        sv[threadIdx.x >> 6] = bv;
        si[threadIdx.x >> 6] = bi;
    }
    __syncthreads();
    if (threadIdx.x == 0) {
        for (int w = 1; w < 4; w++) {
            if (sv[w] > bv || (sv[w] == bv && si[w] < bi)) {
                bv = sv[w];
                bi = si[w];
            }
        }
        out_tok[(size_t)t * NSTEPSn + p] = bi;
    }
}

// ---------------- Embedding gather ----------------
__global__ __launch_bounds__(256) void embed_kernel(const float* __restrict__ E,
                                                    const int* __restrict__ toks,
                                                    float* __restrict__ x, int p) {
    int t = blockIdx.x;
    int tok = toks[(size_t)t * NSTEPSn + p];
    float4 v = ((const float4*)(E + (size_t)tok * Hn))[threadIdx.x];
    ((float4*)(x + (size_t)t * Hn))[threadIdx.x] = v;
}

extern "C" void kernel_launch(void* const* d_in, const int* in_sizes, int n_in,
                              void* d_out, int out_size, void* d_ws, size_t ws_size,
                              hipStream_t stream) {
    const float* x0 = (const float*)d_in[0];
    const float* Wq = (const float*)d_in[1];
    const float* Wk = (const float*)d_in[2];
    const float* Wv = (const float*)d_in[3];
    const float* Wo = (const float*)d_in[4];
    const float* Wg = (const float*)d_in[5];
    const float* Wu = (const float*)d_in[6];
    const float* Wd = (const float*)d_in[7];
    const float* n1 = (const float*)d_in[8];
    const float* n2 = (const float*)d_in[9];
    const float* Emb = (const float*)d_in[10];
    const float* Wout = (const float*)d_in[11];
    const float* bout = (const float*)d_in[12];
    int* toks = (int*)d_out;

    float* ws = (float*)d_ws;
    const size_t M1 = 1024 * 1024;
    float* EK = ws;                  // V x H fp32           4MB
    float* EV = ws + 1 * M1;         //                      4MB
    float* K0 = ws + 2 * M1;         // T x H fp32           16MB
    float* V0 = ws + 6 * M1;         //                      16MB
    float* xb = ws + 10 * M1;        // residual hidden      16MB
    float* qb = ws + 14 * M1;        // q / MLP acc / logits 16MB
    float* Gc = ws + 18 * M1;        // silu chunk fp32      16MB
    unsigned short* s2a = (unsigned short*)(ws + 22 * M1);  // h/l TxH  (16MB used)
    unsigned short* s2g = (unsigned short*)(ws + 28 * M1);  // h/l TxH  (16MB used)
    double2* tab = (double2*)(ws + 34 * M1);                // 256 double2  4KB
    unsigned short* W2q = (unsigned short*)(ws + 34 * M1 + 1024);  // 2 planes used
    unsigned short* W2k = W2q + 3 * M1;
    unsigned short* W2v = W2k + 3 * M1;
    unsigned short* W2o = W2v + 3 * M1;
    unsigned short* W2t = W2o + 3 * M1;  // Wout
    unsigned short* W2g = W2t + 3 * M1;
    unsigned short* W2u = W2g + 12 * M1;
    unsigned short* W2d = W2u + 12 * M1;
    // total ~= 238 MB (offsets kept from the bf16x3 layout; 3rd planes unused)

    const size_t STH = (size_t)Tn * Hn;  // plane stride, T x 1024
    const size_t SVH = (size_t)Vn * Hn;  // plane stride, V x H
    const size_t SW1 = M1;               // plane stride, 1M-element weights
    const size_t SW4 = 4 * M1;           // plane stride, 4M-element weights

    dim3 blk(256);
    dim3 gblk(512);
    const int gTH = 512;  // (M/64=64) x (N/128=8), 1D swizzled -> 2 blocks/CU
    const int gVH = 128;  // (M/64=16) x 8
    const int gAT = (Tn * NHn) / 32;  // attn: 8 pairs/wave x 4 waves = 2048

    // ---- One-time precompute ----
    rope_tab_kernel<<<1, 256, 0, stream>>>(tab);
    presplit_kernel<<<dim3(16, 16), blk, 0, stream>>>(Wq, W2q, Hn, Hn);
    presplit_kernel<<<dim3(16, 16), blk, 0, stream>>>(Wk, W2k, Hn, Hn);
    presplit_kernel<<<dim3(16, 16), blk, 0, stream>>>(Wv, W2v, Hn, Hn);
    presplit_kernel<<<dim3(16, 16), blk, 0, stream>>>(Wo, W2o, Hn, Hn);
    presplit_kernel<<<dim3(16, 16), blk, 0, stream>>>(Wout, W2t, Hn, Vn);
    presplit_kernel<<<dim3(In / 64, Hn / 64), blk, 0, stream>>>(Wg, W2g, Hn, In);
    presplit_kernel<<<dim3(In / 64, Hn / 64), blk, 0, stream>>>(Wu, W2u, Hn, In);
    presplit_kernel<<<dim3(Hn / 64, In / 64), blk, 0, stream>>>(Wd, W2d, In, Hn);
    rmsnorm2_kernel<<<Vn, 256, 0, stream>>>(Emb, n1, s2a, SVH);
    gemm2_kernel<EPI_NONE, false><<<gVH, gblk, 0, stream>>>(
        s2a, SVH, W2k, SW1, Hn, EK, nullptr, 0, nullptr, Hn, Hn);
    gemm2_kernel<EPI_NONE, false><<<gVH, gblk, 0, stream>>>(
        s2a, SVH, W2v, SW1, Hn, EV, nullptr, 0, nullptr, Hn, Hn);

    for (int p = 0; p < NSTEPSn; p++) {
        const float* src = (p == 0) ? x0 : xb;

        rmsnorm2_kernel<<<Tn, 256, 0, stream>>>(src, n1, s2a, STH);
        gemm2_kernel<EPI_NONE, false><<<gTH, gblk, 0, stream>>>(
            s2a, STH, W2q, SW1, Hn, qb, nullptr, 0, nullptr, Hn, Hn);
        if (p == 0) {
            gemm2_kernel<EPI_NONE, false><<<gTH, gblk, 0, stream>>>(
                s2a, STH, W2k, SW1, Hn, K0, nullptr, 0, nullptr, Hn, Hn);
            gemm2_kernel<EPI_NONE, false><<<gTH, gblk, 0, stream>>>(
                s2a, STH, W2v, SW1, Hn, V0, nullptr, 0, nullptr, Hn, Hn);
        }
        attn_kernel<<<gAT, 256, 0, stream>>>(qb, K0, V0, EK, EV, toks,
                                             tab, s2a, STH, p);
        // h2 = ctx @ Wo + src  (in-place into xb when src == xb)
        gemm2_kernel<EPI_ADD, false><<<gTH, gblk, 0, stream>>>(
            s2a, STH, W2o, SW1, Hn, xb, nullptr, 0, src, Hn, Hn);
        rmsnorm2_kernel<<<Tn, 256, 0, stream>>>(xb, n2, s2a, STH);
        // Gated MLP, chunked over I (4 x 1024): G (silu -> Gc f32), U (mul by
        // Gc -> s2g h/l), then chunk-accumulated @Wd into qb.
        for (int c = 0; c < 4; c++) {
            gemm2_kernel<EPI_SILU, false><<<gTH, gblk, 0, stream>>>(
                s2a, STH, W2g + (size_t)c * M1, SW4, Hn,
                Gc, nullptr, 0, nullptr, Hn, 1024);
            gemm2_kernel<EPI_MUL, true><<<gTH, gblk, 0, stream>>>(
                s2a, STH, W2u + (size_t)c * M1, SW4, Hn,
                nullptr, s2g, STH, Gc, Hn, 1024);
            if (c < 3) {
                gemm2_kernel<EPI_ADD, false><<<gTH, gblk, 0, stream>>>(
                    s2g, STH, W2d + (size_t)c * 1024, SW4, In,
                    qb, nullptr, 0, (c == 0) ? xb : qb, Hn, Hn);
            } else {
                gemm2_kernel<EPI_ADD, true><<<gTH, gblk, 0, stream>>>(
                    s2g, STH, W2d + (size_t)c * 1024, SW4, In,
                    nullptr, s2a, STH, qb, Hn, Hn);
            }
        }
        // logits = out @ Wout + bout  (into qb)
        gemm2_kernel<EPI_BIAS, false><<<gTH, gblk, 0, stream>>>(
            s2a, STH, W2t, SW1, Hn, qb, nullptr, 0, bout, Hn, Vn);
        argmax_kernel<<<Tn, 256, 0, stream>>>(qb, toks, p);
        if (p < NSTEPSn - 1) embed_kernel<<<Tn, 256, 0, stream>>>(Emb, toks, xb, p);
    }
}

// Round 11
// 5605.950 us; speedup vs baseline: 1.4172x; 1.0353x over previous
//
#include <hip/hip_runtime.h>
#include <hip/hip_fp16.h>
#include <cmath>

#define Tn 4096
#define Hn 1024
#define NHn 16
#define HDn 64
#define In 4096
#define Vn 1024
#define NSTEPSn 8

enum { EPI_NONE = 0, EPI_ADD = 1, EPI_SILU = 2, EPI_MUL = 3, EPI_BIAS = 4 };

typedef __attribute__((ext_vector_type(8))) _Float16 f16x8;
typedef __attribute__((ext_vector_type(4))) float f32x4;

// fp32 -> f16 high/low split (RNE), with the LOW plane pre-scaled by 2^11 so
// it stays in f16 NORMAL range. Reconstruction: x ~= h + l * 2^-11, residual
// ~2^-22 relative. The 2^-11 is applied in the GEMM promote (accl accumulator).
__device__ inline unsigned short f16rne(float x) {
    return __half_as_ushort(__float2half(x));
}
__device__ inline float f16tof(unsigned short h) {
    return __half2float(__ushort_as_half(h));
}
__device__ inline void split2(float x, unsigned short& h, unsigned short& l) {
    h = f16rne(x);
    float r = (x - f16tof(h)) * 2048.0f;
    l = f16rne(r);
}

// Async global->LDS, 16B per lane (wave-uniform LDS base; HW scatters lane*16).
__device__ __forceinline__ void gload_lds(const unsigned short* g,
                                          const unsigned short* l) {
    __builtin_amdgcn_global_load_lds(
        (const __attribute__((address_space(1))) unsigned int*)(uintptr_t)g,
        (__attribute__((address_space(3))) unsigned int*)(unsigned int)(uintptr_t)l,
        16, 0, 0);
}

// ---------------- RoPE cos/sin table ----------------
__global__ void rope_tab_kernel(double2* __restrict__ tab) {
    int tid = threadIdx.x;  // 256 threads
    int j = tid >> 5, i = tid & 31;
    double inv = exp(-((double)(2 * i) * (1.0 / (double)HDn)) * 9.210340371976184);
    double ang = (double)j * inv;
    double2 cs;
    cs.x = cos(ang);
    cs.y = sin(ang);
    tab[tid] = cs;
}

// ---------------- Weight pre-split: W[K][N] fp32 -> W2[2][N][K] f16 ----------------
__global__ __launch_bounds__(256) void presplit_kernel(const float* __restrict__ W,
                                                       unsigned short* __restrict__ W2,
                                                       int K, int N) {
    __shared__ float S[64][65];
    int k0 = blockIdx.y * 64, n0 = blockIdx.x * 64;
    int tid = threadIdx.x;
#pragma unroll
    for (int r = 0; r < 4; r++) {
        int idx = tid + r * 256;
        int kr = idx >> 4, c4 = (idx & 15) << 2;
        float4 v = *(const float4*)(W + (size_t)(k0 + kr) * N + n0 + c4);
        S[kr][c4] = v.x;
        S[kr][c4 + 1] = v.y;
        S[kr][c4 + 2] = v.z;
        S[kr][c4 + 3] = v.w;
    }
    __syncthreads();
    size_t PS = (size_t)N * K;
#pragma unroll
    for (int r = 0; r < 4; r++) {
        int idx = tid + r * 256;
        int kq = idx & 15, n = idx >> 4;
        ushort4 hq, lq;
        split2(S[4 * kq + 0][n], hq.x, lq.x);
        split2(S[4 * kq + 1][n], hq.y, lq.y);
        split2(S[4 * kq + 2][n], hq.z, lq.z);
        split2(S[4 * kq + 3][n], hq.w, lq.w);
        size_t off = (size_t)(n0 + n) * K + k0 + 4 * kq;
        *(ushort4*)(W2 + off) = hq;
        *(ushort4*)(W2 + PS + off) = lq;
    }
}

// ---------------- RMSNorm -> f16 h/l planes (f64 math) ----------------
__global__ __launch_bounds__(256) void rmsnorm2_kernel(const float* __restrict__ x,
                                                       const float* __restrict__ w,
                                                       unsigned short* __restrict__ y2,
                                                       size_t stride) {
    int t = blockIdx.x;
    const float4* xr = (const float4*)(x + (size_t)t * Hn);
    float4 v = xr[threadIdx.x];
    double ss = (double)v.x * v.x + (double)v.y * v.y + (double)v.z * v.z + (double)v.w * v.w;
#pragma unroll
    for (int o = 1; o < 64; o <<= 1) ss += __shfl_xor(ss, o, 64);
    __shared__ double red[4];
    if ((threadIdx.x & 63) == 0) red[threadIdx.x >> 6] = ss;
    __syncthreads();
    double tot = red[0] + red[1] + red[2] + red[3];
    double rs = 1.0 / sqrt(tot * (1.0 / Hn) + 1e-6);
    const float4* wr = (const float4*)w;
    float4 wv = wr[threadIdx.x];
    float o[4];
    o[0] = (float)((double)v.x * rs * (double)wv.x);
    o[1] = (float)((double)v.y * rs * (double)wv.y);
    o[2] = (float)((double)v.z * rs * (double)wv.z);
    o[3] = (float)((double)v.w * rs * (double)wv.w);
    ushort4 hq, lq;
    split2(o[0], hq.x, lq.x);
    split2(o[1], hq.y, lq.y);
    split2(o[2], hq.z, lq.z);
    split2(o[3], hq.w, lq.w);
    size_t off = (size_t)t * Hn + threadIdx.x * 4;
    *(ushort4*)(y2 + off) = hq;
    *(ushort4*)(y2 + stride + off) = lq;
}

// ---------------- Attention: 8 (t,head) pairs per wave, stride-8 cols ----------
__global__ __launch_bounds__(256) void attn_kernel(const float* __restrict__ q,
                                                   const float* __restrict__ K0,
                                                   const float* __restrict__ V0,
                                                   const float* __restrict__ EK,
                                                   const float* __restrict__ EV,
                                                   const int* __restrict__ toks,
                                                   const double2* __restrict__ tab,
                                                   unsigned short* __restrict__ ctx2,
                                                   size_t stride, int p) {
    int wv = blockIdx.x * 4 + (threadIdx.x >> 6);  // wave id; 8 pairs per wave
    int lane = threadIdx.x & 63;
    int g = lane >> 3, s = lane & 7;
    int pair = wv * 8 + g;  // t*NH + head
    int t = pair >> 4;
    int head = pair & 15;
    int colbase = pair << 6;  // base into [T*NH*64] arrays

    // ---- q load + rope at position p (partner in-lane: k <-> k+4) ----
    double qv[8], qr[8];
#pragma unroll
    for (int k = 0; k < 8; k++) qv[k] = (double)q[colbase + s + 8 * k];
#pragma unroll
    for (int k = 0; k < 4; k++) {
        double2 cs = tab[p * 32 + s + 8 * k];
        qr[k] = qv[k] * cs.x - qv[k + 4] * cs.y;       // half=0: qv*c - part*s
        qr[k + 4] = qv[k + 4] * cs.x + qv[k] * cs.y;   // half=1: qv*c + part*s
    }

    // ---- scores ----
    double sc[NSTEPSn];
    int tk[NSTEPSn];
    double m = -1e300;
    for (int j = 0; j <= p; j++) {
        double kr[8];
        if (j == 0) {
            tk[0] = 0;
#pragma unroll
            for (int k = 0; k < 8; k++) kr[k] = (double)K0[colbase + s + 8 * k];
        } else {
            int tok = toks[(size_t)t * NSTEPSn + (j - 1)];
            tk[j] = tok;
            size_t eb = (size_t)tok * Hn + (head << 6);
            double kv[8];
#pragma unroll
            for (int k = 0; k < 8; k++) kv[k] = (double)EK[eb + s + 8 * k];
#pragma unroll
            for (int k = 0; k < 4; k++) {
                double2 cs = tab[j * 32 + s + 8 * k];
                kr[k] = kv[k] * cs.x - kv[k + 4] * cs.y;
                kr[k + 4] = kv[k + 4] * cs.x + kv[k] * cs.y;
            }
        }
        double pr = 0.0;
#pragma unroll
        for (int k = 0; k < 8; k++) pr += qr[k] * kr[k];
#pragma unroll
        for (int o = 1; o < 8; o <<= 1) pr += __shfl_xor(pr, o, 64);
        sc[j] = pr * 0.125;
        m = fmax(m, sc[j]);
    }

    // ---- softmax (f32 exp, f64 sum) ----
    double den = 0.0;
    for (int j = 0; j <= p; j++) {
        sc[j] = (double)expf((float)(sc[j] - m));
        den += sc[j];
    }
    double invd = 1.0 / den;

    // ---- PV ----
    double acc[8];
#pragma unroll
    for (int k = 0; k < 8; k++) acc[k] = 0.0;
    for (int j = 0; j <= p; j++) {
        if (j == 0) {
#pragma unroll
            for (int k = 0; k < 8; k++)
                acc[k] += sc[0] * (double)V0[colbase + s + 8 * k];
        } else {
            size_t eb = (size_t)tk[j] * Hn + (head << 6);
#pragma unroll
            for (int k = 0; k < 8; k++)
                acc[k] += sc[j] * (double)EV[eb + s + 8 * k];
        }
    }

#pragma unroll
    for (int k = 0; k < 8; k++) {
        unsigned short h, l;
        split2((float)(acc[k] * invd), h, l);
        ctx2[colbase + s + 8 * k] = h;
        ctx2[stride + colbase + s + 8 * k] = l;
    }
}

// ---------------- f16x2 MFMA GEMM: 64x128 tile, 8 waves, 3-buffer pipeline ----
// C(M x N) = A(M x K) @ B(K x N). A planes [2][M][K] f16, B planes [2][N][K];
// low planes pre-scaled by 2^11. 3 products per K-chunk:
//   Ah*Bh -> acc (unit scale), Ah*Bl' + Al'*Bh -> accl (2^11 scale).
// Promote: accd += acc + accl * 2^-11 (f64) every 2 chunks (cadence and
// per-accumulator product order bit-identical to the verified R10 kernel).
// SINGLE barrier + single counted vmcnt per chunk (was 6 barriers in 3 phases):
// the end-of-chunk barrier proves all waves consumed their chunk c-1 reads
// (MFMAs force lgkmcnt pre-barrier), so staging into buf (c+2)%3 — last read
// at c-1 — is race-free; vmcnt(3)+barrier proves chunk c+1 landed block-wide.
// Bank-conflict-free LDS cells: slot position = global_slot ^ ((row>>1)&3).
// Read bank = 16(row&1) + 4*pos + d: (row&1, (row>>1)&3) covers all 8 bank
// groups exactly twice over 16 rows -> 2 lanes/bank (free; was 4-way with the
// (row&3) xor — measured 4.2M conflict cycles). Same involution on the
// global source of global_load_lds (linear LDS dest) and on the read offset;
// 4-lanes-per-64B-line global coalescing preserved; data per lane unchanged.
#define BUFU 12288  // ushorts per buffer: 24KB (A 8KB + B 16KB)
template <int EPI, bool PAIR>
__global__ __launch_bounds__(512, 4) void gemm2_kernel(
    const unsigned short* __restrict__ A2, size_t strideA,
    const unsigned short* __restrict__ B2, size_t strideB, int ldbk,
    float* Cf, unsigned short* C2, size_t strideC,
    const float* aux, int K, int ldc) {
    __shared__ __align__(16) unsigned short lds[3 * BUFU];  // 72 KB

    int tid = threadIdx.x;
    int wv = tid >> 6, lane = tid & 63;
    int wr = wv >> 2;  // 2 m-groups of 32
    int wc = wv & 3;   // 4 n-groups of 32

    // ---- XCD swizzle: GN = 8 fixed (N=1024/128) ----
    int f = blockIdx.x;
    int xcd = f & 7;
    int j = f >> 3;
    int bmPer = gridDim.x >> 6;  // m-blocks per xcd (512->8, 128->2)
    int mblk = (xcd * bmPer + (j >> 3)) * 64;
    int nblk = (j & 7) * 128;

    // ---- staging segments: 24 x 1KB, each wave owns 3 ----
    // row-major cells, slot swizzled by (row>>1)&3; lanes 4q..4q+3 cover one
    // 64B row-slice (permuted) -> coalesced global_load_lds source.
    int rsel = lane >> 2;
    int csel = ((lane & 3) ^ ((lane >> 3) & 3)) << 3;
    const unsigned short* gseg[3];
    unsigned lseg[3];
#pragma unroll
    for (int i = 0; i < 3; i++) {
        int s = wv * 3 + i;
        if (s < 8) {
            int pl = s >> 2, sub = s & 3;
            gseg[i] = A2 + (size_t)pl * strideA +
                      (size_t)(mblk + sub * 16 + rsel) * K + csel;
            lseg[i] = pl * 2048 + sub * 512;
        } else {
            int u = s - 8;
            int pl = u >> 3, sub = u & 7;
            gseg[i] = B2 + (size_t)pl * strideB +
                      (size_t)(nblk + sub * 16 + rsel) * ldbk + csel;
            lseg[i] = 4096 + pl * 4096 + sub * 512;
        }
    }

    f32x4 acc[2][2], accl[2][2];
    double accd[2][2][4];
#pragma unroll
    for (int mt = 0; mt < 2; mt++)
#pragma unroll
        for (int nt = 0; nt < 2; nt++) {
            acc[mt][nt] = (f32x4){0.f, 0.f, 0.f, 0.f};
            accl[mt][nt] = (f32x4){0.f, 0.f, 0.f, 0.f};
#pragma unroll
            for (int r = 0; r < 4; r++) accd[mt][nt][r] = 0.0;
        }

    int rA = lane & 15;
    // fragment offset within a 512-ushort segment: row rA, slot hi^((rA>>1)&3)
    unsigned fo = (rA << 5) + ((((lane >> 4) ^ ((lane >> 1) & 3))) << 3);

    int nc = K >> 5;  // 32-K chunks

    // ---- prologue: stage chunk0 -> buf0, chunk1 -> buf1 ----
#pragma unroll
    for (int i = 0; i < 3; i++) gload_lds(gseg[i], lds + lseg[i]);
#pragma unroll
    for (int i = 0; i < 3; i++) gload_lds(gseg[i] + 32, lds + BUFU + lseg[i]);
    asm volatile("s_waitcnt vmcnt(3)" ::: "memory");  // chunk 0 landed
    __builtin_amdgcn_s_barrier();

    int rd = 0, w2 = 2;
    for (int c = 0; c < nc; ++c) {
        const unsigned short* Ar = lds + rd * BUFU;
        unsigned short* Lw = lds + w2 * BUFU;
        const bool pf = (c + 2 < nc);
        const bool nx = (c + 1 < nc);
        int koff = (c + 2) << 5;

        // stage chunk c+2 into buf w2 (read finished at iter c-1; barrier-safe)
        if (pf) {
            gload_lds(gseg[0] + koff, Lw + lseg[0]);
            gload_lds(gseg[1] + koff, Lw + lseg[1]);
            gload_lds(gseg[2] + koff, Lw + lseg[2]);
        }

        // all 8 fragment reads for chunk c (proven landed by prev vmcnt+barrier)
        f16x8 Ah[2], Al[2], Bh[2], Bl[2];
#pragma unroll
        for (int mt = 0; mt < 2; mt++) {
            Ah[mt] = *(const f16x8*)(Ar + (wr * 2 + mt) * 512 + fo);
            Al[mt] = *(const f16x8*)(Ar + 2048 + (wr * 2 + mt) * 512 + fo);
        }
#pragma unroll
        for (int nt = 0; nt < 2; nt++) {
            Bh[nt] = *(const f16x8*)(Ar + 4096 + (wc * 2 + nt) * 512 + fo);
            Bl[nt] = *(const f16x8*)(Ar + 8192 + (wc * 2 + nt) * 512 + fo);
        }

        // promote completed chunks (every 2 chunks; overlaps DMA/ds latency)
        if (c > 0 && (c & 1) == 0) {
#pragma unroll
            for (int mt = 0; mt < 2; mt++)
#pragma unroll
                for (int nt = 0; nt < 2; nt++)
#pragma unroll
                    for (int r = 0; r < 4; r++) {
                        accd[mt][nt][r] += (double)acc[mt][nt][r] +
                                           (double)accl[mt][nt][r] * 4.8828125e-4;
                        acc[mt][nt][r] = 0.f;
                        accl[mt][nt][r] = 0.f;
                    }
        }

        __builtin_amdgcn_s_setprio(1);
#pragma unroll
        for (int mt = 0; mt < 2; mt++)
#pragma unroll
            for (int nt = 0; nt < 2; nt++)
                acc[mt][nt] = __builtin_amdgcn_mfma_f32_16x16x32_f16(
                    Ah[mt], Bh[nt], acc[mt][nt], 0, 0, 0);
#pragma unroll
        for (int mt = 0; mt < 2; mt++)
#pragma unroll
            for (int nt = 0; nt < 2; nt++)
                accl[mt][nt] = __builtin_amdgcn_mfma_f32_16x16x32_f16(
                    Ah[mt], Bl[nt], accl[mt][nt], 0, 0, 0);
#pragma unroll
        for (int mt = 0; mt < 2; mt++)
#pragma unroll
            for (int nt = 0; nt < 2; nt++)
                accl[mt][nt] = __builtin_amdgcn_mfma_f32_16x16x32_f16(
                    Al[mt], Bh[nt], accl[mt][nt], 0, 0, 0);
        __builtin_amdgcn_s_setprio(0);

        // chunk c+1 proven landed for next iteration; never vmcnt(0) steady-state
        if (nx) {
            if (pf)
                asm volatile("s_waitcnt vmcnt(3)" ::: "memory");
            else
                asm volatile("s_waitcnt vmcnt(0)" ::: "memory");
        }
        __builtin_amdgcn_s_barrier();

        rd = (rd + 1 == 3) ? 0 : rd + 1;
        w2 = (w2 + 1 == 3) ? 0 : w2 + 1;
    }

    // final promote (last 2 chunks)
#pragma unroll
    for (int mt = 0; mt < 2; mt++)
#pragma unroll
        for (int nt = 0; nt < 2; nt++)
#pragma unroll
            for (int r = 0; r < 4; r++)
                accd[mt][nt][r] += (double)acc[mt][nt][r] +
                                   (double)accl[mt][nt][r] * 4.8828125e-4;

    // ---- epilogue (f64), write f32 or f16 h/l pair ----
#pragma unroll
    for (int mt = 0; mt < 2; mt++)
#pragma unroll
        for (int nt = 0; nt < 2; nt++) {
            int n = nblk + wc * 32 + nt * 16 + (lane & 15);
            int mb = mblk + wr * 32 + mt * 16 + ((lane >> 4) << 2);
#pragma unroll
            for (int r = 0; r < 4; r++) {
                int m = mb + r;
                size_t off = (size_t)m * ldc + n;
                double v = accd[mt][nt][r];
                if (EPI == EPI_ADD) v += (double)aux[off];
                if (EPI == EPI_SILU) {
                    float vf = (float)v;
                    v = (double)(vf / (1.0f + expf(-vf)));
                }
                if (EPI == EPI_MUL) v *= (double)aux[off];
                if (EPI == EPI_BIAS) v += (double)aux[n];
                if (PAIR) {
                    unsigned short h, l;
                    split2((float)v, h, l);
                    C2[off] = h;
                    C2[strideC + off] = l;
                } else {
                    Cf[off] = (float)v;
                }
            }
        }
}

// ---------------- Argmax over f32 logits (first-max tie-break) ----------------
__global__ __launch_bounds__(256) void argmax_kernel(const float* __restrict__ logits,
                                                     int* __restrict__ out_tok, int p) {
    int t = blockIdx.x;
    const float* lr = logits + (size_t)t * Vn;
    float bv = -INFINITY;
    int bi = 0x7fffffff;
    for (int j = threadIdx.x; j < Vn; j += 256) {
        float v = lr[j];
        if (v > bv || (v == bv && j < bi)) {
            bv = v;
            bi = j;
        }
    }
#pragma unroll
    for (int o = 1; o < 64; o <<= 1) {
        float ov = __shfl_xor(bv, o, 64);
        int oi = __shfl_xor(bi, o, 64);
        if (ov > bv || (ov == bv && oi < bi)) {
            bv = ov;
            bi = oi;
        }
    }
    __shared__ float sv[4];
    __shared__ int si[4];
    if ((threadIdx.x & 63) == 0) {
        sv[threadIdx.x >> 6] = bv;
        si[threadIdx.x >> 6] = bi;
    }
    __syncthreads();
    if (threadIdx.x == 0) {
        for (int w = 1; w < 4; w++) {
            if (sv[w] > bv || (sv[w] == bv && si[w] < bi)) {
                bv = sv[w];
                bi = si[w];
            }
        }
        out_tok[(size_t)t * NSTEPSn + p] = bi;
    }
}

// ---------------- Embedding gather ----------------
__global__ __launch_bounds__(256) void embed_kernel(const float* __restrict__ E,
                                                    const int* __restrict__ toks,
                                                    float* __restrict__ x, int p) {
    int t = blockIdx.x;
    int tok = toks[(size_t)t * NSTEPSn + p];
    float4 v = ((const float4*)(E + (size_t)tok * Hn))[threadIdx.x];
    ((float4*)(x + (size_t)t * Hn))[threadIdx.x] = v;
}

extern "C" void kernel_launch(void* const* d_in, const int* in_sizes, int n_in,
                              void* d_out, int out_size, void* d_ws, size_t ws_size,
                              hipStream_t stream) {
    const float* x0 = (const float*)d_in[0];
    const float* Wq = (const float*)d_in[1];
    const float* Wk = (const float*)d_in[2];
    const float* Wv = (const float*)d_in[3];
    const float* Wo = (const float*)d_in[4];
    const float* Wg = (const float*)d_in[5];
    const float* Wu = (const float*)d_in[6];
    const float* Wd = (const float*)d_in[7];
    const float* n1 = (const float*)d_in[8];
    const float* n2 = (const float*)d_in[9];
    const float* Emb = (const float*)d_in[10];
    const float* Wout = (const float*)d_in[11];
    const float* bout = (const float*)d_in[12];
    int* toks = (int*)d_out;

    float* ws = (float*)d_ws;
    const size_t M1 = 1024 * 1024;
    float* EK = ws;                  // V x H fp32           4MB
    float* EV = ws + 1 * M1;         //                      4MB
    float* K0 = ws + 2 * M1;         // T x H fp32           16MB
    float* V0 = ws + 6 * M1;         //                      16MB
    float* xb = ws + 10 * M1;        // residual hidden      16MB
    float* qb = ws + 14 * M1;        // q / MLP acc / logits 16MB
    float* Gc = ws + 18 * M1;        // silu chunk fp32      16MB
    unsigned short* s2a = (unsigned short*)(ws + 22 * M1);  // h/l TxH  (16MB used)
    unsigned short* s2g = (unsigned short*)(ws + 28 * M1);  // h/l TxH  (16MB used)
    double2* tab = (double2*)(ws + 34 * M1);                // 256 double2  4KB
    unsigned short* W2q = (unsigned short*)(ws + 34 * M1 + 1024);  // 2 planes used
    unsigned short* W2k = W2q + 3 * M1;
    unsigned short* W2v = W2k + 3 * M1;
    unsigned short* W2o = W2v + 3 * M1;
    unsigned short* W2t = W2o + 3 * M1;  // Wout
    unsigned short* W2g = W2t + 3 * M1;
    unsigned short* W2u = W2g + 12 * M1;
    unsigned short* W2d = W2u + 12 * M1;
    // total ~= 238 MB (offsets kept from the bf16x3 layout; 3rd planes unused)

    const size_t STH = (size_t)Tn * Hn;  // plane stride, T x 1024
    const size_t SVH = (size_t)Vn * Hn;  // plane stride, V x H
    const size_t SW1 = M1;               // plane stride, 1M-element weights
    const size_t SW4 = 4 * M1;           // plane stride, 4M-element weights

    dim3 blk(256);
    dim3 gblk(512);
    const int gTH = 512;  // (M/64=64) x (N/128=8), 1D swizzled -> 2 blocks/CU
    const int gVH = 128;  // (M/64=16) x 8
    const int gAT = (Tn * NHn) / 32;  // attn: 8 pairs/wave x 4 waves = 2048

    // ---- One-time precompute ----
    rope_tab_kernel<<<1, 256, 0, stream>>>(tab);
    presplit_kernel<<<dim3(16, 16), blk, 0, stream>>>(Wq, W2q, Hn, Hn);
    presplit_kernel<<<dim3(16, 16), blk, 0, stream>>>(Wk, W2k, Hn, Hn);
    presplit_kernel<<<dim3(16, 16), blk, 0, stream>>>(Wv, W2v, Hn, Hn);
    presplit_kernel<<<dim3(16, 16), blk, 0, stream>>>(Wo, W2o, Hn, Hn);
    presplit_kernel<<<dim3(16, 16), blk, 0, stream>>>(Wout, W2t, Hn, Vn);
    presplit_kernel<<<dim3(In / 64, Hn / 64), blk, 0, stream>>>(Wg, W2g, Hn, In);
    presplit_kernel<<<dim3(In / 64, Hn / 64), blk, 0, stream>>>(Wu, W2u, Hn, In);
    presplit_kernel<<<dim3(Hn / 64, In / 64), blk, 0, stream>>>(Wd, W2d, In, Hn);
    rmsnorm2_kernel<<<Vn, 256, 0, stream>>>(Emb, n1, s2a, SVH);
    gemm2_kernel<EPI_NONE, false><<<gVH, gblk, 0, stream>>>(
        s2a, SVH, W2k, SW1, Hn, EK, nullptr, 0, nullptr, Hn, Hn);
    gemm2_kernel<EPI_NONE, false><<<gVH, gblk, 0, stream>>>(
        s2a, SVH, W2v, SW1, Hn, EV, nullptr, 0, nullptr, Hn, Hn);

    for (int p = 0; p < NSTEPSn; p++) {
        const float* src = (p == 0) ? x0 : xb;

        rmsnorm2_kernel<<<Tn, 256, 0, stream>>>(src, n1, s2a, STH);
        gemm2_kernel<EPI_NONE, false><<<gTH, gblk, 0, stream>>>(
            s2a, STH, W2q, SW1, Hn, qb, nullptr, 0, nullptr, Hn, Hn);
        if (p == 0) {
            gemm2_kernel<EPI_NONE, false><<<gTH, gblk, 0, stream>>>(
                s2a, STH, W2k, SW1, Hn, K0, nullptr, 0, nullptr, Hn, Hn);
            gemm2_kernel<EPI_NONE, false><<<gTH, gblk, 0, stream>>>(
                s2a, STH, W2v, SW1, Hn, V0, nullptr, 0, nullptr, Hn, Hn);
        }
        attn_kernel<<<gAT, 256, 0, stream>>>(qb, K0, V0, EK, EV, toks,
                                             tab, s2a, STH, p);
        // h2 = ctx @ Wo + src  (in-place into xb when src == xb)
        gemm2_kernel<EPI_ADD, false><<<gTH, gblk, 0, stream>>>(
            s2a, STH, W2o, SW1, Hn, xb, nullptr, 0, src, Hn, Hn);
        rmsnorm2_kernel<<<Tn, 256, 0, stream>>>(xb, n2, s2a, STH);
        // Gated MLP, chunked over I (4 x 1024): G (silu -> Gc f32), U (mul by
        // Gc -> s2g h/l), then chunk-accumulated @Wd into qb.
        for (int c = 0; c < 4; c++) {
            gemm2_kernel<EPI_SILU, false><<<gTH, gblk, 0, stream>>>(
                s2a, STH, W2g + (size_t)c * M1, SW4, Hn,
                Gc, nullptr, 0, nullptr, Hn, 1024);
            gemm2_kernel<EPI_MUL, true><<<gTH, gblk, 0, stream>>>(
                s2a, STH, W2u + (size_t)c * M1, SW4, Hn,
                nullptr, s2g, STH, Gc, Hn, 1024);
            if (c < 3) {
                gemm2_kernel<EPI_ADD, false><<<gTH, gblk, 0, stream>>>(
                    s2g, STH, W2d + (size_t)c * 1024, SW4, In,
                    qb, nullptr, 0, (c == 0) ? xb : qb, Hn, Hn);
            } else {
                gemm2_kernel<EPI_ADD, true><<<gTH, gblk, 0, stream>>>(
                    s2g, STH, W2d + (size_t)c * 1024, SW4, In,
                    nullptr, s2a, STH, qb, Hn, Hn);
            }
        }
        // logits = out @ Wout + bout  (into qb)
        gemm2_kernel<EPI_BIAS, false><<<gTH, gblk, 0, stream>>>(
            s2a, STH, W2t, SW1, Hn, qb, nullptr, 0, bout, Hn, Vn);
        argmax_kernel<<<Tn, 256, 0, stream>>>(qb, toks, p);
        if (p < NSTEPSn - 1) embed_kernel<<<Tn, 256, 0, stream>>>(Emb, toks, xb, p);
    }
}